// Round 11
// baseline (981.554 us; speedup 1.0000x reference)
//
#include <hip/hip_runtime.h>
#include <hip/hip_fp16.h>
#include <math.h>

#define NN 20000
#define NE 320000
#define NG 16
#define ECAP 48   // edges staged per batch in k_gather (deg ~16+-4, max ~40)

typedef _Float16 f16x2 __attribute__((ext_vector_type(2)));
typedef _Float16 f16x8 __attribute__((ext_vector_type(8)));
typedef float    f32x4 __attribute__((ext_vector_type(4)));

__device__ __forceinline__ float dot2f(f16x2 a, f16x2 b, float c){
#if defined(__has_builtin)
#if __has_builtin(__builtin_amdgcn_fdot2)
  return __builtin_amdgcn_fdot2(a, b, c, false);
#else
  return c + (float)a.x*(float)b.x + (float)a.y*(float)b.y;
#endif
#else
  return c + (float)a.x*(float)b.x + (float)a.y*(float)b.y;
#endif
}

__device__ __forceinline__ f16x2 pack2f(float a, float b){
  f16x2 r; r.x = (_Float16)a; r.y = (_Float16)b; return r;
}

__device__ __forceinline__ unsigned packu2f(float a, float b){
  union { f16x2 h; unsigned u; } X; X.h = pack2f(a, b); return X.u;
}

__device__ __forceinline__ float silu_f(float x){ return x / (1.0f + __expf(-x)); }

// recompute bessel basis from dR (identical math/constants throughout all rounds)
__device__ __forceinline__ void bessel8(const float* __restrict__ dR, int e, float* rb){
  float x = dR[3*e+0], y = dR[3*e+1], z = dR[3*e+2];
  float r = sqrtf(x*x + y*y + z*z);
  float rs = fmaxf(r, 1e-6f);
  float inv = 1.0f / rs;
  float env;
  if (r < 3.5f) env = 1.0f;
  else if (r > 4.0f) env = 0.0f;
  else {
    float t = (r - 3.5f) * 2.0f;
    env = 0.5f * (cosf(3.14159265358979323846f * t) + 1.0f);
  }
  float c = 0.7071067811865476f * inv * env;
  #pragma unroll
  for (int k=0;k<8;k++){
    float arg = (float)(k+1) * 0.7853981633974483f * rs;
    rb[k] = c * sinf(arg);
  }
}

// ---------------- geometry: spherical harmonics only (fallback path) ----------------
__global__ void k_geom(const float* __restrict__ dR, float* __restrict__ sh1){
  int e = blockIdx.x*256 + threadIdx.x;
  if (e >= NE) return;
  float x = dR[3*e+0], y = dR[3*e+1], z = dR[3*e+2];
  float r = sqrtf(x*x + y*y + z*z);
  float inv = 1.0f / fmaxf(r, 1e-6f);
  const float SQ3 = 1.7320508075688772f;
  sh1[3*e+0] = SQ3 * x * inv;
  sh1[3*e+1] = SQ3 * y * inv;
  sh1[3*e+2] = SQ3 * z * inv;
}

// ---------------- edge pre-permute (fast path): kills dependent gather chains ----
// Round-11: optionally ALSO precomputes the bessel basis rb[k][p] (identical math
// to bessel8) so k_edgew never runs trig -- it was a 64-lane serial segment
// between two barriers, executed twice (once per layer).
__global__ void k_prep(const float* __restrict__ dR, const int* __restrict__ senders,
                       const int* __restrict__ perm,
                       float* __restrict__ sh1, float* __restrict__ dRp,
                       int* __restrict__ sendp, float* __restrict__ rbp){
  int p = blockIdx.x*256 + threadIdx.x;
  if (p >= NE) return;
  int e = perm[p];
  float x = dR[3*e+0], y = dR[3*e+1], z = dR[3*e+2];
  dRp[3*p+0] = x; dRp[3*p+1] = y; dRp[3*p+2] = z;
  float r = sqrtf(x*x + y*y + z*z);
  float inv = 1.0f / fmaxf(r, 1e-6f);
  const float SQ3 = 1.7320508075688772f;
  sh1[3*p+0] = SQ3 * x * inv;
  sh1[3*p+1] = SQ3 * y * inv;
  sh1[3*p+2] = SQ3 * z * inv;
  sendp[p] = senders[e];
  if (rbp){
    float rs = fmaxf(r, 1e-6f);
    float env;
    if (r < 3.5f) env = 1.0f;
    else if (r > 4.0f) env = 0.0f;
    else {
      float t = (r - 3.5f) * 2.0f;
      env = 0.5f * (cosf(3.14159265358979323846f * t) + 1.0f);
    }
    float c = 0.7071067811865476f * (1.0f/rs) * env;
    #pragma unroll
    for (int k=0;k<8;k++){
      float arg = (float)(k+1) * 0.7853981633974483f * rs;
      rbp[(size_t)k*NE + p] = c * sinf(arg);
    }
  }
}

// ---------------- one-time weight transpose: W[i][e][o] -> W[i][o][e] ------------
__global__ void k_wt(const float* __restrict__ Wscs, const float* __restrict__ Wscv,
                     float* __restrict__ Wst, float* __restrict__ Wvt){
  int idx = blockIdx.x*256 + threadIdx.x;
  if (idx < 49152){                       // 2 layers x 64 x 4 x 96
    int l = idx/24576, r = idx - l*24576;
    int i = r/384; int rem = r - i*384; int e = rem/96; int o = rem - e*96;
    Wst[l*24576 + i*384 + o*4 + e] = Wscs[idx];
  } else if (idx < 49152 + 8192){         // 2 layers x 32 x 4 x 32
    int k = idx - 49152;
    int l = k/4096, r = k - l*4096;
    int i = r/128; int rem = r - i*128; int e = rem/32; int op = rem - e*32;
    Wvt[l*4096 + i*128 + op*4 + e] = Wscv[idx];
  }
}

// ---------------- node embedding ----------------
__global__ void k_embed(const float* __restrict__ nodes, const float* __restrict__ W,
                        float* __restrict__ s){
  int idx = blockIdx.x*256 + threadIdx.x;   // N*64 exact
  int n = idx>>6, o = idx&63;
  float a = nodes[n*4+0]*W[o] + nodes[n*4+1]*W[64+o]
          + nodes[n*4+2]*W[128+o] + nodes[n*4+3]*W[192+o];
  s[idx] = 0.5f*a;
}

// ---------------- counting sort of edges by receiver ----------------
__global__ void k_hist(const int* __restrict__ receivers, int* __restrict__ cnt){
  int e = blockIdx.x*256 + threadIdx.x;
  if (e < NE) atomicAdd(&cnt[receivers[e]], 1);
}

__global__ void k_scan(const int* __restrict__ cnt, int* __restrict__ row, int* __restrict__ cur){
  __shared__ int lsum[1024];
  int t = threadIdx.x;
  int base = t*20;
  int local[20];
  int s = 0;
  #pragma unroll
  for (int i=0;i<20;i++){
    int idx = base+i;
    int v = (idx<NN) ? cnt[idx] : 0;
    local[i] = s; s += v;
  }
  lsum[t] = s; __syncthreads();
  for (int off=1; off<1024; off<<=1){
    int v = (t>=off) ? lsum[t-off] : 0;
    __syncthreads();
    lsum[t] += v;
    __syncthreads();
  }
  int pre = (t>0) ? lsum[t-1] : 0;
  #pragma unroll
  for (int i=0;i<20;i++){
    int idx = base+i;
    if (idx<NN){ int r = pre+local[i]; row[idx]=r; cur[idx]=r; }
  }
  if (t==1023) row[NN] = lsum[1023];
}

__global__ void k_scatter(const int* __restrict__ receivers, int* __restrict__ cur,
                          int* __restrict__ perm){
  int e = blockIdx.x*256 + threadIdx.x;
  if (e < NE){
    int d = receivers[e];
    int p = atomicAdd(&cur[d], 1);
    perm[p] = e;
  }
}

// ---------------- per-layer node linears: 16 nodes/block, 4 nodes/wave ----------
__global__ void k_node(const float* __restrict__ s, const float* __restrict__ v,
                       const float* __restrict__ attrs,
                       const float* __restrict__ W1s, const float* __restrict__ W1v,
                       const float* __restrict__ Wscst, const float* __restrict__ Wscvt,
                       __half* __restrict__ s1, __half* __restrict__ v1,
                       float* __restrict__ scs, float* __restrict__ scv){
  __shared__ float ls[16][64];
  __shared__ float lv[16][96];
  __shared__ float la[16][4];
  int tid = threadIdx.x;
  int nb = blockIdx.x*16;   // 1250*16 = 20000 exact
  for (int i=tid;i<1024;i+=256) ls[i>>6][i&63] = s[(size_t)(nb+(i>>6))*64 + (i&63)];
  for (int i=tid;i<1536;i+=256){ int j=i/96, q=i-96*j; lv[j][q] = v[(size_t)(nb+j)*96+q]; }
  if (tid<64) la[tid>>2][tid&3] = attrs[(nb+(tid>>2))*4 + (tid&3)];
  __syncthreads();
  int w = tid>>6, q = tid&63;
  int jb = w*4;                       // this wave's 4 nodes: nb+jb .. nb+jb+3
  float laj[4][4];
  #pragma unroll
  for (int j=0;j<4;j++)
    #pragma unroll
    for (int e=0;e<4;e++) laj[j][e] = la[jb+j][e];

  // s1 = s @ W1s / 8  (loads batched x4)
  {
    float acc[4] = {0,0,0,0};
    for (int i=0;i<64;i+=4){
      float wv0 = W1s[(i+0)*64+q];
      float wv1 = W1s[(i+1)*64+q];
      float wv2 = W1s[(i+2)*64+q];
      float wv3 = W1s[(i+3)*64+q];
      #pragma unroll
      for (int j=0;j<4;j++){
        acc[j] = fmaf(ls[jb+j][i+0], wv0, acc[j]);
        acc[j] = fmaf(ls[jb+j][i+1], wv1, acc[j]);
        acc[j] = fmaf(ls[jb+j][i+2], wv2, acc[j]);
        acc[j] = fmaf(ls[jb+j][i+3], wv3, acc[j]);
      }
    }
    #pragma unroll
    for (int j=0;j<4;j++) s1[(size_t)(nb+jb+j)*64+q] = __float2half(acc[j]*0.125f);
  }
  // sc_s (two-stage, loads batched x4)
  #pragma unroll 1
  for (int o=q;o<96;o+=64){
    float t0[4]={0,0,0,0}, t1[4]={0,0,0,0}, t2[4]={0,0,0,0}, t3[4]={0,0,0,0};
    for (int i=0;i<64;i+=4){
      float4 wa = *(const float4*)(Wscst + (i+0)*384 + o*4);
      float4 wb = *(const float4*)(Wscst + (i+1)*384 + o*4);
      float4 wc = *(const float4*)(Wscst + (i+2)*384 + o*4);
      float4 wd = *(const float4*)(Wscst + (i+3)*384 + o*4);
      #pragma unroll
      for (int j=0;j<4;j++){
        float s0 = ls[jb+j][i+0], s1v = ls[jb+j][i+1];
        float s2 = ls[jb+j][i+2], s3 = ls[jb+j][i+3];
        t0[j] = fmaf(s0, wa.x, t0[j]); t1[j] = fmaf(s0, wa.y, t1[j]);
        t2[j] = fmaf(s0, wa.z, t2[j]); t3[j] = fmaf(s0, wa.w, t3[j]);
        t0[j] = fmaf(s1v, wb.x, t0[j]); t1[j] = fmaf(s1v, wb.y, t1[j]);
        t2[j] = fmaf(s1v, wb.z, t2[j]); t3[j] = fmaf(s1v, wb.w, t3[j]);
        t0[j] = fmaf(s2, wc.x, t0[j]); t1[j] = fmaf(s2, wc.y, t1[j]);
        t2[j] = fmaf(s2, wc.z, t2[j]); t3[j] = fmaf(s2, wc.w, t3[j]);
        t0[j] = fmaf(s3, wd.x, t0[j]); t1[j] = fmaf(s3, wd.y, t1[j]);
        t2[j] = fmaf(s3, wd.z, t2[j]); t3[j] = fmaf(s3, wd.w, t3[j]);
      }
    }
    #pragma unroll
    for (int j=0;j<4;j++){
      float acc = t0[j]*laj[j][0] + t1[j]*laj[j][1]
                + t2[j]*laj[j][2] + t3[j]*laj[j][3];
      scs[(size_t)(nb+jb+j)*96+o] = acc*0.0625f;
    }
  }
  // v1 (loads batched x4)
  #pragma unroll 1
  for (int f=q;f<96;f+=64){
    int op=f/3, c=f-3*op;
    float acc[4] = {0,0,0,0};
    for (int i=0;i<32;i+=4){
      float wv0 = W1v[(i+0)*32+op];
      float wv1 = W1v[(i+1)*32+op];
      float wv2 = W1v[(i+2)*32+op];
      float wv3 = W1v[(i+3)*32+op];
      #pragma unroll
      for (int j=0;j<4;j++){
        acc[j] = fmaf(lv[jb+j][(i+0)*3+c], wv0, acc[j]);
        acc[j] = fmaf(lv[jb+j][(i+1)*3+c], wv1, acc[j]);
        acc[j] = fmaf(lv[jb+j][(i+2)*3+c], wv2, acc[j]);
        acc[j] = fmaf(lv[jb+j][(i+3)*3+c], wv3, acc[j]);
      }
    }
    #pragma unroll
    for (int j=0;j<4;j++) v1[(size_t)(nb+jb+j)*96+f] = __float2half(acc[j]*0.17677669529663687f);
  }
  // sc_v (two-stage, loads batched x4)
  #pragma unroll 1
  for (int f=q;f<96;f+=64){
    int op=f/3, c=f-3*op;
    float t0[4]={0,0,0,0}, t1[4]={0,0,0,0}, t2[4]={0,0,0,0}, t3[4]={0,0,0,0};
    for (int i=0;i<32;i+=4){
      float4 wa = *(const float4*)(Wscvt + (i+0)*128 + op*4);
      float4 wb = *(const float4*)(Wscvt + (i+1)*128 + op*4);
      float4 wc = *(const float4*)(Wscvt + (i+2)*128 + op*4);
      float4 wd = *(const float4*)(Wscvt + (i+3)*128 + op*4);
      #pragma unroll
      for (int j=0;j<4;j++){
        float v0 = lv[jb+j][(i+0)*3+c], v1v = lv[jb+j][(i+1)*3+c];
        float v2 = lv[jb+j][(i+2)*3+c], v3 = lv[jb+j][(i+3)*3+c];
        t0[j] = fmaf(v0, wa.x, t0[j]); t1[j] = fmaf(v0, wa.y, t1[j]);
        t2[j] = fmaf(v0, wa.z, t2[j]); t3[j] = fmaf(v0, wa.w, t3[j]);
        t0[j] = fmaf(v1v, wb.x, t0[j]); t1[j] = fmaf(v1v, wb.y, t1[j]);
        t2[j] = fmaf(v1v, wb.z, t2[j]); t3[j] = fmaf(v1v, wb.w, t3[j]);
        t0[j] = fmaf(v2, wc.x, t0[j]); t1[j] = fmaf(v2, wc.y, t1[j]);
        t2[j] = fmaf(v2, wc.z, t2[j]); t3[j] = fmaf(v2, wc.w, t3[j]);
        t0[j] = fmaf(v3, wd.x, t0[j]); t1[j] = fmaf(v3, wd.y, t1[j]);
        t2[j] = fmaf(v3, wd.z, t2[j]); t3[j] = fmaf(v3, wd.w, t3[j]);
      }
    }
    #pragma unroll
    for (int j=0;j<4;j++){
      float acc = t0[j]*laj[j][0] + t1[j]*laj[j][1]
                + t2[j]*laj[j][2] + t3[j]*laj[j][3];
      scv[(size_t)(nb+jb+j)*96+f] = acc*0.08838834764831845f;
    }
  }
}

// ---------------- edge MLP: persistent-weight multi-tile version -----------------
// Round-11: rb staged from the precomputed table (coalesced, all 256 threads)
// when rbp != null -- removes the 64-lane trig segment entirely. Fallback keeps
// the round-10 in-kernel bessel for small-workspace configs.
#define R2S 196
#define HT2S 68
__launch_bounds__(256, 4)
__global__ void k_edgew(const float* __restrict__ dRp, const float* __restrict__ rbp,
                        const int* __restrict__ row, int n0, int n1, int cap,
                        const float* __restrict__ R0, const float* __restrict__ R1,
                        const float* __restrict__ R2,
                        __half* __restrict__ wbuf){
  __shared__ __align__(16) f16x2 hT2[32*HT2S];  // 8.7 KB: [kpair][e] stride 68; rb staging (fp32 view) / h1 / h2
  __shared__ __align__(16) float r0s[512];      // 2 KB: R0 fp32
  __shared__ __align__(16) f16x2 wgt2[32*R2S];  // 24.5 KB: R2 k-pairs, persistent
  int tid = threadIdx.x;
  int p0 = row[n0], p1 = row[n1];
  int vmax = p1 - p0; if (vmax > cap) vmax = cap;
  int ntiles = (vmax + 63) >> 6;

  int eg = tid & 15, e0 = eg*4;
  int jg = tid >> 4, j0 = jg*4;
  int wv = tid >> 6;
  int ln = tid & 63;
  int col = ln & 15;
  int quad = ln >> 4;

  // ---- persistent staging (once per block) ----
  if (tid < 128) ((float4*)r0s)[tid] = ((const float4*)R0)[tid];
  for (int i=tid; i<6144; i+=256){
    int kp = i/192, o = i-192*kp;
    wgt2[kp*R2S + o] = pack2f(R2[(2*kp)*192 + o], R2[(2*kp+1)*192 + o]);
  }
  // R1 A-frags direct from global into registers (was LDS wgt1)
  union { uint4 u; f16x8 v; } rA0, rA1;
  {
    int jA = 16*wv + col;
    rA0.u.x = packu2f(R1[(8*quad+0)*64 + jA], R1[(8*quad+1)*64 + jA]);
    rA0.u.y = packu2f(R1[(8*quad+2)*64 + jA], R1[(8*quad+3)*64 + jA]);
    rA0.u.z = packu2f(R1[(8*quad+4)*64 + jA], R1[(8*quad+5)*64 + jA]);
    rA0.u.w = packu2f(R1[(8*quad+6)*64 + jA], R1[(8*quad+7)*64 + jA]);
    rA1.u.x = packu2f(R1[(32+8*quad+0)*64 + jA], R1[(32+8*quad+1)*64 + jA]);
    rA1.u.y = packu2f(R1[(32+8*quad+2)*64 + jA], R1[(32+8*quad+3)*64 + jA]);
    rA1.u.z = packu2f(R1[(32+8*quad+4)*64 + jA], R1[(32+8*quad+5)*64 + jA]);
    rA1.u.w = packu2f(R1[(32+8*quad+6)*64 + jA], R1[(32+8*quad+7)*64 + jA]);
  }
  // visibility of r0s/wgt2 covered by the loop-top barrier of the first tile

  for (int tile = blockIdx.x; tile < ntiles; tile += gridDim.x){
    int tbase = tile*64;
    int vcnt = vmax - tbase; if (vcnt > 64) vcnt = 64;

    __syncthreads();   // [A] staging visible / prev tile's phase-C hT2 reads done
    // stage rb for the 64 edges into hT2 region (fp32 view, rows k<8)
    float* hTf = (float*)hT2;
    if (rbp){
      #pragma unroll
      for (int rep=0; rep<2; rep++){
        int idx = tid + rep*256;        // 0..511
        int k = idx>>6, e = idx&63;
        float v = (e < vcnt) ? rbp[(size_t)k*NE + (p0 + tbase + e)] : 0.0f;
        hTf[k*HT2S + e] = v;
      }
    } else if (tid < 64){
      float rbv[8];
      if (tid < vcnt){
        bessel8(dRp, p0 + tbase + tid, rbv);
      } else {
        #pragma unroll
        for (int k=0;k<8;k++) rbv[k]=0.0f;
      }
      #pragma unroll
      for (int k=0;k<8;k++) hTf[k*HT2S + tid] = rbv[k];
    }
    __syncthreads();   // [B]

    // read rb tile into regs (before overwriting hT2 with h1 pairs)
    float rb[8][4];
    {
      const float4* hTf4 = (const float4*)hTf;
      #pragma unroll
      for (int k=0;k<8;k++){
        float4 v = hTf4[k*17 + eg];
        rb[k][0]=v.x; rb[k][1]=v.y; rb[k][2]=v.z; rb[k][3]=v.w;
      }
    }
    // phase A: h1 tile (fp32 math, tiny K=8)
    float a[4][4];
    #pragma unroll
    for (int j=0;j<4;j++)
      #pragma unroll
      for (int e=0;e<4;e++) a[j][e]=0.0f;
    {
      const float4* r0s4 = (const float4*)r0s;
      #pragma unroll
      for (int k=0;k<8;k++){
        float4 w = r0s4[k*16 + jg];
        float wj[4] = {w.x,w.y,w.z,w.w};
        #pragma unroll
        for (int j=0;j<4;j++)
          #pragma unroll
          for (int e=0;e<4;e++) a[j][e] = fmaf(rb[k][e], wj[j], a[j][e]);
      }
    }
    #pragma unroll
    for (int j=0;j<4;j++)
      #pragma unroll
      for (int e=0;e<4;e++) a[j][e] = silu_f(a[j][e]*0.3535533905932738f);
    __syncthreads();   // [C] all rb reads complete
    // write h1 as k-pairs: rows j0/2, j0/2+1 of hT2
    #pragma unroll
    for (int jp=0;jp<2;jp++){
      union {uint4 u; f16x2 h[4];} U;
      #pragma unroll
      for (int e=0;e<4;e++) U.h[e] = pack2f(a[2*jp][e], a[2*jp+1][e]);
      *(uint4*)(hT2 + (j0/2 + jp)*HT2S + e0) = U.u;
    }
    __syncthreads();   // [D]

    // phase B via MFMA: wave wv owns j-tile [16*wv,16*wv+16), loops 4 e-tiles.
    {
      const unsigned int* hT2u = (const unsigned int*)hT2;
      f32x4 accB[4];
      #pragma unroll
      for (int nt=0; nt<4; nt++){
        union { uint4 u; f16x8 v; } B0, B1;
        int eB = 16*nt + col;
        B0.u.x = hT2u[(4*quad+0)*HT2S + eB];
        B0.u.y = hT2u[(4*quad+1)*HT2S + eB];
        B0.u.z = hT2u[(4*quad+2)*HT2S + eB];
        B0.u.w = hT2u[(4*quad+3)*HT2S + eB];
        B1.u.x = hT2u[(16+4*quad+0)*HT2S + eB];
        B1.u.y = hT2u[(16+4*quad+1)*HT2S + eB];
        B1.u.z = hT2u[(16+4*quad+2)*HT2S + eB];
        B1.u.w = hT2u[(16+4*quad+3)*HT2S + eB];
        f32x4 acc = {0.0f,0.0f,0.0f,0.0f};
        acc = __builtin_amdgcn_mfma_f32_16x16x32_f16(rA0.v, B0.v, acc, 0, 0, 0);
        acc = __builtin_amdgcn_mfma_f32_16x16x32_f16(rA1.v, B1.v, acc, 0, 0, 0);
        accB[nt] = acc;
      }
      __syncthreads();   // [E] all h1 (hT2) reads complete
      // silu + pack + write h2^T as k-pairs
      #pragma unroll
      for (int nt=0; nt<4; nt++){
        float h0 = silu_f(accB[nt][0]*0.125f);
        float h1v = silu_f(accB[nt][1]*0.125f);
        float h2v = silu_f(accB[nt][2]*0.125f);
        float h3v = silu_f(accB[nt][3]*0.125f);
        hT2[(8*wv + 2*quad + 0)*HT2S + 16*nt + col] = pack2f(h0, h1v);
        hT2[(8*wv + 2*quad + 1)*HT2S + 16*nt + col] = pack2f(h2v, h3v);
      }
    }
    __syncthreads();   // [F] h2 visible

    // phase C via MFMA: wave wv handles edges [16*wv, 16*wv+16)
    {
      const unsigned int* hT2u = (const unsigned int*)hT2;
      const unsigned int* wgt2u = (const unsigned int*)wgt2;
      int eA = 16*wv + col;     // A's m index
      union { uint4 u; f16x8 v; } A0, A1;
      A0.u.x = hT2u[(4*quad+0)*HT2S + eA];
      A0.u.y = hT2u[(4*quad+1)*HT2S + eA];
      A0.u.z = hT2u[(4*quad+2)*HT2S + eA];
      A0.u.w = hT2u[(4*quad+3)*HT2S + eA];
      A1.u.x = hT2u[(16+4*quad+0)*HT2S + eA];
      A1.u.y = hT2u[(16+4*quad+1)*HT2S + eA];
      A1.u.z = hT2u[(16+4*quad+2)*HT2S + eA];
      A1.u.w = hT2u[(16+4*quad+3)*HT2S + eA];
      int erow = 16*wv + 4*quad;           // D rows: erow+0..3
      #pragma unroll
      for (int ot=0; ot<12; ot++){
        int o = 16*ot + col;
        union { uint4 u; f16x8 v; } B0, B1;
        B0.u.x = wgt2u[(4*quad+0)*R2S + o];
        B0.u.y = wgt2u[(4*quad+1)*R2S + o];
        B0.u.z = wgt2u[(4*quad+2)*R2S + o];
        B0.u.w = wgt2u[(4*quad+3)*R2S + o];
        B1.u.x = wgt2u[(16+4*quad+0)*R2S + o];
        B1.u.y = wgt2u[(16+4*quad+1)*R2S + o];
        B1.u.z = wgt2u[(16+4*quad+2)*R2S + o];
        B1.u.w = wgt2u[(16+4*quad+3)*R2S + o];
        f32x4 acc = {0.0f,0.0f,0.0f,0.0f};
        acc = __builtin_amdgcn_mfma_f32_16x16x32_f16(A0.v, B0.v, acc, 0, 0, 0);
        acc = __builtin_amdgcn_mfma_f32_16x16x32_f16(A1.v, B1.v, acc, 0, 0, 0);
        // direct predicated stores (uniform-true branch for full tiles)
        #pragma unroll
        for (int r=0;r<4;r++){
          int eib = erow + r;
          if (eib < vcnt)
            wbuf[(size_t)(tbase+eib)*192 + o] = __float2half(acc[r]);
        }
      }
    }
  }
}

// ---------------- gather: role-split + 8-deep load batching, spill-free ---------
__launch_bounds__(128, 4)
__global__ void k_gather(const __half* __restrict__ wbuf,
                         const int* __restrict__ row, const int* __restrict__ sendp,
                         const float* __restrict__ sh1,
                         const __half* __restrict__ s1, const __half* __restrict__ v1,
                         int n0, int cap,
                         float* __restrict__ a_s, float* __restrict__ a_v){
  __shared__ int   srcs[ECAP];
  __shared__ float sh1r[ECAP*3];
  int n = n0 + blockIdx.x;
  int t = threadIdx.x;
  int pc0 = row[n0];
  int p0 = row[n], p1 = row[n+1];
  int pmax = pc0 + cap; if (p1 > pmax) p1 = pmax;

  int iv = (t - 64) >> 1;          // 0..31 for vrole
  bool even = ((t & 1) == 0);

  float acs = 0.0f, av0 = 0.0f, av1 = 0.0f, av2 = 0.0f;

  for (int base = p0; base < p1; base += ECAP){
    int bc = p1 - base; if (bc > ECAP) bc = ECAP;
    __syncthreads();   // protect LDS reuse across batches
    if (t < bc){
      srcs[t] = sendp[base + t];
      sh1r[3*t+0] = sh1[3*(base+t)+0];
      sh1r[3*t+1] = sh1[3*(base+t)+1];
      sh1r[3*t+2] = sh1[3*(base+t)+2];
    }
    __syncthreads();
    const __half* wb = wbuf + (size_t)(base - pc0)*192;
    if (t < 64){
      int o = t;
      int j = 0;
      for (; j + 8 <= bc; j += 8){
        float sv[8], w1[8], w2[8];
        #pragma unroll
        for (int u=0;u<8;u++){
          const __half* wr = wb + (j+u)*192;
          sv[u] = __half2float(s1[(size_t)srcs[j+u]*64 + o]);
          w1[u] = __half2float(wr[o]);
          w2[u] = __half2float(wr[64 + o]);
        }
        #pragma unroll
        for (int u=0;u<8;u++){
          acs = fmaf(w1[u], sv[u], acs);
          float uu = w2[u] * sv[u];
          av0 = fmaf(uu, sh1r[3*(j+u)+0], av0);
          av1 = fmaf(uu, sh1r[3*(j+u)+1], av1);
          av2 = fmaf(uu, sh1r[3*(j+u)+2], av2);
        }
      }
      for (; j < bc; ++j){
        const __half* wr = wb + j*192;
        float sv = __half2float(s1[(size_t)srcs[j]*64 + o]);
        float w1v = __half2float(wr[o]);
        float w2v = __half2float(wr[64 + o]);
        acs = fmaf(w1v, sv, acs);
        float uu = w2v * sv;
        av0 = fmaf(uu, sh1r[3*j+0], av0);
        av1 = fmaf(uu, sh1r[3*j+1], av1);
        av2 = fmaf(uu, sh1r[3*j+2], av2);
      }
    } else {
      int j = 0;
      for (; j + 8 <= bc; j += 8){
        float v0[8], vc1[8], vc2[8], w3[8], w4[8];
        #pragma unroll
        for (int u=0;u<8;u++){
          const __half* wr = wb + (j+u)*192;
          const __half* vr = v1 + (size_t)srcs[j+u]*96 + 3*iv;
          v0[u]  = __half2float(vr[0]);
          vc1[u] = __half2float(vr[1]);
          vc2[u] = __half2float(vr[2]);
          w3[u]  = __half2float(wr[128 + iv]);
          w4[u]  = __half2float(wr[160 + iv]);
        }
        #pragma unroll
        for (int u=0;u<8;u++){
          if (even){
            float dv = v0[u]*sh1r[3*(j+u)+0] + vc1[u]*sh1r[3*(j+u)+1] + vc2[u]*sh1r[3*(j+u)+2];
            acs = fmaf(w4[u], dv, acs);
            av0 = fmaf(w3[u], v0[u], av0);
          } else {
            av1 = fmaf(w3[u], vc1[u], av1);
            av2 = fmaf(w3[u], vc2[u], av2);
          }
        }
      }
      for (; j < bc; ++j){
        const __half* wr = wb + j*192;
        const __half* vr = v1 + (size_t)srcs[j]*96 + 3*iv;
        float v0 = __half2float(vr[0]);
        float vc1 = __half2float(vr[1]);
        float vc2 = __half2float(vr[2]);
        float w3 = __half2float(wr[128 + iv]);
        if (even){
          float w4 = __half2float(wr[160 + iv]);
          float dv = v0*sh1r[3*j+0] + vc1*sh1r[3*j+1] + vc2*sh1r[3*j+2];
          acs = fmaf(w4, dv, acs);
          av0 = fmaf(w3, v0, av0);
        } else {
          av1 = fmaf(w3, vc1, av1);
          av2 = fmaf(w3, vc2, av2);
        }
      }
    }
  }

  if (t < 64){
    a_s[(size_t)n*96 + t] = 0.03125f*acs;              // (1/8)*(1/sqrt(16))
    a_v[(size_t)n*288 + 3*t + 0] = 0.03125f*av0;
    a_v[(size_t)n*288 + 3*t + 1] = 0.03125f*av1;
    a_v[(size_t)n*288 + 3*t + 2] = 0.03125f*av2;
  } else if (even){
    a_s[(size_t)n*96 + 64 + iv] = 0.018042195912175807f*acs;   // 0.03125/sqrt(3)
    a_v[(size_t)n*288 + 192 + 3*iv + 0] = 0.03125f*av0;
  } else {
    a_v[(size_t)n*288 + 192 + 3*iv + 1] = 0.03125f*av1;
    a_v[(size_t)n*288 + 192 + 3*iv + 2] = 0.03125f*av2;
  }
}

// ---------------- fallback: atomic edge kernel (only if ws too small) ----------------
__device__ __forceinline__ void mlp_h2(const float* __restrict__ R0,
                                       const float* lR1, const float rb[8],
                                       float h2[64]){
  float h1[64];
  #pragma unroll
  for (int j=0;j<64;j+=4){
    float a0=0,a1=0,a2=0,a3=0;
    #pragma unroll
    for (int k=0;k<8;k++){
      float r = rb[k];
      const float* wp = R0 + k*64 + j;
      a0 = fmaf(r, wp[0], a0); a1 = fmaf(r, wp[1], a1);
      a2 = fmaf(r, wp[2], a2); a3 = fmaf(r, wp[3], a3);
    }
    h1[j+0]=silu_f(a0*0.3535533905932738f);
    h1[j+1]=silu_f(a1*0.3535533905932738f);
    h1[j+2]=silu_f(a2*0.3535533905932738f);
    h1[j+3]=silu_f(a3*0.3535533905932738f);
  }
  #pragma unroll
  for (int j=0;j<64;j+=4){
    float a0=0,a1=0,a2=0,a3=0;
    #pragma unroll
    for (int k=0;k<64;k++){
      float h = h1[k];
      float4 w4 = *(const float4*)(lR1 + k*64 + j);
      a0 = fmaf(h,w4.x,a0); a1 = fmaf(h,w4.y,a1);
      a2 = fmaf(h,w4.z,a2); a3 = fmaf(h,w4.w,a3);
    }
    h2[j+0]=silu_f(a0*0.125f);
    h2[j+1]=silu_f(a1*0.125f);
    h2[j+2]=silu_f(a2*0.125f);
    h2[j+3]=silu_f(a3*0.125f);
  }
}

__launch_bounds__(256, 2)
__global__ void k_edge(const float* __restrict__ dR, const float* __restrict__ sh1,
                       const int* __restrict__ senders, const int* __restrict__ receivers,
                       const __half* __restrict__ s1, const __half* __restrict__ v1,
                       const float* __restrict__ R0, const float* __restrict__ R1,
                       const float* __restrict__ R2,
                       float* __restrict__ a_s, float* __restrict__ a_v){
  __shared__ __align__(16) float lR1[64*64];
  __shared__ __align__(16) float lR2[64*192];
  int tid = threadIdx.x;
  for (int i=tid;i<4096;i+=256)  lR1[i]=R1[i];
  for (int i=tid;i<12288;i+=256) lR2[i]=R2[i];
  __syncthreads();
  int e = blockIdx.x*256 + tid;
  float rb[8];
  bessel8(dR, e, rb);
  float h2[64];
  mlp_h2(R0, lR1, rb, h2);
  int src = senders[e], dst = receivers[e];
  float sx=sh1[3*e+0], sy=sh1[3*e+1], sz=sh1[3*e+2];
  const __half* srow = s1 + (size_t)src*64;
  const __half* vrow = v1 + (size_t)src*96;
  float* asr = a_s + (size_t)dst*96;
  float* avr = a_v + (size_t)dst*288;
  #pragma unroll 1
  for (int o=0;o<64;o+=4){
    float w10=0,w11=0,w12=0,w13=0, w20=0,w21=0,w22=0,w23=0;
    #pragma unroll
    for (int k=0;k<64;k++){
      float h = h2[k];
      float4 wa = *(const float4*)(lR2 + k*192 + o);
      float4 wb = *(const float4*)(lR2 + k*192 + 64 + o);
      w10=fmaf(h,wa.x,w10); w11=fmaf(h,wa.y,w11); w12=fmaf(h,wa.z,w12); w13=fmaf(h,wa.w,w13);
      w20=fmaf(h,wb.x,w20); w21=fmaf(h,wb.y,w21); w22=fmaf(h,wb.z,w22); w23=fmaf(h,wb.w,w23);
    }
    float sev[4] = {__half2float(srow[o+0]), __half2float(srow[o+1]),
                    __half2float(srow[o+2]), __half2float(srow[o+3])};
    float w1a[4] = {w10,w11,w12,w13};
    float w2a[4] = {w20,w21,w22,w23};
    #pragma unroll
    for (int u=0;u<4;u++){
      atomicAdd(asr+o+u, 0.03125f*w1a[u]*sev[u]);
      float m = 0.03125f*w2a[u]*sev[u];
      atomicAdd(avr+(o+u)*3+0, m*sx);
      atomicAdd(avr+(o+u)*3+1, m*sy);
      atomicAdd(avr+(o+u)*3+2, m*sz);
    }
  }
  #pragma unroll 1
  for (int i0=0;i0<32;i0+=4){
    float w30=0,w31=0,w32=0,w33=0, w40=0,w41=0,w42=0,w43=0;
    #pragma unroll
    for (int k=0;k<64;k++){
      float h = h2[k];
      float4 wa = *(const float4*)(lR2 + k*192 + 128 + i0);
      float4 wb = *(const float4*)(lR2 + k*192 + 160 + i0);
      w30=fmaf(h,wa.x,w30); w31=fmaf(h,wa.y,w31); w32=fmaf(h,wa.z,w32); w33=fmaf(h,wa.w,w33);
      w40=fmaf(h,wb.x,w40); w41=fmaf(h,wb.y,w41); w42=fmaf(h,wb.z,w42); w43=fmaf(h,wb.w,w43);
    }
    float w3a[4] = {w30,w31,w32,w33};
    float w4a[4] = {w40,w41,w42,w43};
    #pragma unroll
    for (int u=0;u<4;u++){
      int i = i0+u;
      float vx=__half2float(vrow[3*i+0]), vy=__half2float(vrow[3*i+1]), vz=__half2float(vrow[3*i+2]);
      float dv = vx*sx + vy*sy + vz*sz;
      atomicAdd(asr+64+i, 0.018042195912175807f*w4a[u]*dv);
      float m3 = 0.03125f*w3a[u];
      atomicAdd(avr+(64+i)*3+0, m3*vx);
      atomicAdd(avr+(64+i)*3+1, m3*vy);
      atomicAdd(avr+(64+i)*3+2, m3*vz);
    }
  }
}

// ---------------- per-layer output transform: o_s, o_v, gating ----------------
// Round-11: W2s/W2v loads batched x4 (same latency medicine as k_node/k_gather).
__launch_bounds__(256, 4)
__global__ void k_out(const float* __restrict__ a_s, const float* __restrict__ a_v,
                      const float* __restrict__ scs, const float* __restrict__ scv,
                      const float* __restrict__ W2s, const float* __restrict__ W2v,
                      float* __restrict__ s_out, float* __restrict__ v_out){
  __shared__ float las[16][96];
  __shared__ float lav[16][288];
  __shared__ float los[16][96];
  int tid = threadIdx.x;
  int nb = blockIdx.x*16;   // 1250*16 = 20000 exact
  for (int i=tid;i<1536;i+=256){ int j=i/96,  q=i-96*j;  las[j][q] = a_s[(size_t)(nb+j)*96 +q]; }
  for (int i=tid;i<4608;i+=256){ int j=i/288, q=i-288*j; lav[j][q] = a_v[(size_t)(nb+j)*288+q]; }
  __syncthreads();
  int w = tid>>6, q = tid&63;
  int jb = w*4;                       // this wave's 4 nodes: nb+jb .. nb+jb+3

  // o_s = a_s @ W2s * scale + scs   (outputs o = q and q+64, wave-private los)
  #pragma unroll 1
  for (int o=q; o<96; o+=64){
    float acc[4] = {0,0,0,0};
    for (int i=0;i<96;i+=4){
      float w0 = W2s[(i+0)*96+o];
      float w1 = W2s[(i+1)*96+o];
      float w2 = W2s[(i+2)*96+o];
      float w3 = W2s[(i+3)*96+o];
      #pragma unroll
      for (int j=0;j<4;j++){
        acc[j] = fmaf(las[jb+j][i+0], w0, acc[j]);
        acc[j] = fmaf(las[jb+j][i+1], w1, acc[j]);
        acc[j] = fmaf(las[jb+j][i+2], w2, acc[j]);
        acc[j] = fmaf(las[jb+j][i+3], w3, acc[j]);
      }
    }
    #pragma unroll
    for (int j=0;j<4;j++)
      los[jb+j][o] = acc[j]*0.10206207261596575f + scs[(size_t)(nb+jb+j)*96+o];
  }
  __syncthreads();   // (wave-private in fact; barrier keeps LDS ordering simple)

  // s_out = silu(o_s[:64])
  #pragma unroll
  for (int j=0;j<4;j++) s_out[(size_t)(nb+jb+j)*64+q] = silu_f(los[jb+j][q]);

  // o_v = a_v @ W2v * scale + scv, gated by silu(o_s[64+op])
  #pragma unroll 1
  for (int f=q; f<96; f+=64){
    int op=f/3, c=f-3*op;
    float acc[4] = {0,0,0,0};
    for (int i=0;i<96;i+=4){
      float w0 = W2v[(i+0)*32+op];
      float w1 = W2v[(i+1)*32+op];
      float w2 = W2v[(i+2)*32+op];
      float w3 = W2v[(i+3)*32+op];
      #pragma unroll
      for (int j=0;j<4;j++){
        acc[j] = fmaf(lav[jb+j][(i+0)*3+c], w0, acc[j]);
        acc[j] = fmaf(lav[jb+j][(i+1)*3+c], w1, acc[j]);
        acc[j] = fmaf(lav[jb+j][(i+2)*3+c], w2, acc[j]);
        acc[j] = fmaf(lav[jb+j][(i+3)*3+c], w3, acc[j]);
      }
    }
    #pragma unroll
    for (int j=0;j<4;j++){
      float ov = acc[j]*0.10206207261596575f + scv[(size_t)(nb+jb+j)*96+f];
      float g = silu_f(los[jb+j][64+op]);
      v_out[(size_t)(nb+jb+j)*96+f] = ov*g;
    }
  }
}

// ---------------- final heads: energy + mags ----------------
__global__ void k_final(const float* __restrict__ s, const float* __restrict__ nodes,
                        const int* __restrict__ n_node,
                        const float* __restrict__ Wen1, const float* __restrict__ Wen2,
                        const float* __restrict__ Wm1, const float* __restrict__ Wm2,
                        const float* __restrict__ scale_occ, const float* __restrict__ shift_occ,
                        const float* __restrict__ escale, const float* __restrict__ eshift,
                        float* __restrict__ out){
  __shared__ float eacc[NG];
  __shared__ int goff[NG+1];
  int tid = threadIdx.x;
  if (tid < NG) eacc[tid] = 0.0f;
  if (tid == 0){
    int c = 0; goff[0] = 0;
    for (int g=0; g<NG; g++){ c += n_node[g]; goff[g+1] = c; }
  }
  __syncthreads();
  int n = blockIdx.x*256 + tid;
  if (n < NN){
    float sv[64];
    #pragma unroll
    for (int i=0;i<64;i++) sv[i]=s[(size_t)n*64+i];
    float en=0.0f, m0=0.0f, m1=0.0f;
    #pragma unroll 1
    for (int jj=0;jj<32;jj++){
      float he=0.0f, hm=0.0f;
      #pragma unroll
      for (int i=0;i<64;i++){
        he = fmaf(sv[i], Wen1[i*32+jj], he);
        hm = fmaf(sv[i], Wm1[i*32+jj], hm);
      }
      he *= 0.125f; hm *= 0.125f;
      en = fmaf(he, Wen2[jj], en);
      m0 = fmaf(hm, Wm2[jj*2+0], m0);
      m1 = fmaf(hm, Wm2[jj*2+1], m1);
    }
    const float INVS32 = 0.17677669529663687f;
    en *= INVS32; m0 *= INVS32; m1 *= INVS32;
    en = escale[0]*en + eshift[0];
    int g = 0;
    for (int gg=0; gg<NG; gg++) if (n >= goff[gg+1]) g = gg+1;
    atomicAdd(&eacc[g], en);
    float nx=nodes[n*4+0], ny=nodes[n*4+1], nz=nodes[n*4+2];
    float sc0 = nx*scale_occ[0] + ny*scale_occ[2] + nz*scale_occ[4];
    float sc1 = nx*scale_occ[1] + ny*scale_occ[3] + nz*scale_occ[5];
    float sf0 = nx*shift_occ[0] + ny*shift_occ[2] + nz*shift_occ[4];
    float sf1 = nx*shift_occ[1] + ny*shift_occ[3] + nz*shift_occ[5];
    out[16 + n*2 + 0] = sc0*m0 + sf0;
    out[16 + n*2 + 1] = sc1*m1 + sf1;
  }
  __syncthreads();
  if (tid < NG) atomicAdd(&out[tid], eacc[tid]);
}

extern "C" void kernel_launch(void* const* d_in, const int* in_sizes, int n_in,
                              void* d_out, int out_size, void* d_ws, size_t ws_size,
                              hipStream_t stream){
  const float* nodes   = (const float*)d_in[0];
  const float* dR      = (const float*)d_in[1];
  const int*  senders  = (const int*)d_in[2];
  const int*  receivers= (const int*)d_in[3];
  const int*  n_node   = (const int*)d_in[4];
  const float* W_embed = (const float*)d_in[5];
  const float* W_sc_s  = (const float*)d_in[6];
  const float* W_sc_v  = (const float*)d_in[7];
  const float* W_l1_s  = (const float*)d_in[8];
  const float* W_l1_v  = (const float*)d_in[9];
  const float* Wr0     = (const float*)d_in[10];
  const float* Wr1     = (const float*)d_in[11];
  const float* Wr2     = (const float*)d_in[12];
  const float* W_l2_s  = (const float*)d_in[13];
  const float* W_l2_v  = (const float*)d_in[14];
  const float* W_en1   = (const float*)d_in[15];
  const float* W_en2   = (const float*)d_in[16];
  const float* W_mag1  = (const float*)d_in[17];
  const float* W_mag2  = (const float*)d_in[18];
  const float* scale_occ = (const float*)d_in[19];
  const float* shift_occ = (const float*)d_in[20];
  const float* escale  = (const float*)d_in[21];
  const float* eshift  = (const float*)d_in[22];
  float* out = (float*)d_out;
  float* ws  = (float*)d_ws;

  // ---- workspace map (float-index offsets) ----
  float*  sh1  = ws + 0;         // NE*3 f32 (PERMUTED order in fast path)
  float*  sA   = ws + 960000;    // NN*64 f32
  float*  vA   = ws + 2240000;   // NN*96 f32
  __half* s1h  = (__half*)(ws + 4160000);   // NN*64 halves = 640,000 f32
  __half* v1h  = (__half*)(ws + 4800000);   // NN*96 halves = 960,000 f32
  float*  dRp  = ws + 5760000;   // NE*3 f32 permuted dR = 960,000 f32
  int*    sendp= (int*)(ws + 6720000);      // NE ints = 320,000 -> ends 7,040,000
  float*  Wst  = ws + 7040000;   // 2*24576 = 49,152 transposed W_sc_s
  float*  Wvt  = ws + 7089152;   // 2*4096  =  8,192 transposed W_sc_v -> ends 7,097,344
  float*  scs  = ws + 7360000;   // 1,920,000 f32
  float*  scv  = ws + 9280000;   // 1,920,000 f32
  float*  a_s  = ws + 11200000;  // 1,920,000 f32
  float*  a_v  = ws + 13120000;  // 5,760,000 f32 -> ends 18,880,000
  int*    cnt  = (int*)(ws + 18880000);  // 20,000
  int*    row  = (int*)(ws + 18900000);  // 20,001
  int*    cur  = (int*)(ws + 18920004);  // 20,000
  int*    perm = (int*)(ws + 18940004);  // 320,000 -> ends 19,260,004
  float*  rbp_ws = ws + 19260008;        // optional NE*8 f32 bessel table

  size_t wsf = ws_size / 4;
  // Preferred layout: rb table (2,560,000 f32) then wbuf. Adaptive: if the
  // workspace can't hold rb + full-NE wbuf, fall back to round-10 layout
  // (wbuf at 19,260,008; bessel computed in-kernel).
  size_t cap_rb = (wsf > 21820008) ? ((wsf - 21820008)*4) / 384 : 0;
  const bool use_rb = cap_rb > (size_t)NE;
  __half* wbuf;
  size_t cap_edges;
  if (use_rb){
    wbuf = (__half*)(ws + 21820008);     // 16B aligned (21,820,008*4 % 16 == 0)
    cap_edges = cap_rb;
  } else {
    wbuf = (__half*)(ws + 19260008);
    cap_edges = (wsf > 19260008) ? ((wsf - 19260008)*4) / 384 : 0;
  }
  if (cap_edges > 128) cap_edges -= 64;   // slack for 64-edge tile granularity
  const bool fast = cap_edges >= 4096;
  int cap = (int)((cap_edges > (size_t)NE) ? (size_t)NE + 8192 : cap_edges);
  // single chunk when wbuf can hold ALL edges; else the statistical heuristic.
  int npc;
  if (cap_edges > (size_t)NE){
    npc = NN;
  } else {
    npc = (int)(cap / 20); if (npc < 1) npc = 1; if (npc > NN) npc = NN;
  }
  int nchunk = (NN + npc - 1) / npc;
  float* rbp = use_rb ? rbp_ws : (float*)nullptr;

  hipMemsetAsync(vA, 0, (size_t)NN*96*sizeof(float), stream);   // v starts at zero
  hipMemsetAsync(out, 0, 16*sizeof(float), stream);             // energy accumulators

  k_embed<<<5000, 256, 0, stream>>>(nodes, W_embed, sA);
  k_wt<<<225, 256, 0, stream>>>(W_sc_s, W_sc_v, Wst, Wvt);

  if (fast){
    hipMemsetAsync(cnt, 0, NN*sizeof(int), stream);
    k_hist<<<1250, 256, 0, stream>>>(receivers, cnt);
    k_scan<<<1, 1024, 0, stream>>>(cnt, row, cur);
    k_scatter<<<1250, 256, 0, stream>>>(receivers, cur, perm);
    k_prep<<<1250, 256, 0, stream>>>(dR, senders, perm, sh1, dRp, sendp, rbp);
  } else {
    k_geom<<<1250, 256, 0, stream>>>(dR, sh1);
  }

  for (int l=0; l<2; l++){
    k_node<<<1250, 256, 0, stream>>>(sA, vA, nodes,
                                     W_l1_s + l*4096, W_l1_v + l*1024,
                                     Wst + l*24576, Wvt + l*4096,
                                     s1h, v1h, scs, scv);
    if (fast){
      for (int ck=0; ck<nchunk; ck++){
        int n0 = ck*npc;
        int n1 = n0 + npc; if (n1 > NN) n1 = NN;
        int cover = (n1-n0)*17 + 4096; if (cover > cap) cover = cap;
        int ntile_ub = (cover+63)/64;
        int grid = ntile_ub < 1024 ? ntile_ub : 1024;   // 4 blocks/CU residency
        k_edgew<<<grid, 256, 0, stream>>>(dRp, rbp, row, n0, n1, cap,
                                       Wr0 + l*512, Wr1 + l*4096, Wr2 + l*12288, wbuf);
        k_gather<<<n1-n0, 128, 0, stream>>>(wbuf, row, sendp, sh1, s1h, v1h,
                                            n0, cap, a_s, a_v);
      }
    } else {
      hipMemsetAsync(a_s, 0, (size_t)NN*384*sizeof(float), stream);  // a_s+a_v contiguous
      k_edge<<<1250, 256, 0, stream>>>(dR, sh1, senders, receivers, s1h, v1h,
                                       Wr0 + l*512, Wr1 + l*4096, Wr2 + l*12288,
                                       a_s, a_v);
    }
    // writes back into sA/vA (safe: k_out reads only a_s/a_v/scs/scv)
    k_out<<<1250, 256, 0, stream>>>(a_s, a_v, scs, scv,
                                    W_l2_s + l*9216, W_l2_v + l*3072,
                                    sA, vA);
  }
  k_final<<<79, 256, 0, stream>>>(sA, nodes, n_node, W_en1, W_en2, W_mag1, W_mag2,
                                  scale_occ, shift_occ, escale, eshift, out);
}

// Round 12
// 602.336 us; speedup vs baseline: 1.6296x; 1.6296x over previous
//
#include <hip/hip_runtime.h>
#include <hip/hip_fp16.h>
#include <math.h>

#define NN 20000
#define NE 320000
#define NG 16
#define ECAP 48   // edges staged per batch in k_gather (deg ~16+-4, max ~40)

typedef _Float16 f16x2 __attribute__((ext_vector_type(2)));
typedef _Float16 f16x8 __attribute__((ext_vector_type(8)));
typedef float    f32x4 __attribute__((ext_vector_type(4)));

__device__ __forceinline__ float dot2f(f16x2 a, f16x2 b, float c){
#if defined(__has_builtin)
#if __has_builtin(__builtin_amdgcn_fdot2)
  return __builtin_amdgcn_fdot2(a, b, c, false);
#else
  return c + (float)a.x*(float)b.x + (float)a.y*(float)b.y;
#endif
#else
  return c + (float)a.x*(float)b.x + (float)a.y*(float)b.y;
#endif
}

__device__ __forceinline__ f16x2 pack2f(float a, float b){
  f16x2 r; r.x = (_Float16)a; r.y = (_Float16)b; return r;
}

__device__ __forceinline__ unsigned packu2f(float a, float b){
  union { f16x2 h; unsigned u; } X; X.h = pack2f(a, b); return X.u;
}

__device__ __forceinline__ float silu_f(float x){ return x / (1.0f + __expf(-x)); }

// recompute bessel basis from dR (identical math/constants throughout all rounds)
__device__ __forceinline__ void bessel8(const float* __restrict__ dR, int e, float* rb){
  float x = dR[3*e+0], y = dR[3*e+1], z = dR[3*e+2];
  float r = sqrtf(x*x + y*y + z*z);
  float rs = fmaxf(r, 1e-6f);
  float inv = 1.0f / rs;
  float env;
  if (r < 3.5f) env = 1.0f;
  else if (r > 4.0f) env = 0.0f;
  else {
    float t = (r - 3.5f) * 2.0f;
    env = 0.5f * (cosf(3.14159265358979323846f * t) + 1.0f);
  }
  float c = 0.7071067811865476f * inv * env;
  #pragma unroll
  for (int k=0;k<8;k++){
    float arg = (float)(k+1) * 0.7853981633974483f * rs;
    rb[k] = c * sinf(arg);
  }
}

// ---------------- geometry: spherical harmonics only (fallback path) ----------------
__global__ void k_geom(const float* __restrict__ dR, float* __restrict__ sh1){
  int e = blockIdx.x*256 + threadIdx.x;
  if (e >= NE) return;
  float x = dR[3*e+0], y = dR[3*e+1], z = dR[3*e+2];
  float r = sqrtf(x*x + y*y + z*z);
  float inv = 1.0f / fmaxf(r, 1e-6f);
  const float SQ3 = 1.7320508075688772f;
  sh1[3*e+0] = SQ3 * x * inv;
  sh1[3*e+1] = SQ3 * y * inv;
  sh1[3*e+2] = SQ3 * z * inv;
}

// ---------------- edge pre-permute (fast path): kills dependent gather chains ----
__global__ void k_prep(const float* __restrict__ dR, const int* __restrict__ senders,
                       const int* __restrict__ perm,
                       float* __restrict__ sh1, float* __restrict__ dRp,
                       int* __restrict__ sendp){
  int p = blockIdx.x*256 + threadIdx.x;
  if (p >= NE) return;
  int e = perm[p];
  float x = dR[3*e+0], y = dR[3*e+1], z = dR[3*e+2];
  dRp[3*p+0] = x; dRp[3*p+1] = y; dRp[3*p+2] = z;
  float r = sqrtf(x*x + y*y + z*z);
  float inv = 1.0f / fmaxf(r, 1e-6f);
  const float SQ3 = 1.7320508075688772f;
  sh1[3*p+0] = SQ3 * x * inv;
  sh1[3*p+1] = SQ3 * y * inv;
  sh1[3*p+2] = SQ3 * z * inv;
  sendp[p] = senders[e];
}

// ---------------- one-time weight transpose: W[i][e][o] -> W[i][o][e] ------------
__global__ void k_wt(const float* __restrict__ Wscs, const float* __restrict__ Wscv,
                     float* __restrict__ Wst, float* __restrict__ Wvt){
  int idx = blockIdx.x*256 + threadIdx.x;
  if (idx < 49152){                       // 2 layers x 64 x 4 x 96
    int l = idx/24576, r = idx - l*24576;
    int i = r/384; int rem = r - i*384; int e = rem/96; int o = rem - e*96;
    Wst[l*24576 + i*384 + o*4 + e] = Wscs[idx];
  } else if (idx < 49152 + 8192){         // 2 layers x 32 x 4 x 32
    int k = idx - 49152;
    int l = k/4096, r = k - l*4096;
    int i = r/128; int rem = r - i*128; int e = rem/32; int op = rem - e*32;
    Wvt[l*4096 + i*128 + op*4 + e] = Wscv[idx];
  }
}

// ---------------- node embedding ----------------
__global__ void k_embed(const float* __restrict__ nodes, const float* __restrict__ W,
                        float* __restrict__ s){
  int idx = blockIdx.x*256 + threadIdx.x;   // N*64 exact
  int n = idx>>6, o = idx&63;
  float a = nodes[n*4+0]*W[o] + nodes[n*4+1]*W[64+o]
          + nodes[n*4+2]*W[128+o] + nodes[n*4+3]*W[192+o];
  s[idx] = 0.5f*a;
}

// ---------------- counting sort of edges by receiver ----------------
__global__ void k_hist(const int* __restrict__ receivers, int* __restrict__ cnt){
  int e = blockIdx.x*256 + threadIdx.x;
  if (e < NE) atomicAdd(&cnt[receivers[e]], 1);
}

__global__ void k_scan(const int* __restrict__ cnt, int* __restrict__ row, int* __restrict__ cur){
  __shared__ int lsum[1024];
  int t = threadIdx.x;
  int base = t*20;
  int local[20];
  int s = 0;
  #pragma unroll
  for (int i=0;i<20;i++){
    int idx = base+i;
    int v = (idx<NN) ? cnt[idx] : 0;
    local[i] = s; s += v;
  }
  lsum[t] = s; __syncthreads();
  for (int off=1; off<1024; off<<=1){
    int v = (t>=off) ? lsum[t-off] : 0;
    __syncthreads();
    lsum[t] += v;
    __syncthreads();
  }
  int pre = (t>0) ? lsum[t-1] : 0;
  #pragma unroll
  for (int i=0;i<20;i++){
    int idx = base+i;
    if (idx<NN){ int r = pre+local[i]; row[idx]=r; cur[idx]=r; }
  }
  if (t==1023) row[NN] = lsum[1023];
}

__global__ void k_scatter(const int* __restrict__ receivers, int* __restrict__ cur,
                          int* __restrict__ perm){
  int e = blockIdx.x*256 + threadIdx.x;
  if (e < NE){
    int d = receivers[e];
    int p = atomicAdd(&cur[d], 1);
    perm[p] = e;
  }
}

// ---------------- per-layer node linears: 16 nodes/block, 4 nodes/wave ----------
// Weight loads batched x4 (round-10) -- 4 L2 loads in flight per chain.
__global__ void k_node(const float* __restrict__ s, const float* __restrict__ v,
                       const float* __restrict__ attrs,
                       const float* __restrict__ W1s, const float* __restrict__ W1v,
                       const float* __restrict__ Wscst, const float* __restrict__ Wscvt,
                       __half* __restrict__ s1, __half* __restrict__ v1,
                       float* __restrict__ scs, float* __restrict__ scv){
  __shared__ float ls[16][64];
  __shared__ float lv[16][96];
  __shared__ float la[16][4];
  int tid = threadIdx.x;
  int nb = blockIdx.x*16;   // 1250*16 = 20000 exact
  for (int i=tid;i<1024;i+=256) ls[i>>6][i&63] = s[(size_t)(nb+(i>>6))*64 + (i&63)];
  for (int i=tid;i<1536;i+=256){ int j=i/96, q=i-96*j; lv[j][q] = v[(size_t)(nb+j)*96+q]; }
  if (tid<64) la[tid>>2][tid&3] = attrs[(nb+(tid>>2))*4 + (tid&3)];
  __syncthreads();
  int w = tid>>6, q = tid&63;
  int jb = w*4;                       // this wave's 4 nodes: nb+jb .. nb+jb+3
  float laj[4][4];
  #pragma unroll
  for (int j=0;j<4;j++)
    #pragma unroll
    for (int e=0;e<4;e++) laj[j][e] = la[jb+j][e];

  // s1 = s @ W1s / 8  (loads batched x4)
  {
    float acc[4] = {0,0,0,0};
    for (int i=0;i<64;i+=4){
      float wv0 = W1s[(i+0)*64+q];
      float wv1 = W1s[(i+1)*64+q];
      float wv2 = W1s[(i+2)*64+q];
      float wv3 = W1s[(i+3)*64+q];
      #pragma unroll
      for (int j=0;j<4;j++){
        acc[j] = fmaf(ls[jb+j][i+0], wv0, acc[j]);
        acc[j] = fmaf(ls[jb+j][i+1], wv1, acc[j]);
        acc[j] = fmaf(ls[jb+j][i+2], wv2, acc[j]);
        acc[j] = fmaf(ls[jb+j][i+3], wv3, acc[j]);
      }
    }
    #pragma unroll
    for (int j=0;j<4;j++) s1[(size_t)(nb+jb+j)*64+q] = __float2half(acc[j]*0.125f);
  }
  // sc_s (two-stage, loads batched x4)
  #pragma unroll 1
  for (int o=q;o<96;o+=64){
    float t0[4]={0,0,0,0}, t1[4]={0,0,0,0}, t2[4]={0,0,0,0}, t3[4]={0,0,0,0};
    for (int i=0;i<64;i+=4){
      float4 wa = *(const float4*)(Wscst + (i+0)*384 + o*4);
      float4 wb = *(const float4*)(Wscst + (i+1)*384 + o*4);
      float4 wc = *(const float4*)(Wscst + (i+2)*384 + o*4);
      float4 wd = *(const float4*)(Wscst + (i+3)*384 + o*4);
      #pragma unroll
      for (int j=0;j<4;j++){
        float s0 = ls[jb+j][i+0], s1v = ls[jb+j][i+1];
        float s2 = ls[jb+j][i+2], s3 = ls[jb+j][i+3];
        t0[j] = fmaf(s0, wa.x, t0[j]); t1[j] = fmaf(s0, wa.y, t1[j]);
        t2[j] = fmaf(s0, wa.z, t2[j]); t3[j] = fmaf(s0, wa.w, t3[j]);
        t0[j] = fmaf(s1v, wb.x, t0[j]); t1[j] = fmaf(s1v, wb.y, t1[j]);
        t2[j] = fmaf(s1v, wb.z, t2[j]); t3[j] = fmaf(s1v, wb.w, t3[j]);
        t0[j] = fmaf(s2, wc.x, t0[j]); t1[j] = fmaf(s2, wc.y, t1[j]);
        t2[j] = fmaf(s2, wc.z, t2[j]); t3[j] = fmaf(s2, wc.w, t3[j]);
        t0[j] = fmaf(s3, wd.x, t0[j]); t1[j] = fmaf(s3, wd.y, t1[j]);
        t2[j] = fmaf(s3, wd.z, t2[j]); t3[j] = fmaf(s3, wd.w, t3[j]);
      }
    }
    #pragma unroll
    for (int j=0;j<4;j++){
      float acc = t0[j]*laj[j][0] + t1[j]*laj[j][1]
                + t2[j]*laj[j][2] + t3[j]*laj[j][3];
      scs[(size_t)(nb+jb+j)*96+o] = acc*0.0625f;
    }
  }
  // v1 (loads batched x4)
  #pragma unroll 1
  for (int f=q;f<96;f+=64){
    int op=f/3, c=f-3*op;
    float acc[4] = {0,0,0,0};
    for (int i=0;i<32;i+=4){
      float wv0 = W1v[(i+0)*32+op];
      float wv1 = W1v[(i+1)*32+op];
      float wv2 = W1v[(i+2)*32+op];
      float wv3 = W1v[(i+3)*32+op];
      #pragma unroll
      for (int j=0;j<4;j++){
        acc[j] = fmaf(lv[jb+j][(i+0)*3+c], wv0, acc[j]);
        acc[j] = fmaf(lv[jb+j][(i+1)*3+c], wv1, acc[j]);
        acc[j] = fmaf(lv[jb+j][(i+2)*3+c], wv2, acc[j]);
        acc[j] = fmaf(lv[jb+j][(i+3)*3+c], wv3, acc[j]);
      }
    }
    #pragma unroll
    for (int j=0;j<4;j++) v1[(size_t)(nb+jb+j)*96+f] = __float2half(acc[j]*0.17677669529663687f);
  }
  // sc_v (two-stage, loads batched x4)
  #pragma unroll 1
  for (int f=q;f<96;f+=64){
    int op=f/3, c=f-3*op;
    float t0[4]={0,0,0,0}, t1[4]={0,0,0,0}, t2[4]={0,0,0,0}, t3[4]={0,0,0,0};
    for (int i=0;i<32;i+=4){
      float4 wa = *(const float4*)(Wscvt + (i+0)*128 + op*4);
      float4 wb = *(const float4*)(Wscvt + (i+1)*128 + op*4);
      float4 wc = *(const float4*)(Wscvt + (i+2)*128 + op*4);
      float4 wd = *(const float4*)(Wscvt + (i+3)*128 + op*4);
      #pragma unroll
      for (int j=0;j<4;j++){
        float v0 = lv[jb+j][(i+0)*3+c], v1v = lv[jb+j][(i+1)*3+c];
        float v2 = lv[jb+j][(i+2)*3+c], v3 = lv[jb+j][(i+3)*3+c];
        t0[j] = fmaf(v0, wa.x, t0[j]); t1[j] = fmaf(v0, wa.y, t1[j]);
        t2[j] = fmaf(v0, wa.z, t2[j]); t3[j] = fmaf(v0, wa.w, t3[j]);
        t0[j] = fmaf(v1v, wb.x, t0[j]); t1[j] = fmaf(v1v, wb.y, t1[j]);
        t2[j] = fmaf(v1v, wb.z, t2[j]); t3[j] = fmaf(v1v, wb.w, t3[j]);
        t0[j] = fmaf(v2, wc.x, t0[j]); t1[j] = fmaf(v2, wc.y, t1[j]);
        t2[j] = fmaf(v2, wc.z, t2[j]); t3[j] = fmaf(v2, wc.w, t3[j]);
        t0[j] = fmaf(v3, wd.x, t0[j]); t1[j] = fmaf(v3, wd.y, t1[j]);
        t2[j] = fmaf(v3, wd.z, t2[j]); t3[j] = fmaf(v3, wd.w, t3[j]);
      }
    }
    #pragma unroll
    for (int j=0;j<4;j++){
      float acc = t0[j]*laj[j][0] + t1[j]*laj[j][1]
                + t2[j]*laj[j][2] + t3[j]*laj[j][3];
      scv[(size_t)(nb+jb+j)*96+f] = acc*0.08838834764831845f;
    }
  }
}

// ---------------- edge MLP: persistent-weight multi-tile version -----------------
// R1 A-fragments loaded once into registers; wgt1 LDS gone -> 35.8KB, 4 blocks/CU.
#define R2S 196
#define HT2S 68
__launch_bounds__(256, 4)
__global__ void k_edgew(const float* __restrict__ dRp,
                        const int* __restrict__ row, int n0, int n1, int cap,
                        const float* __restrict__ R0, const float* __restrict__ R1,
                        const float* __restrict__ R2,
                        __half* __restrict__ wbuf){
  __shared__ __align__(16) f16x2 hT2[32*HT2S];  // 8.7 KB: [kpair][e] stride 68; rb staging (fp32 view) / h1 / h2
  __shared__ __align__(16) float r0s[512];      // 2 KB: R0 fp32
  __shared__ __align__(16) f16x2 wgt2[32*R2S];  // 24.5 KB: R2 k-pairs, persistent
  int tid = threadIdx.x;
  int p0 = row[n0], p1 = row[n1];
  int vmax = p1 - p0; if (vmax > cap) vmax = cap;
  int ntiles = (vmax + 63) >> 6;

  int eg = tid & 15, e0 = eg*4;
  int jg = tid >> 4, j0 = jg*4;
  int wv = tid >> 6;
  int ln = tid & 63;
  int col = ln & 15;
  int quad = ln >> 4;

  // ---- persistent staging (once per block) ----
  if (tid < 128) ((float4*)r0s)[tid] = ((const float4*)R0)[tid];
  for (int i=tid; i<6144; i+=256){
    int kp = i/192, o = i-192*kp;
    wgt2[kp*R2S + o] = pack2f(R2[(2*kp)*192 + o], R2[(2*kp+1)*192 + o]);
  }
  // R1 A-frags direct from global into registers (was LDS wgt1)
  union { uint4 u; f16x8 v; } rA0, rA1;
  {
    int jA = 16*wv + col;
    rA0.u.x = packu2f(R1[(8*quad+0)*64 + jA], R1[(8*quad+1)*64 + jA]);
    rA0.u.y = packu2f(R1[(8*quad+2)*64 + jA], R1[(8*quad+3)*64 + jA]);
    rA0.u.z = packu2f(R1[(8*quad+4)*64 + jA], R1[(8*quad+5)*64 + jA]);
    rA0.u.w = packu2f(R1[(8*quad+6)*64 + jA], R1[(8*quad+7)*64 + jA]);
    rA1.u.x = packu2f(R1[(32+8*quad+0)*64 + jA], R1[(32+8*quad+1)*64 + jA]);
    rA1.u.y = packu2f(R1[(32+8*quad+2)*64 + jA], R1[(32+8*quad+3)*64 + jA]);
    rA1.u.z = packu2f(R1[(32+8*quad+4)*64 + jA], R1[(32+8*quad+5)*64 + jA]);
    rA1.u.w = packu2f(R1[(32+8*quad+6)*64 + jA], R1[(32+8*quad+7)*64 + jA]);
  }
  // visibility of r0s/wgt2 covered by the loop-top barrier of the first tile

  for (int tile = blockIdx.x; tile < ntiles; tile += gridDim.x){
    int tbase = tile*64;
    int vcnt = vmax - tbase; if (vcnt > 64) vcnt = 64;

    __syncthreads();   // [A] staging visible / prev tile's phase-C hT2 reads done
    // stage rb for the 64 edges into hT2 region (fp32 view, rows k<8)
    float* hTf = (float*)hT2;
    if (tid < 64){
      float rbv[8];
      if (tid < vcnt){
        bessel8(dRp, p0 + tbase + tid, rbv);
      } else {
        #pragma unroll
        for (int k=0;k<8;k++) rbv[k]=0.0f;
      }
      #pragma unroll
      for (int k=0;k<8;k++) hTf[k*HT2S + tid] = rbv[k];
    }
    __syncthreads();   // [B]

    // read rb tile into regs (before overwriting hT2 with h1 pairs)
    float rb[8][4];
    {
      const float4* hTf4 = (const float4*)hTf;
      #pragma unroll
      for (int k=0;k<8;k++){
        float4 v = hTf4[k*17 + eg];
        rb[k][0]=v.x; rb[k][1]=v.y; rb[k][2]=v.z; rb[k][3]=v.w;
      }
    }
    // phase A: h1 tile (fp32 math, tiny K=8)
    float a[4][4];
    #pragma unroll
    for (int j=0;j<4;j++)
      #pragma unroll
      for (int e=0;e<4;e++) a[j][e]=0.0f;
    {
      const float4* r0s4 = (const float4*)r0s;
      #pragma unroll
      for (int k=0;k<8;k++){
        float4 w = r0s4[k*16 + jg];
        float wj[4] = {w.x,w.y,w.z,w.w};
        #pragma unroll
        for (int j=0;j<4;j++)
          #pragma unroll
          for (int e=0;e<4;e++) a[j][e] = fmaf(rb[k][e], wj[j], a[j][e]);
      }
    }
    #pragma unroll
    for (int j=0;j<4;j++)
      #pragma unroll
      for (int e=0;e<4;e++) a[j][e] = silu_f(a[j][e]*0.3535533905932738f);
    __syncthreads();   // [C] all rb reads complete
    // write h1 as k-pairs: rows j0/2, j0/2+1 of hT2
    #pragma unroll
    for (int jp=0;jp<2;jp++){
      union {uint4 u; f16x2 h[4];} U;
      #pragma unroll
      for (int e=0;e<4;e++) U.h[e] = pack2f(a[2*jp][e], a[2*jp+1][e]);
      *(uint4*)(hT2 + (j0/2 + jp)*HT2S + e0) = U.u;
    }
    __syncthreads();   // [D]

    // phase B via MFMA: wave wv owns j-tile [16*wv,16*wv+16), loops 4 e-tiles.
    {
      const unsigned int* hT2u = (const unsigned int*)hT2;
      f32x4 accB[4];
      #pragma unroll
      for (int nt=0; nt<4; nt++){
        union { uint4 u; f16x8 v; } B0, B1;
        int eB = 16*nt + col;
        B0.u.x = hT2u[(4*quad+0)*HT2S + eB];
        B0.u.y = hT2u[(4*quad+1)*HT2S + eB];
        B0.u.z = hT2u[(4*quad+2)*HT2S + eB];
        B0.u.w = hT2u[(4*quad+3)*HT2S + eB];
        B1.u.x = hT2u[(16+4*quad+0)*HT2S + eB];
        B1.u.y = hT2u[(16+4*quad+1)*HT2S + eB];
        B1.u.z = hT2u[(16+4*quad+2)*HT2S + eB];
        B1.u.w = hT2u[(16+4*quad+3)*HT2S + eB];
        f32x4 acc = {0.0f,0.0f,0.0f,0.0f};
        acc = __builtin_amdgcn_mfma_f32_16x16x32_f16(rA0.v, B0.v, acc, 0, 0, 0);
        acc = __builtin_amdgcn_mfma_f32_16x16x32_f16(rA1.v, B1.v, acc, 0, 0, 0);
        accB[nt] = acc;
      }
      __syncthreads();   // [E] all h1 (hT2) reads complete
      // silu + pack + write h2^T as k-pairs
      #pragma unroll
      for (int nt=0; nt<4; nt++){
        float h0 = silu_f(accB[nt][0]*0.125f);
        float h1v = silu_f(accB[nt][1]*0.125f);
        float h2v = silu_f(accB[nt][2]*0.125f);
        float h3v = silu_f(accB[nt][3]*0.125f);
        hT2[(8*wv + 2*quad + 0)*HT2S + 16*nt + col] = pack2f(h0, h1v);
        hT2[(8*wv + 2*quad + 1)*HT2S + 16*nt + col] = pack2f(h2v, h3v);
      }
    }
    __syncthreads();   // [F] h2 visible

    // phase C via MFMA: wave wv handles edges [16*wv, 16*wv+16)
    {
      const unsigned int* hT2u = (const unsigned int*)hT2;
      const unsigned int* wgt2u = (const unsigned int*)wgt2;
      int eA = 16*wv + col;     // A's m index
      union { uint4 u; f16x8 v; } A0, A1;
      A0.u.x = hT2u[(4*quad+0)*HT2S + eA];
      A0.u.y = hT2u[(4*quad+1)*HT2S + eA];
      A0.u.z = hT2u[(4*quad+2)*HT2S + eA];
      A0.u.w = hT2u[(4*quad+3)*HT2S + eA];
      A1.u.x = hT2u[(16+4*quad+0)*HT2S + eA];
      A1.u.y = hT2u[(16+4*quad+1)*HT2S + eA];
      A1.u.z = hT2u[(16+4*quad+2)*HT2S + eA];
      A1.u.w = hT2u[(16+4*quad+3)*HT2S + eA];
      int erow = 16*wv + 4*quad;           // D rows: erow+0..3
      #pragma unroll
      for (int ot=0; ot<12; ot++){
        int o = 16*ot + col;
        union { uint4 u; f16x8 v; } B0, B1;
        B0.u.x = wgt2u[(4*quad+0)*R2S + o];
        B0.u.y = wgt2u[(4*quad+1)*R2S + o];
        B0.u.z = wgt2u[(4*quad+2)*R2S + o];
        B0.u.w = wgt2u[(4*quad+3)*R2S + o];
        B1.u.x = wgt2u[(16+4*quad+0)*R2S + o];
        B1.u.y = wgt2u[(16+4*quad+1)*R2S + o];
        B1.u.z = wgt2u[(16+4*quad+2)*R2S + o];
        B1.u.w = wgt2u[(16+4*quad+3)*R2S + o];
        f32x4 acc = {0.0f,0.0f,0.0f,0.0f};
        acc = __builtin_amdgcn_mfma_f32_16x16x32_f16(A0.v, B0.v, acc, 0, 0, 0);
        acc = __builtin_amdgcn_mfma_f32_16x16x32_f16(A1.v, B1.v, acc, 0, 0, 0);
        // direct predicated stores (uniform-true branch for full tiles)
        #pragma unroll
        for (int r=0;r<4;r++){
          int eib = erow + r;
          if (eib < vcnt)
            wbuf[(size_t)(tbase+eib)*192 + o] = __float2half(acc[r]);
        }
      }
    }
  }
}

// ---------------- gather: role-split + 8-deep load batching, spill-free ---------
__launch_bounds__(128, 4)
__global__ void k_gather(const __half* __restrict__ wbuf,
                         const int* __restrict__ row, const int* __restrict__ sendp,
                         const float* __restrict__ sh1,
                         const __half* __restrict__ s1, const __half* __restrict__ v1,
                         int n0, int cap,
                         float* __restrict__ a_s, float* __restrict__ a_v){
  __shared__ int   srcs[ECAP];
  __shared__ float sh1r[ECAP*3];
  int n = n0 + blockIdx.x;
  int t = threadIdx.x;
  int pc0 = row[n0];
  int p0 = row[n], p1 = row[n+1];
  int pmax = pc0 + cap; if (p1 > pmax) p1 = pmax;

  int iv = (t - 64) >> 1;          // 0..31 for vrole
  bool even = ((t & 1) == 0);

  float acs = 0.0f, av0 = 0.0f, av1 = 0.0f, av2 = 0.0f;

  for (int base = p0; base < p1; base += ECAP){
    int bc = p1 - base; if (bc > ECAP) bc = ECAP;
    __syncthreads();   // protect LDS reuse across batches
    if (t < bc){
      srcs[t] = sendp[base + t];
      sh1r[3*t+0] = sh1[3*(base+t)+0];
      sh1r[3*t+1] = sh1[3*(base+t)+1];
      sh1r[3*t+2] = sh1[3*(base+t)+2];
    }
    __syncthreads();
    const __half* wb = wbuf + (size_t)(base - pc0)*192;
    if (t < 64){
      int o = t;
      int j = 0;
      for (; j + 8 <= bc; j += 8){
        float sv[8], w1[8], w2[8];
        #pragma unroll
        for (int u=0;u<8;u++){
          const __half* wr = wb + (j+u)*192;
          sv[u] = __half2float(s1[(size_t)srcs[j+u]*64 + o]);
          w1[u] = __half2float(wr[o]);
          w2[u] = __half2float(wr[64 + o]);
        }
        #pragma unroll
        for (int u=0;u<8;u++){
          acs = fmaf(w1[u], sv[u], acs);
          float uu = w2[u] * sv[u];
          av0 = fmaf(uu, sh1r[3*(j+u)+0], av0);
          av1 = fmaf(uu, sh1r[3*(j+u)+1], av1);
          av2 = fmaf(uu, sh1r[3*(j+u)+2], av2);
        }
      }
      for (; j < bc; ++j){
        const __half* wr = wb + j*192;
        float sv = __half2float(s1[(size_t)srcs[j]*64 + o]);
        float w1v = __half2float(wr[o]);
        float w2v = __half2float(wr[64 + o]);
        acs = fmaf(w1v, sv, acs);
        float uu = w2v * sv;
        av0 = fmaf(uu, sh1r[3*j+0], av0);
        av1 = fmaf(uu, sh1r[3*j+1], av1);
        av2 = fmaf(uu, sh1r[3*j+2], av2);
      }
    } else {
      int j = 0;
      for (; j + 8 <= bc; j += 8){
        float v0[8], vc1[8], vc2[8], w3[8], w4[8];
        #pragma unroll
        for (int u=0;u<8;u++){
          const __half* wr = wb + (j+u)*192;
          const __half* vr = v1 + (size_t)srcs[j+u]*96 + 3*iv;
          v0[u]  = __half2float(vr[0]);
          vc1[u] = __half2float(vr[1]);
          vc2[u] = __half2float(vr[2]);
          w3[u]  = __half2float(wr[128 + iv]);
          w4[u]  = __half2float(wr[160 + iv]);
        }
        #pragma unroll
        for (int u=0;u<8;u++){
          if (even){
            float dv = v0[u]*sh1r[3*(j+u)+0] + vc1[u]*sh1r[3*(j+u)+1] + vc2[u]*sh1r[3*(j+u)+2];
            acs = fmaf(w4[u], dv, acs);
            av0 = fmaf(w3[u], v0[u], av0);
          } else {
            av1 = fmaf(w3[u], vc1[u], av1);
            av2 = fmaf(w3[u], vc2[u], av2);
          }
        }
      }
      for (; j < bc; ++j){
        const __half* wr = wb + j*192;
        const __half* vr = v1 + (size_t)srcs[j]*96 + 3*iv;
        float v0 = __half2float(vr[0]);
        float vc1 = __half2float(vr[1]);
        float vc2 = __half2float(vr[2]);
        float w3 = __half2float(wr[128 + iv]);
        if (even){
          float w4 = __half2float(wr[160 + iv]);
          float dv = v0*sh1r[3*j+0] + vc1*sh1r[3*j+1] + vc2*sh1r[3*j+2];
          acs = fmaf(w4, dv, acs);
          av0 = fmaf(w3, v0, av0);
        } else {
          av1 = fmaf(w3, vc1, av1);
          av2 = fmaf(w3, vc2, av2);
        }
      }
    }
  }

  if (t < 64){
    a_s[(size_t)n*96 + t] = 0.03125f*acs;              // (1/8)*(1/sqrt(16))
    a_v[(size_t)n*288 + 3*t + 0] = 0.03125f*av0;
    a_v[(size_t)n*288 + 3*t + 1] = 0.03125f*av1;
    a_v[(size_t)n*288 + 3*t + 2] = 0.03125f*av2;
  } else if (even){
    a_s[(size_t)n*96 + 64 + iv] = 0.018042195912175807f*acs;   // 0.03125/sqrt(3)
    a_v[(size_t)n*288 + 192 + 3*iv + 0] = 0.03125f*av0;
  } else {
    a_v[(size_t)n*288 + 192 + 3*iv + 1] = 0.03125f*av1;
    a_v[(size_t)n*288 + 192 + 3*iv + 2] = 0.03125f*av2;
  }
}

// ---------------- fallback: atomic edge kernel (only if ws too small) ----------------
__device__ __forceinline__ void mlp_h2(const float* __restrict__ R0,
                                       const float* lR1, const float rb[8],
                                       float h2[64]){
  float h1[64];
  #pragma unroll
  for (int j=0;j<64;j+=4){
    float a0=0,a1=0,a2=0,a3=0;
    #pragma unroll
    for (int k=0;k<8;k++){
      float r = rb[k];
      const float* wp = R0 + k*64 + j;
      a0 = fmaf(r, wp[0], a0); a1 = fmaf(r, wp[1], a1);
      a2 = fmaf(r, wp[2], a2); a3 = fmaf(r, wp[3], a3);
    }
    h1[j+0]=silu_f(a0*0.3535533905932738f);
    h1[j+1]=silu_f(a1*0.3535533905932738f);
    h1[j+2]=silu_f(a2*0.3535533905932738f);
    h1[j+3]=silu_f(a3*0.3535533905932738f);
  }
  #pragma unroll
  for (int j=0;j<64;j+=4){
    float a0=0,a1=0,a2=0,a3=0;
    #pragma unroll
    for (int k=0;k<64;k++){
      float h = h1[k];
      float4 w4 = *(const float4*)(lR1 + k*64 + j);
      a0 = fmaf(h,w4.x,a0); a1 = fmaf(h,w4.y,a1);
      a2 = fmaf(h,w4.z,a2); a3 = fmaf(h,w4.w,a3);
    }
    h2[j+0]=silu_f(a0*0.125f);
    h2[j+1]=silu_f(a1*0.125f);
    h2[j+2]=silu_f(a2*0.125f);
    h2[j+3]=silu_f(a3*0.125f);
  }
}

__launch_bounds__(256, 2)
__global__ void k_edge(const float* __restrict__ dR, const float* __restrict__ sh1,
                       const int* __restrict__ senders, const int* __restrict__ receivers,
                       const __half* __restrict__ s1, const __half* __restrict__ v1,
                       const float* __restrict__ R0, const float* __restrict__ R1,
                       const float* __restrict__ R2,
                       float* __restrict__ a_s, float* __restrict__ a_v){
  __shared__ __align__(16) float lR1[64*64];
  __shared__ __align__(16) float lR2[64*192];
  int tid = threadIdx.x;
  for (int i=tid;i<4096;i+=256)  lR1[i]=R1[i];
  for (int i=tid;i<12288;i+=256) lR2[i]=R2[i];
  __syncthreads();
  int e = blockIdx.x*256 + tid;
  float rb[8];
  bessel8(dR, e, rb);
  float h2[64];
  mlp_h2(R0, lR1, rb, h2);
  int src = senders[e], dst = receivers[e];
  float sx=sh1[3*e+0], sy=sh1[3*e+1], sz=sh1[3*e+2];
  const __half* srow = s1 + (size_t)src*64;
  const __half* vrow = v1 + (size_t)src*96;
  float* asr = a_s + (size_t)dst*96;
  float* avr = a_v + (size_t)dst*288;
  #pragma unroll 1
  for (int o=0;o<64;o+=4){
    float w10=0,w11=0,w12=0,w13=0, w20=0,w21=0,w22=0,w23=0;
    #pragma unroll
    for (int k=0;k<64;k++){
      float h = h2[k];
      float4 wa = *(const float4*)(lR2 + k*192 + o);
      float4 wb = *(const float4*)(lR2 + k*192 + 64 + o);
      w10=fmaf(h,wa.x,w10); w11=fmaf(h,wa.y,w11); w12=fmaf(h,wa.z,w12); w13=fmaf(h,wa.w,w13);
      w20=fmaf(h,wb.x,w20); w21=fmaf(h,wb.y,w21); w22=fmaf(h,wb.z,w22); w23=fmaf(h,wb.w,w23);
    }
    float sev[4] = {__half2float(srow[o+0]), __half2float(srow[o+1]),
                    __half2float(srow[o+2]), __half2float(srow[o+3])};
    float w1a[4] = {w10,w11,w12,w13};
    float w2a[4] = {w20,w21,w22,w23};
    #pragma unroll
    for (int u=0;u<4;u++){
      atomicAdd(asr+o+u, 0.03125f*w1a[u]*sev[u]);
      float m = 0.03125f*w2a[u]*sev[u];
      atomicAdd(avr+(o+u)*3+0, m*sx);
      atomicAdd(avr+(o+u)*3+1, m*sy);
      atomicAdd(avr+(o+u)*3+2, m*sz);
    }
  }
  #pragma unroll 1
  for (int i0=0;i0<32;i0+=4){
    float w30=0,w31=0,w32=0,w33=0, w40=0,w41=0,w42=0,w43=0;
    #pragma unroll
    for (int k=0;k<64;k++){
      float h = h2[k];
      float4 wa = *(const float4*)(lR2 + k*192 + 128 + i0);
      float4 wb = *(const float4*)(lR2 + k*192 + 160 + i0);
      w30=fmaf(h,wa.x,w30); w31=fmaf(h,wa.y,w31); w32=fmaf(h,wa.z,w32); w33=fmaf(h,wa.w,w33);
      w40=fmaf(h,wb.x,w40); w41=fmaf(h,wb.y,w41); w42=fmaf(h,wb.z,w42); w43=fmaf(h,wb.w,w43);
    }
    float w3a[4] = {w30,w31,w32,w33};
    float w4a[4] = {w40,w41,w42,w43};
    #pragma unroll
    for (int u=0;u<4;u++){
      int i = i0+u;
      float vx=__half2float(vrow[3*i+0]), vy=__half2float(vrow[3*i+1]), vz=__half2float(vrow[3*i+2]);
      float dv = vx*sx + vy*sy + vz*sz;
      atomicAdd(asr+64+i, 0.018042195912175807f*w4a[u]*dv);
      float m3 = 0.03125f*w3a[u];
      atomicAdd(avr+(64+i)*3+0, m3*vx);
      atomicAdd(avr+(64+i)*3+1, m3*vy);
      atomicAdd(avr+(64+i)*3+2, m3*vz);
    }
  }
}

// ---------------- per-layer output transform: o_s, o_v, gating ----------------
__launch_bounds__(256, 4)
__global__ void k_out(const float* __restrict__ a_s, const float* __restrict__ a_v,
                      const float* __restrict__ scs, const float* __restrict__ scv,
                      const float* __restrict__ W2s, const float* __restrict__ W2v,
                      float* __restrict__ s_out, float* __restrict__ v_out){
  __shared__ float las[16][96];
  __shared__ float lav[16][288];
  __shared__ float los[16][96];
  int tid = threadIdx.x;
  int nb = blockIdx.x*16;   // 1250*16 = 20000 exact
  for (int i=tid;i<1536;i+=256){ int j=i/96,  q=i-96*j;  las[j][q] = a_s[(size_t)(nb+j)*96 +q]; }
  for (int i=tid;i<4608;i+=256){ int j=i/288, q=i-288*j; lav[j][q] = a_v[(size_t)(nb+j)*288+q]; }
  __syncthreads();
  int w = tid>>6, q = tid&63;
  int jb = w*4;                       // this wave's 4 nodes: nb+jb .. nb+jb+3

  // o_s = a_s @ W2s * scale + scs   (outputs o = q and q+64, wave-private los)
  #pragma unroll 1
  for (int o=q; o<96; o+=64){
    float acc[4] = {0,0,0,0};
    for (int i=0;i<96;i++){
      float wv = W2s[i*96+o];
      #pragma unroll
      for (int j=0;j<4;j++) acc[j] = fmaf(las[jb+j][i], wv, acc[j]);
    }
    #pragma unroll
    for (int j=0;j<4;j++)
      los[jb+j][o] = acc[j]*0.10206207261596575f + scs[(size_t)(nb+jb+j)*96+o];
  }
  __syncthreads();   // (wave-private in fact; barrier keeps LDS ordering simple)

  // s_out = silu(o_s[:64])
  #pragma unroll
  for (int j=0;j<4;j++) s_out[(size_t)(nb+jb+j)*64+q] = silu_f(los[jb+j][q]);

  // o_v = a_v @ W2v * scale + scv, gated by silu(o_s[64+op])
  #pragma unroll 1
  for (int f=q; f<96; f+=64){
    int op=f/3, c=f-3*op;
    float acc[4] = {0,0,0,0};
    for (int i=0;i<96;i++){
      float wv = W2v[i*32+op];
      #pragma unroll
      for (int j=0;j<4;j++) acc[j] = fmaf(lav[jb+j][i*3+c], wv, acc[j]);
    }
    #pragma unroll
    for (int j=0;j<4;j++){
      float ov = acc[j]*0.10206207261596575f + scv[(size_t)(nb+jb+j)*96+f];
      float g = silu_f(los[jb+j][64+op]);
      v_out[(size_t)(nb+jb+j)*96+f] = ov*g;
    }
  }
}

// ---------------- final heads: energy + mags ----------------
__global__ void k_final(const float* __restrict__ s, const float* __restrict__ nodes,
                        const int* __restrict__ n_node,
                        const float* __restrict__ Wen1, const float* __restrict__ Wen2,
                        const float* __restrict__ Wm1, const float* __restrict__ Wm2,
                        const float* __restrict__ scale_occ, const float* __restrict__ shift_occ,
                        const float* __restrict__ escale, const float* __restrict__ eshift,
                        float* __restrict__ out){
  __shared__ float eacc[NG];
  __shared__ int goff[NG+1];
  int tid = threadIdx.x;
  if (tid < NG) eacc[tid] = 0.0f;
  if (tid == 0){
    int c = 0; goff[0] = 0;
    for (int g=0; g<NG; g++){ c += n_node[g]; goff[g+1] = c; }
  }
  __syncthreads();
  int n = blockIdx.x*256 + tid;
  if (n < NN){
    float sv[64];
    #pragma unroll
    for (int i=0;i<64;i++) sv[i]=s[(size_t)n*64+i];
    float en=0.0f, m0=0.0f, m1=0.0f;
    #pragma unroll 1
    for (int jj=0;jj<32;jj++){
      float he=0.0f, hm=0.0f;
      #pragma unroll
      for (int i=0;i<64;i++){
        he = fmaf(sv[i], Wen1[i*32+jj], he);
        hm = fmaf(sv[i], Wm1[i*32+jj], hm);
      }
      he *= 0.125f; hm *= 0.125f;
      en = fmaf(he, Wen2[jj], en);
      m0 = fmaf(hm, Wm2[jj*2+0], m0);
      m1 = fmaf(hm, Wm2[jj*2+1], m1);
    }
    const float INVS32 = 0.17677669529663687f;
    en *= INVS32; m0 *= INVS32; m1 *= INVS32;
    en = escale[0]*en + eshift[0];
    int g = 0;
    for (int gg=0; gg<NG; gg++) if (n >= goff[gg+1]) g = gg+1;
    atomicAdd(&eacc[g], en);
    float nx=nodes[n*4+0], ny=nodes[n*4+1], nz=nodes[n*4+2];
    float sc0 = nx*scale_occ[0] + ny*scale_occ[2] + nz*scale_occ[4];
    float sc1 = nx*scale_occ[1] + ny*scale_occ[3] + nz*scale_occ[5];
    float sf0 = nx*shift_occ[0] + ny*shift_occ[2] + nz*shift_occ[4];
    float sf1 = nx*shift_occ[1] + ny*shift_occ[3] + nz*shift_occ[5];
    out[16 + n*2 + 0] = sc0*m0 + sf0;
    out[16 + n*2 + 1] = sc1*m1 + sf1;
  }
  __syncthreads();
  if (tid < NG) atomicAdd(&out[tid], eacc[tid]);
}

extern "C" void kernel_launch(void* const* d_in, const int* in_sizes, int n_in,
                              void* d_out, int out_size, void* d_ws, size_t ws_size,
                              hipStream_t stream){
  const float* nodes   = (const float*)d_in[0];
  const float* dR      = (const float*)d_in[1];
  const int*  senders  = (const int*)d_in[2];
  const int*  receivers= (const int*)d_in[3];
  const int*  n_node   = (const int*)d_in[4];
  const float* W_embed = (const float*)d_in[5];
  const float* W_sc_s  = (const float*)d_in[6];
  const float* W_sc_v  = (const float*)d_in[7];
  const float* W_l1_s  = (const float*)d_in[8];
  const float* W_l1_v  = (const float*)d_in[9];
  const float* Wr0     = (const float*)d_in[10];
  const float* Wr1     = (const float*)d_in[11];
  const float* Wr2     = (const float*)d_in[12];
  const float* W_l2_s  = (const float*)d_in[13];
  const float* W_l2_v  = (const float*)d_in[14];
  const float* W_en1   = (const float*)d_in[15];
  const float* W_en2   = (const float*)d_in[16];
  const float* W_mag1  = (const float*)d_in[17];
  const float* W_mag2  = (const float*)d_in[18];
  const float* scale_occ = (const float*)d_in[19];
  const float* shift_occ = (const float*)d_in[20];
  const float* escale  = (const float*)d_in[21];
  const float* eshift  = (const float*)d_in[22];
  float* out = (float*)d_out;
  float* ws  = (float*)d_ws;

  // ---- workspace map (float-index offsets) ----
  float*  sh1  = ws + 0;         // NE*3 f32 (PERMUTED order in fast path)
  float*  sA   = ws + 960000;    // NN*64 f32
  float*  vA   = ws + 2240000;   // NN*96 f32
  __half* s1h  = (__half*)(ws + 4160000);   // NN*64 halves = 640,000 f32
  __half* v1h  = (__half*)(ws + 4800000);   // NN*96 halves = 960,000 f32
  float*  dRp  = ws + 5760000;   // NE*3 f32 permuted dR = 960,000 f32
  int*    sendp= (int*)(ws + 6720000);      // NE ints = 320,000 -> ends 7,040,000
  float*  Wst  = ws + 7040000;   // 2*24576 = 49,152 transposed W_sc_s
  float*  Wvt  = ws + 7089152;   // 2*4096  =  8,192 transposed W_sc_v -> ends 7,097,344
  float*  scs  = ws + 7360000;   // 1,920,000 f32
  float*  scv  = ws + 9280000;   // 1,920,000 f32
  float*  a_s  = ws + 11200000;  // 1,920,000 f32
  float*  a_v  = ws + 13120000;  // 5,760,000 f32 -> ends 18,880,000
  int*    cnt  = (int*)(ws + 18880000);  // 20,000
  int*    row  = (int*)(ws + 18900000);  // 20,001
  int*    cur  = (int*)(ws + 18920004);  // 20,000
  int*    perm = (int*)(ws + 18940004);  // 320,000 -> ends 19,260,004
  __half* wbuf = (__half*)(ws + 19260008); // capacity-adaptive fp16, 16B-aligned

  size_t wsf = ws_size / 4;
  // fp16 wbuf: 192 halves = 384 B per edge
  size_t cap_edges = (wsf > 19260008) ? ((wsf - 19260008)*4) / 384 : 0;
  if (cap_edges > 128) cap_edges -= 64;   // slack for 64-edge tile granularity
  const bool fast = cap_edges >= 4096;
  int cap = (int)((cap_edges > (size_t)NE) ? (size_t)NE + 8192 : cap_edges);
  // single chunk when wbuf can hold ALL edges; else the statistical heuristic.
  int npc;
  if (cap_edges > (size_t)NE){
    npc = NN;
  } else {
    npc = (int)(cap / 20); if (npc < 1) npc = 1; if (npc > NN) npc = NN;
  }
  int nchunk = (NN + npc - 1) / npc;

  hipMemsetAsync(vA, 0, (size_t)NN*96*sizeof(float), stream);   // v starts at zero
  hipMemsetAsync(out, 0, 16*sizeof(float), stream);             // energy accumulators

  k_embed<<<5000, 256, 0, stream>>>(nodes, W_embed, sA);
  k_wt<<<225, 256, 0, stream>>>(W_sc_s, W_sc_v, Wst, Wvt);

  if (fast){
    hipMemsetAsync(cnt, 0, NN*sizeof(int), stream);
    k_hist<<<1250, 256, 0, stream>>>(receivers, cnt);
    k_scan<<<1, 1024, 0, stream>>>(cnt, row, cur);
    k_scatter<<<1250, 256, 0, stream>>>(receivers, cur, perm);
    k_prep<<<1250, 256, 0, stream>>>(dR, senders, perm, sh1, dRp, sendp);
  } else {
    k_geom<<<1250, 256, 0, stream>>>(dR, sh1);
  }

  for (int l=0; l<2; l++){
    k_node<<<1250, 256, 0, stream>>>(sA, vA, nodes,
                                     W_l1_s + l*4096, W_l1_v + l*1024,
                                     Wst + l*24576, Wvt + l*4096,
                                     s1h, v1h, scs, scv);
    if (fast){
      for (int ck=0; ck<nchunk; ck++){
        int n0 = ck*npc;
        int n1 = n0 + npc; if (n1 > NN) n1 = NN;
        int cover = (n1-n0)*17 + 4096; if (cover > cap) cover = cap;
        int ntile_ub = (cover+63)/64;
        int grid = ntile_ub < 1024 ? ntile_ub : 1024;   // 4 blocks/CU residency
        k_edgew<<<grid, 256, 0, stream>>>(dRp, row, n0, n1, cap,
                                       Wr0 + l*512, Wr1 + l*4096, Wr2 + l*12288, wbuf);
        k_gather<<<n1-n0, 128, 0, stream>>>(wbuf, row, sendp, sh1, s1h, v1h,
                                            n0, cap, a_s, a_v);
      }
    } else {
      hipMemsetAsync(a_s, 0, (size_t)NN*384*sizeof(float), stream);  // a_s+a_v contiguous
      k_edge<<<1250, 256, 0, stream>>>(dR, sh1, senders, receivers, s1h, v1h,
                                       Wr0 + l*512, Wr1 + l*4096, Wr2 + l*12288,
                                       a_s, a_v);
    }
    // writes back into sA/vA (safe: k_out reads only a_s/a_v/scs/scv)
    k_out<<<1250, 256, 0, stream>>>(a_s, a_v, scs, scv,
                                    W_l2_s + l*9216, W_l2_v + l*3072,
                                    sA, vA);
  }
  k_final<<<79, 256, 0, stream>>>(sA, nodes, n_node, W_en1, W_en2, W_mag1, W_mag2,
                                  scale_occ, shift_occ, escale, eshift, out);
}

// Round 13
// 583.138 us; speedup vs baseline: 1.6832x; 1.0329x over previous
//
#include <hip/hip_runtime.h>
#include <hip/hip_fp16.h>
#include <math.h>

#define NN 20000
#define NE 320000
#define NG 16
#define ECAP 48   // edges staged per batch in k_gather (deg ~16+-4, max ~40)

typedef _Float16 f16x2 __attribute__((ext_vector_type(2)));
typedef _Float16 f16x8 __attribute__((ext_vector_type(8)));
typedef float    f32x4 __attribute__((ext_vector_type(4)));

__device__ __forceinline__ float dot2f(f16x2 a, f16x2 b, float c){
#if defined(__has_builtin)
#if __has_builtin(__builtin_amdgcn_fdot2)
  return __builtin_amdgcn_fdot2(a, b, c, false);
#else
  return c + (float)a.x*(float)b.x + (float)a.y*(float)b.y;
#endif
#else
  return c + (float)a.x*(float)b.x + (float)a.y*(float)b.y;
#endif
}

__device__ __forceinline__ f16x2 pack2f(float a, float b){
  f16x2 r; r.x = (_Float16)a; r.y = (_Float16)b; return r;
}

__device__ __forceinline__ unsigned packu2f(float a, float b){
  union { f16x2 h; unsigned u; } X; X.h = pack2f(a, b); return X.u;
}

__device__ __forceinline__ float silu_f(float x){ return x / (1.0f + __expf(-x)); }

// recompute bessel basis from dR (identical math/constants throughout all rounds)
__device__ __forceinline__ void bessel8(const float* __restrict__ dR, int e, float* rb){
  float x = dR[3*e+0], y = dR[3*e+1], z = dR[3*e+2];
  float r = sqrtf(x*x + y*y + z*z);
  float rs = fmaxf(r, 1e-6f);
  float inv = 1.0f / rs;
  float env;
  if (r < 3.5f) env = 1.0f;
  else if (r > 4.0f) env = 0.0f;
  else {
    float t = (r - 3.5f) * 2.0f;
    env = 0.5f * (cosf(3.14159265358979323846f * t) + 1.0f);
  }
  float c = 0.7071067811865476f * inv * env;
  #pragma unroll
  for (int k=0;k<8;k++){
    float arg = (float)(k+1) * 0.7853981633974483f * rs;
    rb[k] = c * sinf(arg);
  }
}

// ---------------- geometry: spherical harmonics only (fallback path) ----------------
__global__ void k_geom(const float* __restrict__ dR, float* __restrict__ sh1){
  int e = blockIdx.x*256 + threadIdx.x;
  if (e >= NE) return;
  float x = dR[3*e+0], y = dR[3*e+1], z = dR[3*e+2];
  float r = sqrtf(x*x + y*y + z*z);
  float inv = 1.0f / fmaxf(r, 1e-6f);
  const float SQ3 = 1.7320508075688772f;
  sh1[3*e+0] = SQ3 * x * inv;
  sh1[3*e+1] = SQ3 * y * inv;
  sh1[3*e+2] = SQ3 * z * inv;
}

// ---------------- edge pre-permute (fast path): kills dependent gather chains ----
__global__ void k_prep(const float* __restrict__ dR, const int* __restrict__ senders,
                       const int* __restrict__ perm,
                       float* __restrict__ sh1, float* __restrict__ dRp,
                       int* __restrict__ sendp){
  int p = blockIdx.x*256 + threadIdx.x;
  if (p >= NE) return;
  int e = perm[p];
  float x = dR[3*e+0], y = dR[3*e+1], z = dR[3*e+2];
  dRp[3*p+0] = x; dRp[3*p+1] = y; dRp[3*p+2] = z;
  float r = sqrtf(x*x + y*y + z*z);
  float inv = 1.0f / fmaxf(r, 1e-6f);
  const float SQ3 = 1.7320508075688772f;
  sh1[3*p+0] = SQ3 * x * inv;
  sh1[3*p+1] = SQ3 * y * inv;
  sh1[3*p+2] = SQ3 * z * inv;
  sendp[p] = senders[e];
}

// ---------------- one-time weight transpose: W[i][e][o] -> W[i][o][e] ------------
__global__ void k_wt(const float* __restrict__ Wscs, const float* __restrict__ Wscv,
                     float* __restrict__ Wst, float* __restrict__ Wvt){
  int idx = blockIdx.x*256 + threadIdx.x;
  if (idx < 49152){                       // 2 layers x 64 x 4 x 96
    int l = idx/24576, r = idx - l*24576;
    int i = r/384; int rem = r - i*384; int e = rem/96; int o = rem - e*96;
    Wst[l*24576 + i*384 + o*4 + e] = Wscs[idx];
  } else if (idx < 49152 + 8192){         // 2 layers x 32 x 4 x 32
    int k = idx - 49152;
    int l = k/4096, r = k - l*4096;
    int i = r/128; int rem = r - i*128; int e = rem/32; int op = rem - e*32;
    Wvt[l*4096 + i*128 + op*4 + e] = Wscv[idx];
  }
}

// ---------------- node embedding ----------------
__global__ void k_embed(const float* __restrict__ nodes, const float* __restrict__ W,
                        float* __restrict__ s){
  int idx = blockIdx.x*256 + threadIdx.x;   // N*64 exact
  int n = idx>>6, o = idx&63;
  float a = nodes[n*4+0]*W[o] + nodes[n*4+1]*W[64+o]
          + nodes[n*4+2]*W[128+o] + nodes[n*4+3]*W[192+o];
  s[idx] = 0.5f*a;
}

// ---------------- counting sort of edges by receiver ----------------
__global__ void k_hist(const int* __restrict__ receivers, int* __restrict__ cnt){
  int e = blockIdx.x*256 + threadIdx.x;
  if (e < NE) atomicAdd(&cnt[receivers[e]], 1);
}

__global__ void k_scan(const int* __restrict__ cnt, int* __restrict__ row, int* __restrict__ cur){
  __shared__ int lsum[1024];
  int t = threadIdx.x;
  int base = t*20;
  int local[20];
  int s = 0;
  #pragma unroll
  for (int i=0;i<20;i++){
    int idx = base+i;
    int v = (idx<NN) ? cnt[idx] : 0;
    local[i] = s; s += v;
  }
  lsum[t] = s; __syncthreads();
  for (int off=1; off<1024; off<<=1){
    int v = (t>=off) ? lsum[t-off] : 0;
    __syncthreads();
    lsum[t] += v;
    __syncthreads();
  }
  int pre = (t>0) ? lsum[t-1] : 0;
  #pragma unroll
  for (int i=0;i<20;i++){
    int idx = base+i;
    if (idx<NN){ int r = pre+local[i]; row[idx]=r; cur[idx]=r; }
  }
  if (t==1023) row[NN] = lsum[1023];
}

__global__ void k_scatter(const int* __restrict__ receivers, int* __restrict__ cur,
                          int* __restrict__ perm){
  int e = blockIdx.x*256 + threadIdx.x;
  if (e < NE){
    int d = receivers[e];
    int p = atomicAdd(&cur[d], 1);
    perm[p] = e;
  }
}

// ---------------- per-layer node linears: 16 nodes/block, 4 nodes/wave ----------
// Weight loads batched x4 (round-10) -- 4 L2 loads in flight per chain.
__global__ void k_node(const float* __restrict__ s, const float* __restrict__ v,
                       const float* __restrict__ attrs,
                       const float* __restrict__ W1s, const float* __restrict__ W1v,
                       const float* __restrict__ Wscst, const float* __restrict__ Wscvt,
                       __half* __restrict__ s1, __half* __restrict__ v1,
                       float* __restrict__ scs, float* __restrict__ scv){
  __shared__ float ls[16][64];
  __shared__ float lv[16][96];
  __shared__ float la[16][4];
  int tid = threadIdx.x;
  int nb = blockIdx.x*16;   // 1250*16 = 20000 exact
  for (int i=tid;i<1024;i+=256) ls[i>>6][i&63] = s[(size_t)(nb+(i>>6))*64 + (i&63)];
  for (int i=tid;i<1536;i+=256){ int j=i/96, q=i-96*j; lv[j][q] = v[(size_t)(nb+j)*96+q]; }
  if (tid<64) la[tid>>2][tid&3] = attrs[(nb+(tid>>2))*4 + (tid&3)];
  __syncthreads();
  int w = tid>>6, q = tid&63;
  int jb = w*4;                       // this wave's 4 nodes: nb+jb .. nb+jb+3
  float laj[4][4];
  #pragma unroll
  for (int j=0;j<4;j++)
    #pragma unroll
    for (int e=0;e<4;e++) laj[j][e] = la[jb+j][e];

  // s1 = s @ W1s / 8  (loads batched x4)
  {
    float acc[4] = {0,0,0,0};
    for (int i=0;i<64;i+=4){
      float wv0 = W1s[(i+0)*64+q];
      float wv1 = W1s[(i+1)*64+q];
      float wv2 = W1s[(i+2)*64+q];
      float wv3 = W1s[(i+3)*64+q];
      #pragma unroll
      for (int j=0;j<4;j++){
        acc[j] = fmaf(ls[jb+j][i+0], wv0, acc[j]);
        acc[j] = fmaf(ls[jb+j][i+1], wv1, acc[j]);
        acc[j] = fmaf(ls[jb+j][i+2], wv2, acc[j]);
        acc[j] = fmaf(ls[jb+j][i+3], wv3, acc[j]);
      }
    }
    #pragma unroll
    for (int j=0;j<4;j++) s1[(size_t)(nb+jb+j)*64+q] = __float2half(acc[j]*0.125f);
  }
  // sc_s (two-stage, loads batched x4)
  #pragma unroll 1
  for (int o=q;o<96;o+=64){
    float t0[4]={0,0,0,0}, t1[4]={0,0,0,0}, t2[4]={0,0,0,0}, t3[4]={0,0,0,0};
    for (int i=0;i<64;i+=4){
      float4 wa = *(const float4*)(Wscst + (i+0)*384 + o*4);
      float4 wb = *(const float4*)(Wscst + (i+1)*384 + o*4);
      float4 wc = *(const float4*)(Wscst + (i+2)*384 + o*4);
      float4 wd = *(const float4*)(Wscst + (i+3)*384 + o*4);
      #pragma unroll
      for (int j=0;j<4;j++){
        float s0 = ls[jb+j][i+0], s1v = ls[jb+j][i+1];
        float s2 = ls[jb+j][i+2], s3 = ls[jb+j][i+3];
        t0[j] = fmaf(s0, wa.x, t0[j]); t1[j] = fmaf(s0, wa.y, t1[j]);
        t2[j] = fmaf(s0, wa.z, t2[j]); t3[j] = fmaf(s0, wa.w, t3[j]);
        t0[j] = fmaf(s1v, wb.x, t0[j]); t1[j] = fmaf(s1v, wb.y, t1[j]);
        t2[j] = fmaf(s1v, wb.z, t2[j]); t3[j] = fmaf(s1v, wb.w, t3[j]);
        t0[j] = fmaf(s2, wc.x, t0[j]); t1[j] = fmaf(s2, wc.y, t1[j]);
        t2[j] = fmaf(s2, wc.z, t2[j]); t3[j] = fmaf(s2, wc.w, t3[j]);
        t0[j] = fmaf(s3, wd.x, t0[j]); t1[j] = fmaf(s3, wd.y, t1[j]);
        t2[j] = fmaf(s3, wd.z, t2[j]); t3[j] = fmaf(s3, wd.w, t3[j]);
      }
    }
    #pragma unroll
    for (int j=0;j<4;j++){
      float acc = t0[j]*laj[j][0] + t1[j]*laj[j][1]
                + t2[j]*laj[j][2] + t3[j]*laj[j][3];
      scs[(size_t)(nb+jb+j)*96+o] = acc*0.0625f;
    }
  }
  // v1 (loads batched x4)
  #pragma unroll 1
  for (int f=q;f<96;f+=64){
    int op=f/3, c=f-3*op;
    float acc[4] = {0,0,0,0};
    for (int i=0;i<32;i+=4){
      float wv0 = W1v[(i+0)*32+op];
      float wv1 = W1v[(i+1)*32+op];
      float wv2 = W1v[(i+2)*32+op];
      float wv3 = W1v[(i+3)*32+op];
      #pragma unroll
      for (int j=0;j<4;j++){
        acc[j] = fmaf(lv[jb+j][(i+0)*3+c], wv0, acc[j]);
        acc[j] = fmaf(lv[jb+j][(i+1)*3+c], wv1, acc[j]);
        acc[j] = fmaf(lv[jb+j][(i+2)*3+c], wv2, acc[j]);
        acc[j] = fmaf(lv[jb+j][(i+3)*3+c], wv3, acc[j]);
      }
    }
    #pragma unroll
    for (int j=0;j<4;j++) v1[(size_t)(nb+jb+j)*96+f] = __float2half(acc[j]*0.17677669529663687f);
  }
  // sc_v (two-stage, loads batched x4)
  #pragma unroll 1
  for (int f=q;f<96;f+=64){
    int op=f/3, c=f-3*op;
    float t0[4]={0,0,0,0}, t1[4]={0,0,0,0}, t2[4]={0,0,0,0}, t3[4]={0,0,0,0};
    for (int i=0;i<32;i+=4){
      float4 wa = *(const float4*)(Wscvt + (i+0)*128 + op*4);
      float4 wb = *(const float4*)(Wscvt + (i+1)*128 + op*4);
      float4 wc = *(const float4*)(Wscvt + (i+2)*128 + op*4);
      float4 wd = *(const float4*)(Wscvt + (i+3)*128 + op*4);
      #pragma unroll
      for (int j=0;j<4;j++){
        float v0 = lv[jb+j][(i+0)*3+c], v1v = lv[jb+j][(i+1)*3+c];
        float v2 = lv[jb+j][(i+2)*3+c], v3 = lv[jb+j][(i+3)*3+c];
        t0[j] = fmaf(v0, wa.x, t0[j]); t1[j] = fmaf(v0, wa.y, t1[j]);
        t2[j] = fmaf(v0, wa.z, t2[j]); t3[j] = fmaf(v0, wa.w, t3[j]);
        t0[j] = fmaf(v1v, wb.x, t0[j]); t1[j] = fmaf(v1v, wb.y, t1[j]);
        t2[j] = fmaf(v1v, wb.z, t2[j]); t3[j] = fmaf(v1v, wb.w, t3[j]);
        t0[j] = fmaf(v2, wc.x, t0[j]); t1[j] = fmaf(v2, wc.y, t1[j]);
        t2[j] = fmaf(v2, wc.z, t2[j]); t3[j] = fmaf(v2, wc.w, t3[j]);
        t0[j] = fmaf(v3, wd.x, t0[j]); t1[j] = fmaf(v3, wd.y, t1[j]);
        t2[j] = fmaf(v3, wd.z, t2[j]); t3[j] = fmaf(v3, wd.w, t3[j]);
      }
    }
    #pragma unroll
    for (int j=0;j<4;j++){
      float acc = t0[j]*laj[j][0] + t1[j]*laj[j][1]
                + t2[j]*laj[j][2] + t3[j]*laj[j][3];
      scv[(size_t)(nb+jb+j)*96+f] = acc*0.08838834764831845f;
    }
  }
}

// ---------------- edge MLP: persistent-weight multi-tile version -----------------
// Round-13: R2 stored o-major (wgt2t[o][kp], row stride 36 dwords) so phase C's
// B-fragments are TWO contiguous ds_read_b128 per ot instead of 8 ds_read_b32 --
// 96 -> 24 LDS reads per wave-tile (the largest instruction population). Bank-
// optimal: each b128 wave-read tiles all 32 banks at the 1KB/wave minimum.
#define W2S 36
#define HT2S 68
__launch_bounds__(256, 4)
__global__ void k_edgew(const float* __restrict__ dRp,
                        const int* __restrict__ row, int n0, int n1, int cap,
                        const float* __restrict__ R0, const float* __restrict__ R1,
                        const float* __restrict__ R2,
                        __half* __restrict__ wbuf){
  __shared__ __align__(16) f16x2 hT2[32*HT2S];  // 8.7 KB: [kpair][e] stride 68; rb staging (fp32 view) / h1 / h2
  __shared__ __align__(16) float r0s[512];      // 2 KB: R0 fp32
  __shared__ __align__(16) f16x2 wgt2[192*W2S]; // 27 KB: R2 o-major [o][kp], persistent
  int tid = threadIdx.x;
  int p0 = row[n0], p1 = row[n1];
  int vmax = p1 - p0; if (vmax > cap) vmax = cap;
  int ntiles = (vmax + 63) >> 6;

  int eg = tid & 15, e0 = eg*4;
  int jg = tid >> 4, j0 = jg*4;
  int wv = tid >> 6;
  int ln = tid & 63;
  int col = ln & 15;
  int quad = ln >> 4;

  // ---- persistent staging (once per block) ----
  if (tid < 128) ((float4*)r0s)[tid] = ((const float4*)R0)[tid];
  for (int i=tid; i<6144; i+=256){
    int kp = i/192, o = i-192*kp;     // coalesced R2 reads; o-major LDS writes
    wgt2[o*W2S + kp] = pack2f(R2[(2*kp)*192 + o], R2[(2*kp+1)*192 + o]);
  }
  // R1 A-frags direct from global into registers
  union { uint4 u; f16x8 v; } rA0, rA1;
  {
    int jA = 16*wv + col;
    rA0.u.x = packu2f(R1[(8*quad+0)*64 + jA], R1[(8*quad+1)*64 + jA]);
    rA0.u.y = packu2f(R1[(8*quad+2)*64 + jA], R1[(8*quad+3)*64 + jA]);
    rA0.u.z = packu2f(R1[(8*quad+4)*64 + jA], R1[(8*quad+5)*64 + jA]);
    rA0.u.w = packu2f(R1[(8*quad+6)*64 + jA], R1[(8*quad+7)*64 + jA]);
    rA1.u.x = packu2f(R1[(32+8*quad+0)*64 + jA], R1[(32+8*quad+1)*64 + jA]);
    rA1.u.y = packu2f(R1[(32+8*quad+2)*64 + jA], R1[(32+8*quad+3)*64 + jA]);
    rA1.u.z = packu2f(R1[(32+8*quad+4)*64 + jA], R1[(32+8*quad+5)*64 + jA]);
    rA1.u.w = packu2f(R1[(32+8*quad+6)*64 + jA], R1[(32+8*quad+7)*64 + jA]);
  }
  // visibility of r0s/wgt2 covered by the loop-top barrier of the first tile

  for (int tile = blockIdx.x; tile < ntiles; tile += gridDim.x){
    int tbase = tile*64;
    int vcnt = vmax - tbase; if (vcnt > 64) vcnt = 64;

    __syncthreads();   // [A] staging visible / prev tile's phase-C hT2 reads done
    // stage rb for the 64 edges into hT2 region (fp32 view, rows k<8)
    float* hTf = (float*)hT2;
    if (tid < 64){
      float rbv[8];
      if (tid < vcnt){
        bessel8(dRp, p0 + tbase + tid, rbv);
      } else {
        #pragma unroll
        for (int k=0;k<8;k++) rbv[k]=0.0f;
      }
      #pragma unroll
      for (int k=0;k<8;k++) hTf[k*HT2S + tid] = rbv[k];
    }
    __syncthreads();   // [B]

    // read rb tile into regs (before overwriting hT2 with h1 pairs)
    float rb[8][4];
    {
      const float4* hTf4 = (const float4*)hTf;
      #pragma unroll
      for (int k=0;k<8;k++){
        float4 v = hTf4[k*17 + eg];
        rb[k][0]=v.x; rb[k][1]=v.y; rb[k][2]=v.z; rb[k][3]=v.w;
      }
    }
    // phase A: h1 tile (fp32 math, tiny K=8)
    float a[4][4];
    #pragma unroll
    for (int j=0;j<4;j++)
      #pragma unroll
      for (int e=0;e<4;e++) a[j][e]=0.0f;
    {
      const float4* r0s4 = (const float4*)r0s;
      #pragma unroll
      for (int k=0;k<8;k++){
        float4 w = r0s4[k*16 + jg];
        float wj[4] = {w.x,w.y,w.z,w.w};
        #pragma unroll
        for (int j=0;j<4;j++)
          #pragma unroll
          for (int e=0;e<4;e++) a[j][e] = fmaf(rb[k][e], wj[j], a[j][e]);
      }
    }
    #pragma unroll
    for (int j=0;j<4;j++)
      #pragma unroll
      for (int e=0;e<4;e++) a[j][e] = silu_f(a[j][e]*0.3535533905932738f);
    __syncthreads();   // [C] all rb reads complete
    // write h1 as k-pairs: rows j0/2, j0/2+1 of hT2
    #pragma unroll
    for (int jp=0;jp<2;jp++){
      union {uint4 u; f16x2 h[4];} U;
      #pragma unroll
      for (int e=0;e<4;e++) U.h[e] = pack2f(a[2*jp][e], a[2*jp+1][e]);
      *(uint4*)(hT2 + (j0/2 + jp)*HT2S + e0) = U.u;
    }
    __syncthreads();   // [D]

    // phase B via MFMA: wave wv owns j-tile [16*wv,16*wv+16), loops 4 e-tiles.
    {
      const unsigned int* hT2u = (const unsigned int*)hT2;
      f32x4 accB[4];
      #pragma unroll
      for (int nt=0; nt<4; nt++){
        union { uint4 u; f16x8 v; } B0, B1;
        int eB = 16*nt + col;
        B0.u.x = hT2u[(4*quad+0)*HT2S + eB];
        B0.u.y = hT2u[(4*quad+1)*HT2S + eB];
        B0.u.z = hT2u[(4*quad+2)*HT2S + eB];
        B0.u.w = hT2u[(4*quad+3)*HT2S + eB];
        B1.u.x = hT2u[(16+4*quad+0)*HT2S + eB];
        B1.u.y = hT2u[(16+4*quad+1)*HT2S + eB];
        B1.u.z = hT2u[(16+4*quad+2)*HT2S + eB];
        B1.u.w = hT2u[(16+4*quad+3)*HT2S + eB];
        f32x4 acc = {0.0f,0.0f,0.0f,0.0f};
        acc = __builtin_amdgcn_mfma_f32_16x16x32_f16(rA0.v, B0.v, acc, 0, 0, 0);
        acc = __builtin_amdgcn_mfma_f32_16x16x32_f16(rA1.v, B1.v, acc, 0, 0, 0);
        accB[nt] = acc;
      }
      __syncthreads();   // [E] all h1 (hT2) reads complete
      // silu + pack + write h2^T as k-pairs
      #pragma unroll
      for (int nt=0; nt<4; nt++){
        float h0 = silu_f(accB[nt][0]*0.125f);
        float h1v = silu_f(accB[nt][1]*0.125f);
        float h2v = silu_f(accB[nt][2]*0.125f);
        float h3v = silu_f(accB[nt][3]*0.125f);
        hT2[(8*wv + 2*quad + 0)*HT2S + 16*nt + col] = pack2f(h0, h1v);
        hT2[(8*wv + 2*quad + 1)*HT2S + 16*nt + col] = pack2f(h2v, h3v);
      }
    }
    __syncthreads();   // [F] h2 visible

    // phase C via MFMA: wave wv handles edges [16*wv, 16*wv+16)
    {
      const unsigned int* hT2u = (const unsigned int*)hT2;
      const unsigned int* wgt2u = (const unsigned int*)wgt2;
      int eA = 16*wv + col;     // A's m index
      union { uint4 u; f16x8 v; } A0, A1;
      A0.u.x = hT2u[(4*quad+0)*HT2S + eA];
      A0.u.y = hT2u[(4*quad+1)*HT2S + eA];
      A0.u.z = hT2u[(4*quad+2)*HT2S + eA];
      A0.u.w = hT2u[(4*quad+3)*HT2S + eA];
      A1.u.x = hT2u[(16+4*quad+0)*HT2S + eA];
      A1.u.y = hT2u[(16+4*quad+1)*HT2S + eA];
      A1.u.z = hT2u[(16+4*quad+2)*HT2S + eA];
      A1.u.w = hT2u[(16+4*quad+3)*HT2S + eA];
      int erow = 16*wv + 4*quad;           // D rows: erow+0..3
      #pragma unroll
      for (int ot=0; ot<12; ot++){
        int o = 16*ot + col;
        union { uint4 u; f16x8 v; } B0, B1;
        B0.u = *(const uint4*)(wgt2u + o*W2S + 4*quad);
        B1.u = *(const uint4*)(wgt2u + o*W2S + 16 + 4*quad);
        f32x4 acc = {0.0f,0.0f,0.0f,0.0f};
        acc = __builtin_amdgcn_mfma_f32_16x16x32_f16(A0.v, B0.v, acc, 0, 0, 0);
        acc = __builtin_amdgcn_mfma_f32_16x16x32_f16(A1.v, B1.v, acc, 0, 0, 0);
        // direct predicated stores (uniform-true branch for full tiles)
        #pragma unroll
        for (int r=0;r<4;r++){
          int eib = erow + r;
          if (eib < vcnt)
            wbuf[(size_t)(tbase+eib)*192 + o] = __float2half(acc[r]);
        }
      }
    }
  }
}

// ---------------- gather: role-split + 8-deep load batching, spill-free ---------
__launch_bounds__(128, 4)
__global__ void k_gather(const __half* __restrict__ wbuf,
                         const int* __restrict__ row, const int* __restrict__ sendp,
                         const float* __restrict__ sh1,
                         const __half* __restrict__ s1, const __half* __restrict__ v1,
                         int n0, int cap,
                         float* __restrict__ a_s, float* __restrict__ a_v){
  __shared__ int   srcs[ECAP];
  __shared__ float sh1r[ECAP*3];
  int n = n0 + blockIdx.x;
  int t = threadIdx.x;
  int pc0 = row[n0];
  int p0 = row[n], p1 = row[n+1];
  int pmax = pc0 + cap; if (p1 > pmax) p1 = pmax;

  int iv = (t - 64) >> 1;          // 0..31 for vrole
  bool even = ((t & 1) == 0);

  float acs = 0.0f, av0 = 0.0f, av1 = 0.0f, av2 = 0.0f;

  for (int base = p0; base < p1; base += ECAP){
    int bc = p1 - base; if (bc > ECAP) bc = ECAP;
    __syncthreads();   // protect LDS reuse across batches
    if (t < bc){
      srcs[t] = sendp[base + t];
      sh1r[3*t+0] = sh1[3*(base+t)+0];
      sh1r[3*t+1] = sh1[3*(base+t)+1];
      sh1r[3*t+2] = sh1[3*(base+t)+2];
    }
    __syncthreads();
    const __half* wb = wbuf + (size_t)(base - pc0)*192;
    if (t < 64){
      int o = t;
      int j = 0;
      for (; j + 8 <= bc; j += 8){
        float sv[8], w1[8], w2[8];
        #pragma unroll
        for (int u=0;u<8;u++){
          const __half* wr = wb + (j+u)*192;
          sv[u] = __half2float(s1[(size_t)srcs[j+u]*64 + o]);
          w1[u] = __half2float(wr[o]);
          w2[u] = __half2float(wr[64 + o]);
        }
        #pragma unroll
        for (int u=0;u<8;u++){
          acs = fmaf(w1[u], sv[u], acs);
          float uu = w2[u] * sv[u];
          av0 = fmaf(uu, sh1r[3*(j+u)+0], av0);
          av1 = fmaf(uu, sh1r[3*(j+u)+1], av1);
          av2 = fmaf(uu, sh1r[3*(j+u)+2], av2);
        }
      }
      for (; j < bc; ++j){
        const __half* wr = wb + j*192;
        float sv = __half2float(s1[(size_t)srcs[j]*64 + o]);
        float w1v = __half2float(wr[o]);
        float w2v = __half2float(wr[64 + o]);
        acs = fmaf(w1v, sv, acs);
        float uu = w2v * sv;
        av0 = fmaf(uu, sh1r[3*j+0], av0);
        av1 = fmaf(uu, sh1r[3*j+1], av1);
        av2 = fmaf(uu, sh1r[3*j+2], av2);
      }
    } else {
      int j = 0;
      for (; j + 8 <= bc; j += 8){
        float v0[8], vc1[8], vc2[8], w3[8], w4[8];
        #pragma unroll
        for (int u=0;u<8;u++){
          const __half* wr = wb + (j+u)*192;
          const __half* vr = v1 + (size_t)srcs[j+u]*96 + 3*iv;
          v0[u]  = __half2float(vr[0]);
          vc1[u] = __half2float(vr[1]);
          vc2[u] = __half2float(vr[2]);
          w3[u]  = __half2float(wr[128 + iv]);
          w4[u]  = __half2float(wr[160 + iv]);
        }
        #pragma unroll
        for (int u=0;u<8;u++){
          if (even){
            float dv = v0[u]*sh1r[3*(j+u)+0] + vc1[u]*sh1r[3*(j+u)+1] + vc2[u]*sh1r[3*(j+u)+2];
            acs = fmaf(w4[u], dv, acs);
            av0 = fmaf(w3[u], v0[u], av0);
          } else {
            av1 = fmaf(w3[u], vc1[u], av1);
            av2 = fmaf(w3[u], vc2[u], av2);
          }
        }
      }
      for (; j < bc; ++j){
        const __half* wr = wb + j*192;
        const __half* vr = v1 + (size_t)srcs[j]*96 + 3*iv;
        float v0 = __half2float(vr[0]);
        float vc1 = __half2float(vr[1]);
        float vc2 = __half2float(vr[2]);
        float w3 = __half2float(wr[128 + iv]);
        if (even){
          float w4 = __half2float(wr[160 + iv]);
          float dv = v0*sh1r[3*j+0] + vc1*sh1r[3*j+1] + vc2*sh1r[3*j+2];
          acs = fmaf(w4, dv, acs);
          av0 = fmaf(w3, v0, av0);
        } else {
          av1 = fmaf(w3, vc1, av1);
          av2 = fmaf(w3, vc2, av2);
        }
      }
    }
  }

  if (t < 64){
    a_s[(size_t)n*96 + t] = 0.03125f*acs;              // (1/8)*(1/sqrt(16))
    a_v[(size_t)n*288 + 3*t + 0] = 0.03125f*av0;
    a_v[(size_t)n*288 + 3*t + 1] = 0.03125f*av1;
    a_v[(size_t)n*288 + 3*t + 2] = 0.03125f*av2;
  } else if (even){
    a_s[(size_t)n*96 + 64 + iv] = 0.018042195912175807f*acs;   // 0.03125/sqrt(3)
    a_v[(size_t)n*288 + 192 + 3*iv + 0] = 0.03125f*av0;
  } else {
    a_v[(size_t)n*288 + 192 + 3*iv + 1] = 0.03125f*av1;
    a_v[(size_t)n*288 + 192 + 3*iv + 2] = 0.03125f*av2;
  }
}

// ---------------- fallback: atomic edge kernel (only if ws too small) ----------------
__device__ __forceinline__ void mlp_h2(const float* __restrict__ R0,
                                       const float* lR1, const float rb[8],
                                       float h2[64]){
  float h1[64];
  #pragma unroll
  for (int j=0;j<64;j+=4){
    float a0=0,a1=0,a2=0,a3=0;
    #pragma unroll
    for (int k=0;k<8;k++){
      float r = rb[k];
      const float* wp = R0 + k*64 + j;
      a0 = fmaf(r, wp[0], a0); a1 = fmaf(r, wp[1], a1);
      a2 = fmaf(r, wp[2], a2); a3 = fmaf(r, wp[3], a3);
    }
    h1[j+0]=silu_f(a0*0.3535533905932738f);
    h1[j+1]=silu_f(a1*0.3535533905932738f);
    h1[j+2]=silu_f(a2*0.3535533905932738f);
    h1[j+3]=silu_f(a3*0.3535533905932738f);
  }
  #pragma unroll
  for (int j=0;j<64;j+=4){
    float a0=0,a1=0,a2=0,a3=0;
    #pragma unroll
    for (int k=0;k<64;k++){
      float h = h1[k];
      float4 w4 = *(const float4*)(lR1 + k*64 + j);
      a0 = fmaf(h,w4.x,a0); a1 = fmaf(h,w4.y,a1);
      a2 = fmaf(h,w4.z,a2); a3 = fmaf(h,w4.w,a3);
    }
    h2[j+0]=silu_f(a0*0.125f);
    h2[j+1]=silu_f(a1*0.125f);
    h2[j+2]=silu_f(a2*0.125f);
    h2[j+3]=silu_f(a3*0.125f);
  }
}

__launch_bounds__(256, 2)
__global__ void k_edge(const float* __restrict__ dR, const float* __restrict__ sh1,
                       const int* __restrict__ senders, const int* __restrict__ receivers,
                       const __half* __restrict__ s1, const __half* __restrict__ v1,
                       const float* __restrict__ R0, const float* __restrict__ R1,
                       const float* __restrict__ R2,
                       float* __restrict__ a_s, float* __restrict__ a_v){
  __shared__ __align__(16) float lR1[64*64];
  __shared__ __align__(16) float lR2[64*192];
  int tid = threadIdx.x;
  for (int i=tid;i<4096;i+=256)  lR1[i]=R1[i];
  for (int i=tid;i<12288;i+=256) lR2[i]=R2[i];
  __syncthreads();
  int e = blockIdx.x*256 + tid;
  float rb[8];
  bessel8(dR, e, rb);
  float h2[64];
  mlp_h2(R0, lR1, rb, h2);
  int src = senders[e], dst = receivers[e];
  float sx=sh1[3*e+0], sy=sh1[3*e+1], sz=sh1[3*e+2];
  const __half* srow = s1 + (size_t)src*64;
  const __half* vrow = v1 + (size_t)src*96;
  float* asr = a_s + (size_t)dst*96;
  float* avr = a_v + (size_t)dst*288;
  #pragma unroll 1
  for (int o=0;o<64;o+=4){
    float w10=0,w11=0,w12=0,w13=0, w20=0,w21=0,w22=0,w23=0;
    #pragma unroll
    for (int k=0;k<64;k++){
      float h = h2[k];
      float4 wa = *(const float4*)(lR2 + k*192 + o);
      float4 wb = *(const float4*)(lR2 + k*192 + 64 + o);
      w10=fmaf(h,wa.x,w10); w11=fmaf(h,wa.y,w11); w12=fmaf(h,wa.z,w12); w13=fmaf(h,wa.w,w13);
      w20=fmaf(h,wb.x,w20); w21=fmaf(h,wb.y,w21); w22=fmaf(h,wb.z,w22); w23=fmaf(h,wb.w,w23);
    }
    float sev[4] = {__half2float(srow[o+0]), __half2float(srow[o+1]),
                    __half2float(srow[o+2]), __half2float(srow[o+3])};
    float w1a[4] = {w10,w11,w12,w13};
    float w2a[4] = {w20,w21,w22,w23};
    #pragma unroll
    for (int u=0;u<4;u++){
      atomicAdd(asr+o+u, 0.03125f*w1a[u]*sev[u]);
      float m = 0.03125f*w2a[u]*sev[u];
      atomicAdd(avr+(o+u)*3+0, m*sx);
      atomicAdd(avr+(o+u)*3+1, m*sy);
      atomicAdd(avr+(o+u)*3+2, m*sz);
    }
  }
  #pragma unroll 1
  for (int i0=0;i0<32;i0+=4){
    float w30=0,w31=0,w32=0,w33=0, w40=0,w41=0,w42=0,w43=0;
    #pragma unroll
    for (int k=0;k<64;k++){
      float h = h2[k];
      float4 wa = *(const float4*)(lR2 + k*192 + 128 + i0);
      float4 wb = *(const float4*)(lR2 + k*192 + 160 + i0);
      w30=fmaf(h,wa.x,w30); w31=fmaf(h,wa.y,w31); w32=fmaf(h,wa.z,w32); w33=fmaf(h,wa.w,w33);
      w40=fmaf(h,wb.x,w40); w41=fmaf(h,wb.y,w41); w42=fmaf(h,wb.z,w42); w43=fmaf(h,wb.w,w43);
    }
    float w3a[4] = {w30,w31,w32,w33};
    float w4a[4] = {w40,w41,w42,w43};
    #pragma unroll
    for (int u=0;u<4;u++){
      int i = i0+u;
      float vx=__half2float(vrow[3*i+0]), vy=__half2float(vrow[3*i+1]), vz=__half2float(vrow[3*i+2]);
      float dv = vx*sx + vy*sy + vz*sz;
      atomicAdd(asr+64+i, 0.018042195912175807f*w4a[u]*dv);
      float m3 = 0.03125f*w3a[u];
      atomicAdd(avr+(64+i)*3+0, m3*vx);
      atomicAdd(avr+(64+i)*3+1, m3*vy);
      atomicAdd(avr+(64+i)*3+2, m3*vz);
    }
  }
}

// ---------------- per-layer output transform: o_s, o_v, gating ----------------
__launch_bounds__(256, 4)
__global__ void k_out(const float* __restrict__ a_s, const float* __restrict__ a_v,
                      const float* __restrict__ scs, const float* __restrict__ scv,
                      const float* __restrict__ W2s, const float* __restrict__ W2v,
                      float* __restrict__ s_out, float* __restrict__ v_out){
  __shared__ float las[16][96];
  __shared__ float lav[16][288];
  __shared__ float los[16][96];
  int tid = threadIdx.x;
  int nb = blockIdx.x*16;   // 1250*16 = 20000 exact
  for (int i=tid;i<1536;i+=256){ int j=i/96,  q=i-96*j;  las[j][q] = a_s[(size_t)(nb+j)*96 +q]; }
  for (int i=tid;i<4608;i+=256){ int j=i/288, q=i-288*j; lav[j][q] = a_v[(size_t)(nb+j)*288+q]; }
  __syncthreads();
  int w = tid>>6, q = tid&63;
  int jb = w*4;                       // this wave's 4 nodes: nb+jb .. nb+jb+3

  // o_s = a_s @ W2s * scale + scs   (outputs o = q and q+64, wave-private los)
  #pragma unroll 1
  for (int o=q; o<96; o+=64){
    float acc[4] = {0,0,0,0};
    for (int i=0;i<96;i++){
      float wv = W2s[i*96+o];
      #pragma unroll
      for (int j=0;j<4;j++) acc[j] = fmaf(las[jb+j][i], wv, acc[j]);
    }
    #pragma unroll
    for (int j=0;j<4;j++)
      los[jb+j][o] = acc[j]*0.10206207261596575f + scs[(size_t)(nb+jb+j)*96+o];
  }
  __syncthreads();   // (wave-private in fact; barrier keeps LDS ordering simple)

  // s_out = silu(o_s[:64])
  #pragma unroll
  for (int j=0;j<4;j++) s_out[(size_t)(nb+jb+j)*64+q] = silu_f(los[jb+j][q]);

  // o_v = a_v @ W2v * scale + scv, gated by silu(o_s[64+op])
  #pragma unroll 1
  for (int f=q; f<96; f+=64){
    int op=f/3, c=f-3*op;
    float acc[4] = {0,0,0,0};
    for (int i=0;i<96;i++){
      float wv = W2v[i*32+op];
      #pragma unroll
      for (int j=0;j<4;j++) acc[j] = fmaf(lav[jb+j][i*3+c], wv, acc[j]);
    }
    #pragma unroll
    for (int j=0;j<4;j++){
      float ov = acc[j]*0.10206207261596575f + scv[(size_t)(nb+jb+j)*96+f];
      float g = silu_f(los[jb+j][64+op]);
      v_out[(size_t)(nb+jb+j)*96+f] = ov*g;
    }
  }
}

// ---------------- final heads: energy + mags ----------------
__global__ void k_final(const float* __restrict__ s, const float* __restrict__ nodes,
                        const int* __restrict__ n_node,
                        const float* __restrict__ Wen1, const float* __restrict__ Wen2,
                        const float* __restrict__ Wm1, const float* __restrict__ Wm2,
                        const float* __restrict__ scale_occ, const float* __restrict__ shift_occ,
                        const float* __restrict__ escale, const float* __restrict__ eshift,
                        float* __restrict__ out){
  __shared__ float eacc[NG];
  __shared__ int goff[NG+1];
  int tid = threadIdx.x;
  if (tid < NG) eacc[tid] = 0.0f;
  if (tid == 0){
    int c = 0; goff[0] = 0;
    for (int g=0; g<NG; g++){ c += n_node[g]; goff[g+1] = c; }
  }
  __syncthreads();
  int n = blockIdx.x*256 + tid;
  if (n < NN){
    float sv[64];
    #pragma unroll
    for (int i=0;i<64;i++) sv[i]=s[(size_t)n*64+i];
    float en=0.0f, m0=0.0f, m1=0.0f;
    #pragma unroll 1
    for (int jj=0;jj<32;jj++){
      float he=0.0f, hm=0.0f;
      #pragma unroll
      for (int i=0;i<64;i++){
        he = fmaf(sv[i], Wen1[i*32+jj], he);
        hm = fmaf(sv[i], Wm1[i*32+jj], hm);
      }
      he *= 0.125f; hm *= 0.125f;
      en = fmaf(he, Wen2[jj], en);
      m0 = fmaf(hm, Wm2[jj*2+0], m0);
      m1 = fmaf(hm, Wm2[jj*2+1], m1);
    }
    const float INVS32 = 0.17677669529663687f;
    en *= INVS32; m0 *= INVS32; m1 *= INVS32;
    en = escale[0]*en + eshift[0];
    int g = 0;
    for (int gg=0; gg<NG; gg++) if (n >= goff[gg+1]) g = gg+1;
    atomicAdd(&eacc[g], en);
    float nx=nodes[n*4+0], ny=nodes[n*4+1], nz=nodes[n*4+2];
    float sc0 = nx*scale_occ[0] + ny*scale_occ[2] + nz*scale_occ[4];
    float sc1 = nx*scale_occ[1] + ny*scale_occ[3] + nz*scale_occ[5];
    float sf0 = nx*shift_occ[0] + ny*shift_occ[2] + nz*shift_occ[4];
    float sf1 = nx*shift_occ[1] + ny*shift_occ[3] + nz*shift_occ[5];
    out[16 + n*2 + 0] = sc0*m0 + sf0;
    out[16 + n*2 + 1] = sc1*m1 + sf1;
  }
  __syncthreads();
  if (tid < NG) atomicAdd(&out[tid], eacc[tid]);
}

extern "C" void kernel_launch(void* const* d_in, const int* in_sizes, int n_in,
                              void* d_out, int out_size, void* d_ws, size_t ws_size,
                              hipStream_t stream){
  const float* nodes   = (const float*)d_in[0];
  const float* dR      = (const float*)d_in[1];
  const int*  senders  = (const int*)d_in[2];
  const int*  receivers= (const int*)d_in[3];
  const int*  n_node   = (const int*)d_in[4];
  const float* W_embed = (const float*)d_in[5];
  const float* W_sc_s  = (const float*)d_in[6];
  const float* W_sc_v  = (const float*)d_in[7];
  const float* W_l1_s  = (const float*)d_in[8];
  const float* W_l1_v  = (const float*)d_in[9];
  const float* Wr0     = (const float*)d_in[10];
  const float* Wr1     = (const float*)d_in[11];
  const float* Wr2     = (const float*)d_in[12];
  const float* W_l2_s  = (const float*)d_in[13];
  const float* W_l2_v  = (const float*)d_in[14];
  const float* W_en1   = (const float*)d_in[15];
  const float* W_en2   = (const float*)d_in[16];
  const float* W_mag1  = (const float*)d_in[17];
  const float* W_mag2  = (const float*)d_in[18];
  const float* scale_occ = (const float*)d_in[19];
  const float* shift_occ = (const float*)d_in[20];
  const float* escale  = (const float*)d_in[21];
  const float* eshift  = (const float*)d_in[22];
  float* out = (float*)d_out;
  float* ws  = (float*)d_ws;

  // ---- workspace map (float-index offsets) ----
  float*  sh1  = ws + 0;         // NE*3 f32 (PERMUTED order in fast path)
  float*  sA   = ws + 960000;    // NN*64 f32
  float*  vA   = ws + 2240000;   // NN*96 f32
  __half* s1h  = (__half*)(ws + 4160000);   // NN*64 halves = 640,000 f32
  __half* v1h  = (__half*)(ws + 4800000);   // NN*96 halves = 960,000 f32
  float*  dRp  = ws + 5760000;   // NE*3 f32 permuted dR = 960,000 f32
  int*    sendp= (int*)(ws + 6720000);      // NE ints = 320,000 -> ends 7,040,000
  float*  Wst  = ws + 7040000;   // 2*24576 = 49,152 transposed W_sc_s
  float*  Wvt  = ws + 7089152;   // 2*4096  =  8,192 transposed W_sc_v -> ends 7,097,344
  float*  scs  = ws + 7360000;   // 1,920,000 f32
  float*  scv  = ws + 9280000;   // 1,920,000 f32
  float*  a_s  = ws + 11200000;  // 1,920,000 f32
  float*  a_v  = ws + 13120000;  // 5,760,000 f32 -> ends 18,880,000
  int*    cnt  = (int*)(ws + 18880000);  // 20,000
  int*    row  = (int*)(ws + 18900000);  // 20,001
  int*    cur  = (int*)(ws + 18920004);  // 20,000
  int*    perm = (int*)(ws + 18940004);  // 320,000 -> ends 19,260,004
  __half* wbuf = (__half*)(ws + 19260008); // capacity-adaptive fp16, 16B-aligned

  size_t wsf = ws_size / 4;
  // fp16 wbuf: 192 halves = 384 B per edge
  size_t cap_edges = (wsf > 19260008) ? ((wsf - 19260008)*4) / 384 : 0;
  if (cap_edges > 128) cap_edges -= 64;   // slack for 64-edge tile granularity
  const bool fast = cap_edges >= 4096;
  int cap = (int)((cap_edges > (size_t)NE) ? (size_t)NE + 8192 : cap_edges);
  // single chunk when wbuf can hold ALL edges; else the statistical heuristic.
  int npc;
  if (cap_edges > (size_t)NE){
    npc = NN;
  } else {
    npc = (int)(cap / 20); if (npc < 1) npc = 1; if (npc > NN) npc = NN;
  }
  int nchunk = (NN + npc - 1) / npc;

  hipMemsetAsync(vA, 0, (size_t)NN*96*sizeof(float), stream);   // v starts at zero
  hipMemsetAsync(out, 0, 16*sizeof(float), stream);             // energy accumulators

  k_embed<<<5000, 256, 0, stream>>>(nodes, W_embed, sA);
  k_wt<<<225, 256, 0, stream>>>(W_sc_s, W_sc_v, Wst, Wvt);

  if (fast){
    hipMemsetAsync(cnt, 0, NN*sizeof(int), stream);
    k_hist<<<1250, 256, 0, stream>>>(receivers, cnt);
    k_scan<<<1, 1024, 0, stream>>>(cnt, row, cur);
    k_scatter<<<1250, 256, 0, stream>>>(receivers, cur, perm);
    k_prep<<<1250, 256, 0, stream>>>(dR, senders, perm, sh1, dRp, sendp);
  } else {
    k_geom<<<1250, 256, 0, stream>>>(dR, sh1);
  }

  for (int l=0; l<2; l++){
    k_node<<<1250, 256, 0, stream>>>(sA, vA, nodes,
                                     W_l1_s + l*4096, W_l1_v + l*1024,
                                     Wst + l*24576, Wvt + l*4096,
                                     s1h, v1h, scs, scv);
    if (fast){
      for (int ck=0; ck<nchunk; ck++){
        int n0 = ck*npc;
        int n1 = n0 + npc; if (n1 > NN) n1 = NN;
        int cover = (n1-n0)*17 + 4096; if (cover > cap) cover = cap;
        int ntile_ub = (cover+63)/64;
        int grid = ntile_ub < 1024 ? ntile_ub : 1024;   // 4 blocks/CU residency
        k_edgew<<<grid, 256, 0, stream>>>(dRp, row, n0, n1, cap,
                                       Wr0 + l*512, Wr1 + l*4096, Wr2 + l*12288, wbuf);
        k_gather<<<n1-n0, 128, 0, stream>>>(wbuf, row, sendp, sh1, s1h, v1h,
                                            n0, cap, a_s, a_v);
      }
    } else {
      hipMemsetAsync(a_s, 0, (size_t)NN*384*sizeof(float), stream);  // a_s+a_v contiguous
      k_edge<<<1250, 256, 0, stream>>>(dR, sh1, senders, receivers, s1h, v1h,
                                       Wr0 + l*512, Wr1 + l*4096, Wr2 + l*12288,
                                       a_s, a_v);
    }
    // writes back into sA/vA (safe: k_out reads only a_s/a_v/scs/scv)
    k_out<<<1250, 256, 0, stream>>>(a_s, a_v, scs, scv,
                                    W_l2_s + l*9216, W_l2_v + l*3072,
                                    sA, vA);
  }
  k_final<<<79, 256, 0, stream>>>(sA, nodes, n_node, W_en1, W_en2, W_mag1, W_mag2,
                                  scale_occ, shift_occ, escale, eshift, out);
}

// Round 14
// 554.476 us; speedup vs baseline: 1.7702x; 1.0517x over previous
//
#include <hip/hip_runtime.h>
#include <hip/hip_fp16.h>
#include <math.h>

#define NN 20000
#define NE 320000
#define NG 16
#define ECAP 48   // edges staged per batch in k_gather (deg ~16+-4, max ~40)

typedef _Float16 f16x2 __attribute__((ext_vector_type(2)));
typedef _Float16 f16x8 __attribute__((ext_vector_type(8)));
typedef float    f32x4 __attribute__((ext_vector_type(4)));

__device__ __forceinline__ float dot2f(f16x2 a, f16x2 b, float c){
#if defined(__has_builtin)
#if __has_builtin(__builtin_amdgcn_fdot2)
  return __builtin_amdgcn_fdot2(a, b, c, false);
#else
  return c + (float)a.x*(float)b.x + (float)a.y*(float)b.y;
#endif
#else
  return c + (float)a.x*(float)b.x + (float)a.y*(float)b.y;
#endif
}

__device__ __forceinline__ f16x2 pack2f(float a, float b){
  f16x2 r; r.x = (_Float16)a; r.y = (_Float16)b; return r;
}

__device__ __forceinline__ unsigned packu2f(float a, float b){
  union { f16x2 h; unsigned u; } X; X.h = pack2f(a, b); return X.u;
}

__device__ __forceinline__ float silu_f(float x){ return x / (1.0f + __expf(-x)); }

// recompute bessel basis from dR (identical math/constants throughout all rounds)
__device__ __forceinline__ void bessel8(const float* __restrict__ dR, int e, float* rb){
  float x = dR[3*e+0], y = dR[3*e+1], z = dR[3*e+2];
  float r = sqrtf(x*x + y*y + z*z);
  float rs = fmaxf(r, 1e-6f);
  float inv = 1.0f / rs;
  float env;
  if (r < 3.5f) env = 1.0f;
  else if (r > 4.0f) env = 0.0f;
  else {
    float t = (r - 3.5f) * 2.0f;
    env = 0.5f * (cosf(3.14159265358979323846f * t) + 1.0f);
  }
  float c = 0.7071067811865476f * inv * env;
  #pragma unroll
  for (int k=0;k<8;k++){
    float arg = (float)(k+1) * 0.7853981633974483f * rs;
    rb[k] = c * sinf(arg);
  }
}

// ---------------- geometry: spherical harmonics only (fallback path) ----------------
__global__ void k_geom(const float* __restrict__ dR, float* __restrict__ sh1){
  int e = blockIdx.x*256 + threadIdx.x;
  if (e >= NE) return;
  float x = dR[3*e+0], y = dR[3*e+1], z = dR[3*e+2];
  float r = sqrtf(x*x + y*y + z*z);
  float inv = 1.0f / fmaxf(r, 1e-6f);
  const float SQ3 = 1.7320508075688772f;
  sh1[3*e+0] = SQ3 * x * inv;
  sh1[3*e+1] = SQ3 * y * inv;
  sh1[3*e+2] = SQ3 * z * inv;
}

// ---------------- node embedding (fallback path only) ----------------
__global__ void k_embed(const float* __restrict__ nodes, const float* __restrict__ W,
                        float* __restrict__ s){
  int idx = blockIdx.x*256 + threadIdx.x;   // N*64 exact
  int n = idx>>6, o = idx&63;
  float a = nodes[n*4+0]*W[o] + nodes[n*4+1]*W[64+o]
          + nodes[n*4+2]*W[128+o] + nodes[n*4+3]*W[192+o];
  s[idx] = 0.5f*a;
}

// ---------------- edge pre-permute (fast path): kills dependent gather chains ----
__global__ void k_prep(const float* __restrict__ dR, const int* __restrict__ senders,
                       const int* __restrict__ perm,
                       float* __restrict__ sh1, float* __restrict__ dRp,
                       int* __restrict__ sendp){
  int p = blockIdx.x*256 + threadIdx.x;
  if (p >= NE) return;
  int e = perm[p];
  float x = dR[3*e+0], y = dR[3*e+1], z = dR[3*e+2];
  dRp[3*p+0] = x; dRp[3*p+1] = y; dRp[3*p+2] = z;
  float r = sqrtf(x*x + y*y + z*z);
  float inv = 1.0f / fmaxf(r, 1e-6f);
  const float SQ3 = 1.7320508075688772f;
  sh1[3*p+0] = SQ3 * x * inv;
  sh1[3*p+1] = SQ3 * y * inv;
  sh1[3*p+2] = SQ3 * z * inv;
  sendp[p] = senders[e];
}

// ---------------- one-time weight transpose: W[i][e][o] -> W[i][o][e] ------------
__global__ void k_wt(const float* __restrict__ Wscs, const float* __restrict__ Wscv,
                     float* __restrict__ Wst, float* __restrict__ Wvt){
  int idx = blockIdx.x*256 + threadIdx.x;
  if (idx < 49152){                       // 2 layers x 64 x 4 x 96
    int l = idx/24576, r = idx - l*24576;
    int i = r/384; int rem = r - i*384; int e = rem/96; int o = rem - e*96;
    Wst[l*24576 + i*384 + o*4 + e] = Wscs[idx];
  } else if (idx < 49152 + 8192){         // 2 layers x 32 x 4 x 32
    int k = idx - 49152;
    int l = k/4096, r = k - l*4096;
    int i = r/128; int rem = r - i*128; int e = rem/32; int op = rem - e*32;
    Wvt[l*4096 + i*128 + op*4 + e] = Wscv[idx];
  }
}

// ---------------- counting sort of edges by receiver ----------------
__global__ void k_hist(const int* __restrict__ receivers, int* __restrict__ cnt){
  int e = blockIdx.x*256 + threadIdx.x;
  if (e < NE) atomicAdd(&cnt[receivers[e]], 1);
}

__global__ void k_scan(const int* __restrict__ cnt, int* __restrict__ row, int* __restrict__ cur){
  __shared__ int lsum[1024];
  int t = threadIdx.x;
  int base = t*20;
  int local[20];
  int s = 0;
  #pragma unroll
  for (int i=0;i<20;i++){
    int idx = base+i;
    int v = (idx<NN) ? cnt[idx] : 0;
    local[i] = s; s += v;
  }
  lsum[t] = s; __syncthreads();
  for (int off=1; off<1024; off<<=1){
    int v = (t>=off) ? lsum[t-off] : 0;
    __syncthreads();
    lsum[t] += v;
    __syncthreads();
  }
  int pre = (t>0) ? lsum[t-1] : 0;
  #pragma unroll
  for (int i=0;i<20;i++){
    int idx = base+i;
    if (idx<NN){ int r = pre+local[i]; row[idx]=r; cur[idx]=r; }
  }
  if (t==1023) row[NN] = lsum[1023];
}

__global__ void k_scatter(const int* __restrict__ receivers, int* __restrict__ cur,
                          int* __restrict__ perm){
  int e = blockIdx.x*256 + threadIdx.x;
  if (e < NE){
    int d = receivers[e];
    int p = atomicAdd(&cur[d], 1);
    perm[p] = e;
  }
}

// ---------------- per-layer node linears: 16 nodes/block, 4 nodes/wave ----------
// Weight loads batched x4 (round-10). Round-14: embed mode (W_embed != null) for
// layer 0 -- computes ls directly from nodes (identical math to k_embed) and
// writes ZERO v1/scv without computing (v==0 at layer 0 by construction).
__global__ void k_node(const float* __restrict__ s, const float* __restrict__ v,
                       const float* __restrict__ attrs, const float* __restrict__ W_embed,
                       const float* __restrict__ W1s, const float* __restrict__ W1v,
                       const float* __restrict__ Wscst, const float* __restrict__ Wscvt,
                       __half* __restrict__ s1, __half* __restrict__ v1,
                       float* __restrict__ scs, float* __restrict__ scv){
  __shared__ float ls[16][64];
  __shared__ float lv[16][96];
  __shared__ float la[16][4];
  int tid = threadIdx.x;
  int nb = blockIdx.x*16;   // 1250*16 = 20000 exact
  if (W_embed){
    // layer 0: ls = embed(nodes) = (nodes @ W_embed)/2 ; v == 0 -> skip lv
    for (int i=tid;i<1024;i+=256){
      int j=i>>6, o=i&63;
      int n = nb + j;
      float a = attrs[n*4+0]*W_embed[o] + attrs[n*4+1]*W_embed[64+o]
              + attrs[n*4+2]*W_embed[128+o] + attrs[n*4+3]*W_embed[192+o];
      ls[j][o] = 0.5f*a;
    }
  } else {
    for (int i=tid;i<1024;i+=256) ls[i>>6][i&63] = s[(size_t)(nb+(i>>6))*64 + (i&63)];
    for (int i=tid;i<1536;i+=256){ int j=i/96, q=i-96*j; lv[j][q] = v[(size_t)(nb+j)*96+q]; }
  }
  if (tid<64) la[tid>>2][tid&3] = attrs[(nb+(tid>>2))*4 + (tid&3)];
  __syncthreads();
  int w = tid>>6, q = tid&63;
  int jb = w*4;                       // this wave's 4 nodes: nb+jb .. nb+jb+3
  float laj[4][4];
  #pragma unroll
  for (int j=0;j<4;j++)
    #pragma unroll
    for (int e=0;e<4;e++) laj[j][e] = la[jb+j][e];

  // s1 = s @ W1s / 8  (loads batched x4)
  {
    float acc[4] = {0,0,0,0};
    for (int i=0;i<64;i+=4){
      float wv0 = W1s[(i+0)*64+q];
      float wv1 = W1s[(i+1)*64+q];
      float wv2 = W1s[(i+2)*64+q];
      float wv3 = W1s[(i+3)*64+q];
      #pragma unroll
      for (int j=0;j<4;j++){
        acc[j] = fmaf(ls[jb+j][i+0], wv0, acc[j]);
        acc[j] = fmaf(ls[jb+j][i+1], wv1, acc[j]);
        acc[j] = fmaf(ls[jb+j][i+2], wv2, acc[j]);
        acc[j] = fmaf(ls[jb+j][i+3], wv3, acc[j]);
      }
    }
    #pragma unroll
    for (int j=0;j<4;j++) s1[(size_t)(nb+jb+j)*64+q] = __float2half(acc[j]*0.125f);
  }
  // sc_s (two-stage, loads batched x4)
  #pragma unroll 1
  for (int o=q;o<96;o+=64){
    float t0[4]={0,0,0,0}, t1[4]={0,0,0,0}, t2[4]={0,0,0,0}, t3[4]={0,0,0,0};
    for (int i=0;i<64;i+=4){
      float4 wa = *(const float4*)(Wscst + (i+0)*384 + o*4);
      float4 wb = *(const float4*)(Wscst + (i+1)*384 + o*4);
      float4 wc = *(const float4*)(Wscst + (i+2)*384 + o*4);
      float4 wd = *(const float4*)(Wscst + (i+3)*384 + o*4);
      #pragma unroll
      for (int j=0;j<4;j++){
        float s0 = ls[jb+j][i+0], s1v = ls[jb+j][i+1];
        float s2 = ls[jb+j][i+2], s3 = ls[jb+j][i+3];
        t0[j] = fmaf(s0, wa.x, t0[j]); t1[j] = fmaf(s0, wa.y, t1[j]);
        t2[j] = fmaf(s0, wa.z, t2[j]); t3[j] = fmaf(s0, wa.w, t3[j]);
        t0[j] = fmaf(s1v, wb.x, t0[j]); t1[j] = fmaf(s1v, wb.y, t1[j]);
        t2[j] = fmaf(s1v, wb.z, t2[j]); t3[j] = fmaf(s1v, wb.w, t3[j]);
        t0[j] = fmaf(s2, wc.x, t0[j]); t1[j] = fmaf(s2, wc.y, t1[j]);
        t2[j] = fmaf(s2, wc.z, t2[j]); t3[j] = fmaf(s2, wc.w, t3[j]);
        t0[j] = fmaf(s3, wd.x, t0[j]); t1[j] = fmaf(s3, wd.y, t1[j]);
        t2[j] = fmaf(s3, wd.z, t2[j]); t3[j] = fmaf(s3, wd.w, t3[j]);
      }
    }
    #pragma unroll
    for (int j=0;j<4;j++){
      float acc = t0[j]*laj[j][0] + t1[j]*laj[j][1]
                + t2[j]*laj[j][2] + t3[j]*laj[j][3];
      scs[(size_t)(nb+jb+j)*96+o] = acc*0.0625f;
    }
  }
  if (W_embed){
    // layer 0: v == 0 -> v1 = 0, sc_v = 0 (exact)
    #pragma unroll 1
    for (int f=q;f<96;f+=64){
      #pragma unroll
      for (int j=0;j<4;j++){
        v1[(size_t)(nb+jb+j)*96+f] = __float2half(0.0f);
        scv[(size_t)(nb+jb+j)*96+f] = 0.0f;
      }
    }
    return;
  }
  // v1 (loads batched x4)
  #pragma unroll 1
  for (int f=q;f<96;f+=64){
    int op=f/3, c=f-3*op;
    float acc[4] = {0,0,0,0};
    for (int i=0;i<32;i+=4){
      float wv0 = W1v[(i+0)*32+op];
      float wv1 = W1v[(i+1)*32+op];
      float wv2 = W1v[(i+2)*32+op];
      float wv3 = W1v[(i+3)*32+op];
      #pragma unroll
      for (int j=0;j<4;j++){
        acc[j] = fmaf(lv[jb+j][(i+0)*3+c], wv0, acc[j]);
        acc[j] = fmaf(lv[jb+j][(i+1)*3+c], wv1, acc[j]);
        acc[j] = fmaf(lv[jb+j][(i+2)*3+c], wv2, acc[j]);
        acc[j] = fmaf(lv[jb+j][(i+3)*3+c], wv3, acc[j]);
      }
    }
    #pragma unroll
    for (int j=0;j<4;j++) v1[(size_t)(nb+jb+j)*96+f] = __float2half(acc[j]*0.17677669529663687f);
  }
  // sc_v (two-stage, loads batched x4)
  #pragma unroll 1
  for (int f=q;f<96;f+=64){
    int op=f/3, c=f-3*op;
    float t0[4]={0,0,0,0}, t1[4]={0,0,0,0}, t2[4]={0,0,0,0}, t3[4]={0,0,0,0};
    for (int i=0;i<32;i+=4){
      float4 wa = *(const float4*)(Wscvt + (i+0)*128 + op*4);
      float4 wb = *(const float4*)(Wscvt + (i+1)*128 + op*4);
      float4 wc = *(const float4*)(Wscvt + (i+2)*128 + op*4);
      float4 wd = *(const float4*)(Wscvt + (i+3)*128 + op*4);
      #pragma unroll
      for (int j=0;j<4;j++){
        float v0 = lv[jb+j][(i+0)*3+c], v1v = lv[jb+j][(i+1)*3+c];
        float v2 = lv[jb+j][(i+2)*3+c], v3 = lv[jb+j][(i+3)*3+c];
        t0[j] = fmaf(v0, wa.x, t0[j]); t1[j] = fmaf(v0, wa.y, t1[j]);
        t2[j] = fmaf(v0, wa.z, t2[j]); t3[j] = fmaf(v0, wa.w, t3[j]);
        t0[j] = fmaf(v1v, wb.x, t0[j]); t1[j] = fmaf(v1v, wb.y, t1[j]);
        t2[j] = fmaf(v1v, wb.z, t2[j]); t3[j] = fmaf(v1v, wb.w, t3[j]);
        t0[j] = fmaf(v2, wc.x, t0[j]); t1[j] = fmaf(v2, wc.y, t1[j]);
        t2[j] = fmaf(v2, wc.z, t2[j]); t3[j] = fmaf(v2, wc.w, t3[j]);
        t0[j] = fmaf(v3, wd.x, t0[j]); t1[j] = fmaf(v3, wd.y, t1[j]);
        t2[j] = fmaf(v3, wd.z, t2[j]); t3[j] = fmaf(v3, wd.w, t3[j]);
      }
    }
    #pragma unroll
    for (int j=0;j<4;j++){
      float acc = t0[j]*laj[j][0] + t1[j]*laj[j][1]
                + t2[j]*laj[j][2] + t3[j]*laj[j][3];
      scv[(size_t)(nb+jb+j)*96+f] = acc*0.08838834764831845f;
    }
  }
}

// ---------------- edge MLP: persistent-weight multi-tile version -----------------
// R2 stored o-major (round-13): phase-C B-frags are 2 contiguous ds_read_b128.
#define W2S 36
#define HT2S 68
__launch_bounds__(256, 4)
__global__ void k_edgew(const float* __restrict__ dRp,
                        const int* __restrict__ row, int n0, int n1, int cap,
                        const float* __restrict__ R0, const float* __restrict__ R1,
                        const float* __restrict__ R2,
                        __half* __restrict__ wbuf){
  __shared__ __align__(16) f16x2 hT2[32*HT2S];  // 8.7 KB: [kpair][e] stride 68; rb staging (fp32 view) / h1 / h2
  __shared__ __align__(16) float r0s[512];      // 2 KB: R0 fp32
  __shared__ __align__(16) f16x2 wgt2[192*W2S]; // 27 KB: R2 o-major [o][kp], persistent
  int tid = threadIdx.x;
  int p0 = row[n0], p1 = row[n1];
  int vmax = p1 - p0; if (vmax > cap) vmax = cap;
  int ntiles = (vmax + 63) >> 6;

  int eg = tid & 15, e0 = eg*4;
  int jg = tid >> 4, j0 = jg*4;
  int wv = tid >> 6;
  int ln = tid & 63;
  int col = ln & 15;
  int quad = ln >> 4;

  // ---- persistent staging (once per block) ----
  if (tid < 128) ((float4*)r0s)[tid] = ((const float4*)R0)[tid];
  for (int i=tid; i<6144; i+=256){
    int kp = i/192, o = i-192*kp;     // coalesced R2 reads; o-major LDS writes
    wgt2[o*W2S + kp] = pack2f(R2[(2*kp)*192 + o], R2[(2*kp+1)*192 + o]);
  }
  // R1 A-frags direct from global into registers
  union { uint4 u; f16x8 v; } rA0, rA1;
  {
    int jA = 16*wv + col;
    rA0.u.x = packu2f(R1[(8*quad+0)*64 + jA], R1[(8*quad+1)*64 + jA]);
    rA0.u.y = packu2f(R1[(8*quad+2)*64 + jA], R1[(8*quad+3)*64 + jA]);
    rA0.u.z = packu2f(R1[(8*quad+4)*64 + jA], R1[(8*quad+5)*64 + jA]);
    rA0.u.w = packu2f(R1[(8*quad+6)*64 + jA], R1[(8*quad+7)*64 + jA]);
    rA1.u.x = packu2f(R1[(32+8*quad+0)*64 + jA], R1[(32+8*quad+1)*64 + jA]);
    rA1.u.y = packu2f(R1[(32+8*quad+2)*64 + jA], R1[(32+8*quad+3)*64 + jA]);
    rA1.u.z = packu2f(R1[(32+8*quad+4)*64 + jA], R1[(32+8*quad+5)*64 + jA]);
    rA1.u.w = packu2f(R1[(32+8*quad+6)*64 + jA], R1[(32+8*quad+7)*64 + jA]);
  }
  // visibility of r0s/wgt2 covered by the loop-top barrier of the first tile

  for (int tile = blockIdx.x; tile < ntiles; tile += gridDim.x){
    int tbase = tile*64;
    int vcnt = vmax - tbase; if (vcnt > 64) vcnt = 64;

    __syncthreads();   // [A] staging visible / prev tile's phase-C hT2 reads done
    // stage rb for the 64 edges into hT2 region (fp32 view, rows k<8)
    float* hTf = (float*)hT2;
    if (tid < 64){
      float rbv[8];
      if (tid < vcnt){
        bessel8(dRp, p0 + tbase + tid, rbv);
      } else {
        #pragma unroll
        for (int k=0;k<8;k++) rbv[k]=0.0f;
      }
      #pragma unroll
      for (int k=0;k<8;k++) hTf[k*HT2S + tid] = rbv[k];
    }
    __syncthreads();   // [B]

    // read rb tile into regs (before overwriting hT2 with h1 pairs)
    float rb[8][4];
    {
      const float4* hTf4 = (const float4*)hTf;
      #pragma unroll
      for (int k=0;k<8;k++){
        float4 v = hTf4[k*17 + eg];
        rb[k][0]=v.x; rb[k][1]=v.y; rb[k][2]=v.z; rb[k][3]=v.w;
      }
    }
    // phase A: h1 tile (fp32 math, tiny K=8)
    float a[4][4];
    #pragma unroll
    for (int j=0;j<4;j++)
      #pragma unroll
      for (int e=0;e<4;e++) a[j][e]=0.0f;
    {
      const float4* r0s4 = (const float4*)r0s;
      #pragma unroll
      for (int k=0;k<8;k++){
        float4 w = r0s4[k*16 + jg];
        float wj[4] = {w.x,w.y,w.z,w.w};
        #pragma unroll
        for (int j=0;j<4;j++)
          #pragma unroll
          for (int e=0;e<4;e++) a[j][e] = fmaf(rb[k][e], wj[j], a[j][e]);
      }
    }
    #pragma unroll
    for (int j=0;j<4;j++)
      #pragma unroll
      for (int e=0;e<4;e++) a[j][e] = silu_f(a[j][e]*0.3535533905932738f);
    __syncthreads();   // [C] all rb reads complete
    // write h1 as k-pairs: rows j0/2, j0/2+1 of hT2
    #pragma unroll
    for (int jp=0;jp<2;jp++){
      union {uint4 u; f16x2 h[4];} U;
      #pragma unroll
      for (int e=0;e<4;e++) U.h[e] = pack2f(a[2*jp][e], a[2*jp+1][e]);
      *(uint4*)(hT2 + (j0/2 + jp)*HT2S + e0) = U.u;
    }
    __syncthreads();   // [D]

    // phase B via MFMA: wave wv owns j-tile [16*wv,16*wv+16), loops 4 e-tiles.
    {
      const unsigned int* hT2u = (const unsigned int*)hT2;
      f32x4 accB[4];
      #pragma unroll
      for (int nt=0; nt<4; nt++){
        union { uint4 u; f16x8 v; } B0, B1;
        int eB = 16*nt + col;
        B0.u.x = hT2u[(4*quad+0)*HT2S + eB];
        B0.u.y = hT2u[(4*quad+1)*HT2S + eB];
        B0.u.z = hT2u[(4*quad+2)*HT2S + eB];
        B0.u.w = hT2u[(4*quad+3)*HT2S + eB];
        B1.u.x = hT2u[(16+4*quad+0)*HT2S + eB];
        B1.u.y = hT2u[(16+4*quad+1)*HT2S + eB];
        B1.u.z = hT2u[(16+4*quad+2)*HT2S + eB];
        B1.u.w = hT2u[(16+4*quad+3)*HT2S + eB];
        f32x4 acc = {0.0f,0.0f,0.0f,0.0f};
        acc = __builtin_amdgcn_mfma_f32_16x16x32_f16(rA0.v, B0.v, acc, 0, 0, 0);
        acc = __builtin_amdgcn_mfma_f32_16x16x32_f16(rA1.v, B1.v, acc, 0, 0, 0);
        accB[nt] = acc;
      }
      __syncthreads();   // [E] all h1 (hT2) reads complete
      // silu + pack + write h2^T as k-pairs
      #pragma unroll
      for (int nt=0; nt<4; nt++){
        float h0 = silu_f(accB[nt][0]*0.125f);
        float h1v = silu_f(accB[nt][1]*0.125f);
        float h2v = silu_f(accB[nt][2]*0.125f);
        float h3v = silu_f(accB[nt][3]*0.125f);
        hT2[(8*wv + 2*quad + 0)*HT2S + 16*nt + col] = pack2f(h0, h1v);
        hT2[(8*wv + 2*quad + 1)*HT2S + 16*nt + col] = pack2f(h2v, h3v);
      }
    }
    __syncthreads();   // [F] h2 visible

    // phase C via MFMA: wave wv handles edges [16*wv, 16*wv+16)
    {
      const unsigned int* hT2u = (const unsigned int*)hT2;
      const unsigned int* wgt2u = (const unsigned int*)wgt2;
      int eA = 16*wv + col;     // A's m index
      union { uint4 u; f16x8 v; } A0, A1;
      A0.u.x = hT2u[(4*quad+0)*HT2S + eA];
      A0.u.y = hT2u[(4*quad+1)*HT2S + eA];
      A0.u.z = hT2u[(4*quad+2)*HT2S + eA];
      A0.u.w = hT2u[(4*quad+3)*HT2S + eA];
      A1.u.x = hT2u[(16+4*quad+0)*HT2S + eA];
      A1.u.y = hT2u[(16+4*quad+1)*HT2S + eA];
      A1.u.z = hT2u[(16+4*quad+2)*HT2S + eA];
      A1.u.w = hT2u[(16+4*quad+3)*HT2S + eA];
      int erow = 16*wv + 4*quad;           // D rows: erow+0..3
      #pragma unroll
      for (int ot=0; ot<12; ot++){
        int o = 16*ot + col;
        union { uint4 u; f16x8 v; } B0, B1;
        B0.u = *(const uint4*)(wgt2u + o*W2S + 4*quad);
        B1.u = *(const uint4*)(wgt2u + o*W2S + 16 + 4*quad);
        f32x4 acc = {0.0f,0.0f,0.0f,0.0f};
        acc = __builtin_amdgcn_mfma_f32_16x16x32_f16(A0.v, B0.v, acc, 0, 0, 0);
        acc = __builtin_amdgcn_mfma_f32_16x16x32_f16(A1.v, B1.v, acc, 0, 0, 0);
        // direct predicated stores (uniform-true branch for full tiles)
        #pragma unroll
        for (int r=0;r<4;r++){
          int eib = erow + r;
          if (eib < vcnt)
            wbuf[(size_t)(tbase+eib)*192 + o] = __float2half(acc[r]);
        }
      }
    }
  }
}

// ---------------- gather: role-split + 8-deep load batching, spill-free ---------
__launch_bounds__(128, 4)
__global__ void k_gather(const __half* __restrict__ wbuf,
                         const int* __restrict__ row, const int* __restrict__ sendp,
                         const float* __restrict__ sh1,
                         const __half* __restrict__ s1, const __half* __restrict__ v1,
                         int n0, int cap,
                         float* __restrict__ a_s, float* __restrict__ a_v){
  __shared__ int   srcs[ECAP];
  __shared__ float sh1r[ECAP*3];
  int n = n0 + blockIdx.x;
  int t = threadIdx.x;
  int pc0 = row[n0];
  int p0 = row[n], p1 = row[n+1];
  int pmax = pc0 + cap; if (p1 > pmax) p1 = pmax;

  int iv = (t - 64) >> 1;          // 0..31 for vrole
  bool even = ((t & 1) == 0);

  float acs = 0.0f, av0 = 0.0f, av1 = 0.0f, av2 = 0.0f;

  for (int base = p0; base < p1; base += ECAP){
    int bc = p1 - base; if (bc > ECAP) bc = ECAP;
    __syncthreads();   // protect LDS reuse across batches
    if (t < bc){
      srcs[t] = sendp[base + t];
      sh1r[3*t+0] = sh1[3*(base+t)+0];
      sh1r[3*t+1] = sh1[3*(base+t)+1];
      sh1r[3*t+2] = sh1[3*(base+t)+2];
    }
    __syncthreads();
    const __half* wb = wbuf + (size_t)(base - pc0)*192;
    if (t < 64){
      int o = t;
      int j = 0;
      for (; j + 8 <= bc; j += 8){
        float sv[8], w1[8], w2[8];
        #pragma unroll
        for (int u=0;u<8;u++){
          const __half* wr = wb + (j+u)*192;
          sv[u] = __half2float(s1[(size_t)srcs[j+u]*64 + o]);
          w1[u] = __half2float(wr[o]);
          w2[u] = __half2float(wr[64 + o]);
        }
        #pragma unroll
        for (int u=0;u<8;u++){
          acs = fmaf(w1[u], sv[u], acs);
          float uu = w2[u] * sv[u];
          av0 = fmaf(uu, sh1r[3*(j+u)+0], av0);
          av1 = fmaf(uu, sh1r[3*(j+u)+1], av1);
          av2 = fmaf(uu, sh1r[3*(j+u)+2], av2);
        }
      }
      for (; j < bc; ++j){
        const __half* wr = wb + j*192;
        float sv = __half2float(s1[(size_t)srcs[j]*64 + o]);
        float w1v = __half2float(wr[o]);
        float w2v = __half2float(wr[64 + o]);
        acs = fmaf(w1v, sv, acs);
        float uu = w2v * sv;
        av0 = fmaf(uu, sh1r[3*j+0], av0);
        av1 = fmaf(uu, sh1r[3*j+1], av1);
        av2 = fmaf(uu, sh1r[3*j+2], av2);
      }
    } else {
      int j = 0;
      for (; j + 8 <= bc; j += 8){
        float v0[8], vc1[8], vc2[8], w3[8], w4[8];
        #pragma unroll
        for (int u=0;u<8;u++){
          const __half* wr = wb + (j+u)*192;
          const __half* vr = v1 + (size_t)srcs[j+u]*96 + 3*iv;
          v0[u]  = __half2float(vr[0]);
          vc1[u] = __half2float(vr[1]);
          vc2[u] = __half2float(vr[2]);
          w3[u]  = __half2float(wr[128 + iv]);
          w4[u]  = __half2float(wr[160 + iv]);
        }
        #pragma unroll
        for (int u=0;u<8;u++){
          if (even){
            float dv = v0[u]*sh1r[3*(j+u)+0] + vc1[u]*sh1r[3*(j+u)+1] + vc2[u]*sh1r[3*(j+u)+2];
            acs = fmaf(w4[u], dv, acs);
            av0 = fmaf(w3[u], v0[u], av0);
          } else {
            av1 = fmaf(w3[u], vc1[u], av1);
            av2 = fmaf(w3[u], vc2[u], av2);
          }
        }
      }
      for (; j < bc; ++j){
        const __half* wr = wb + j*192;
        const __half* vr = v1 + (size_t)srcs[j]*96 + 3*iv;
        float v0 = __half2float(vr[0]);
        float vc1 = __half2float(vr[1]);
        float vc2 = __half2float(vr[2]);
        float w3 = __half2float(wr[128 + iv]);
        if (even){
          float w4 = __half2float(wr[160 + iv]);
          float dv = v0*sh1r[3*j+0] + vc1*sh1r[3*j+1] + vc2*sh1r[3*j+2];
          acs = fmaf(w4, dv, acs);
          av0 = fmaf(w3, v0, av0);
        } else {
          av1 = fmaf(w3, vc1, av1);
          av2 = fmaf(w3, vc2, av2);
        }
      }
    }
  }

  if (t < 64){
    a_s[(size_t)n*96 + t] = 0.03125f*acs;              // (1/8)*(1/sqrt(16))
    a_v[(size_t)n*288 + 3*t + 0] = 0.03125f*av0;
    a_v[(size_t)n*288 + 3*t + 1] = 0.03125f*av1;
    a_v[(size_t)n*288 + 3*t + 2] = 0.03125f*av2;
  } else if (even){
    a_s[(size_t)n*96 + 64 + iv] = 0.018042195912175807f*acs;   // 0.03125/sqrt(3)
    a_v[(size_t)n*288 + 192 + 3*iv + 0] = 0.03125f*av0;
  } else {
    a_v[(size_t)n*288 + 192 + 3*iv + 1] = 0.03125f*av1;
    a_v[(size_t)n*288 + 192 + 3*iv + 2] = 0.03125f*av2;
  }
}

// ---------------- fallback: atomic edge kernel (only if ws too small) ----------------
__device__ __forceinline__ void mlp_h2(const float* __restrict__ R0,
                                       const float* lR1, const float rb[8],
                                       float h2[64]){
  float h1[64];
  #pragma unroll
  for (int j=0;j<64;j+=4){
    float a0=0,a1=0,a2=0,a3=0;
    #pragma unroll
    for (int k=0;k<8;k++){
      float r = rb[k];
      const float* wp = R0 + k*64 + j;
      a0 = fmaf(r, wp[0], a0); a1 = fmaf(r, wp[1], a1);
      a2 = fmaf(r, wp[2], a2); a3 = fmaf(r, wp[3], a3);
    }
    h1[j+0]=silu_f(a0*0.3535533905932738f);
    h1[j+1]=silu_f(a1*0.3535533905932738f);
    h1[j+2]=silu_f(a2*0.3535533905932738f);
    h1[j+3]=silu_f(a3*0.3535533905932738f);
  }
  #pragma unroll
  for (int j=0;j<64;j+=4){
    float a0=0,a1=0,a2=0,a3=0;
    #pragma unroll
    for (int k=0;k<64;k++){
      float h = h1[k];
      float4 w4 = *(const float4*)(lR1 + k*64 + j);
      a0 = fmaf(h,w4.x,a0); a1 = fmaf(h,w4.y,a1);
      a2 = fmaf(h,w4.z,a2); a3 = fmaf(h,w4.w,a3);
    }
    h2[j+0]=silu_f(a0*0.125f);
    h2[j+1]=silu_f(a1*0.125f);
    h2[j+2]=silu_f(a2*0.125f);
    h2[j+3]=silu_f(a3*0.125f);
  }
}

__launch_bounds__(256, 2)
__global__ void k_edge(const float* __restrict__ dR, const float* __restrict__ sh1,
                       const int* __restrict__ senders, const int* __restrict__ receivers,
                       const __half* __restrict__ s1, const __half* __restrict__ v1,
                       const float* __restrict__ R0, const float* __restrict__ R1,
                       const float* __restrict__ R2,
                       float* __restrict__ a_s, float* __restrict__ a_v){
  __shared__ __align__(16) float lR1[64*64];
  __shared__ __align__(16) float lR2[64*192];
  int tid = threadIdx.x;
  for (int i=tid;i<4096;i+=256)  lR1[i]=R1[i];
  for (int i=tid;i<12288;i+=256) lR2[i]=R2[i];
  __syncthreads();
  int e = blockIdx.x*256 + tid;
  float rb[8];
  bessel8(dR, e, rb);
  float h2[64];
  mlp_h2(R0, lR1, rb, h2);
  int src = senders[e], dst = receivers[e];
  float sx=sh1[3*e+0], sy=sh1[3*e+1], sz=sh1[3*e+2];
  const __half* srow = s1 + (size_t)src*64;
  const __half* vrow = v1 + (size_t)src*96;
  float* asr = a_s + (size_t)dst*96;
  float* avr = a_v + (size_t)dst*288;
  #pragma unroll 1
  for (int o=0;o<64;o+=4){
    float w10=0,w11=0,w12=0,w13=0, w20=0,w21=0,w22=0,w23=0;
    #pragma unroll
    for (int k=0;k<64;k++){
      float h = h2[k];
      float4 wa = *(const float4*)(lR2 + k*192 + o);
      float4 wb = *(const float4*)(lR2 + k*192 + 64 + o);
      w10=fmaf(h,wa.x,w10); w11=fmaf(h,wa.y,w11); w12=fmaf(h,wa.z,w12); w13=fmaf(h,wa.w,w13);
      w20=fmaf(h,wb.x,w20); w21=fmaf(h,wb.y,w21); w22=fmaf(h,wb.z,w22); w23=fmaf(h,wb.w,w23);
    }
    float sev[4] = {__half2float(srow[o+0]), __half2float(srow[o+1]),
                    __half2float(srow[o+2]), __half2float(srow[o+3])};
    float w1a[4] = {w10,w11,w12,w13};
    float w2a[4] = {w20,w21,w22,w23};
    #pragma unroll
    for (int u=0;u<4;u++){
      atomicAdd(asr+o+u, 0.03125f*w1a[u]*sev[u]);
      float m = 0.03125f*w2a[u]*sev[u];
      atomicAdd(avr+(o+u)*3+0, m*sx);
      atomicAdd(avr+(o+u)*3+1, m*sy);
      atomicAdd(avr+(o+u)*3+2, m*sz);
    }
  }
  #pragma unroll 1
  for (int i0=0;i0<32;i0+=4){
    float w30=0,w31=0,w32=0,w33=0, w40=0,w41=0,w42=0,w43=0;
    #pragma unroll
    for (int k=0;k<64;k++){
      float h = h2[k];
      float4 wa = *(const float4*)(lR2 + k*192 + 128 + i0);
      float4 wb = *(const float4*)(lR2 + k*192 + 160 + i0);
      w30=fmaf(h,wa.x,w30); w31=fmaf(h,wa.y,w31); w32=fmaf(h,wa.z,w32); w33=fmaf(h,wa.w,w33);
      w40=fmaf(h,wb.x,w40); w41=fmaf(h,wb.y,w41); w42=fmaf(h,wb.z,w42); w43=fmaf(h,wb.w,w43);
    }
    float w3a[4] = {w30,w31,w32,w33};
    float w4a[4] = {w40,w41,w42,w43};
    #pragma unroll
    for (int u=0;u<4;u++){
      int i = i0+u;
      float vx=__half2float(vrow[3*i+0]), vy=__half2float(vrow[3*i+1]), vz=__half2float(vrow[3*i+2]);
      float dv = vx*sx + vy*sy + vz*sz;
      atomicAdd(asr+64+i, 0.018042195912175807f*w4a[u]*dv);
      float m3 = 0.03125f*w3a[u];
      atomicAdd(avr+(64+i)*3+0, m3*vx);
      atomicAdd(avr+(64+i)*3+1, m3*vy);
      atomicAdd(avr+(64+i)*3+2, m3*vz);
    }
  }
}

// ---------------- per-layer output transform: o_s, o_v, gating ----------------
__launch_bounds__(256, 4)
__global__ void k_out(const float* __restrict__ a_s, const float* __restrict__ a_v,
                      const float* __restrict__ scs, const float* __restrict__ scv,
                      const float* __restrict__ W2s, const float* __restrict__ W2v,
                      float* __restrict__ s_out, float* __restrict__ v_out){
  __shared__ float las[16][96];
  __shared__ float lav[16][288];
  __shared__ float los[16][96];
  int tid = threadIdx.x;
  int nb = blockIdx.x*16;   // 1250*16 = 20000 exact
  for (int i=tid;i<1536;i+=256){ int j=i/96,  q=i-96*j;  las[j][q] = a_s[(size_t)(nb+j)*96 +q]; }
  for (int i=tid;i<4608;i+=256){ int j=i/288, q=i-288*j; lav[j][q] = a_v[(size_t)(nb+j)*288+q]; }
  __syncthreads();
  int w = tid>>6, q = tid&63;
  int jb = w*4;                       // this wave's 4 nodes: nb+jb .. nb+jb+3

  // o_s = a_s @ W2s * scale + scs   (outputs o = q and q+64, wave-private los)
  #pragma unroll 1
  for (int o=q; o<96; o+=64){
    float acc[4] = {0,0,0,0};
    for (int i=0;i<96;i++){
      float wv = W2s[i*96+o];
      #pragma unroll
      for (int j=0;j<4;j++) acc[j] = fmaf(las[jb+j][i], wv, acc[j]);
    }
    #pragma unroll
    for (int j=0;j<4;j++)
      los[jb+j][o] = acc[j]*0.10206207261596575f + scs[(size_t)(nb+jb+j)*96+o];
  }
  __syncthreads();   // (wave-private in fact; barrier keeps LDS ordering simple)

  // s_out = silu(o_s[:64])
  #pragma unroll
  for (int j=0;j<4;j++) s_out[(size_t)(nb+jb+j)*64+q] = silu_f(los[jb+j][q]);

  // o_v = a_v @ W2v * scale + scv, gated by silu(o_s[64+op])
  #pragma unroll 1
  for (int f=q; f<96; f+=64){
    int op=f/3, c=f-3*op;
    float acc[4] = {0,0,0,0};
    for (int i=0;i<96;i++){
      float wv = W2v[i*32+op];
      #pragma unroll
      for (int j=0;j<4;j++) acc[j] = fmaf(lav[jb+j][i*3+c], wv, acc[j]);
    }
    #pragma unroll
    for (int j=0;j<4;j++){
      float ov = acc[j]*0.10206207261596575f + scv[(size_t)(nb+jb+j)*96+f];
      float g = silu_f(los[jb+j][64+op]);
      v_out[(size_t)(nb+jb+j)*96+f] = ov*g;
    }
  }
}

// ---------------- final heads: energy + mags ----------------
__global__ void k_final(const float* __restrict__ s, const float* __restrict__ nodes,
                        const int* __restrict__ n_node,
                        const float* __restrict__ Wen1, const float* __restrict__ Wen2,
                        const float* __restrict__ Wm1, const float* __restrict__ Wm2,
                        const float* __restrict__ scale_occ, const float* __restrict__ shift_occ,
                        const float* __restrict__ escale, const float* __restrict__ eshift,
                        float* __restrict__ out){
  __shared__ float eacc[NG];
  __shared__ int goff[NG+1];
  int tid = threadIdx.x;
  if (tid < NG) eacc[tid] = 0.0f;
  if (tid == 0){
    int c = 0; goff[0] = 0;
    for (int g=0; g<NG; g++){ c += n_node[g]; goff[g+1] = c; }
  }
  __syncthreads();
  int n = blockIdx.x*256 + tid;
  if (n < NN){
    float sv[64];
    #pragma unroll
    for (int i=0;i<64;i++) sv[i]=s[(size_t)n*64+i];
    float en=0.0f, m0=0.0f, m1=0.0f;
    #pragma unroll 1
    for (int jj=0;jj<32;jj++){
      float he=0.0f, hm=0.0f;
      #pragma unroll
      for (int i=0;i<64;i++){
        he = fmaf(sv[i], Wen1[i*32+jj], he);
        hm = fmaf(sv[i], Wm1[i*32+jj], hm);
      }
      he *= 0.125f; hm *= 0.125f;
      en = fmaf(he, Wen2[jj], en);
      m0 = fmaf(hm, Wm2[jj*2+0], m0);
      m1 = fmaf(hm, Wm2[jj*2+1], m1);
    }
    const float INVS32 = 0.17677669529663687f;
    en *= INVS32; m0 *= INVS32; m1 *= INVS32;
    en = escale[0]*en + eshift[0];
    int g = 0;
    for (int gg=0; gg<NG; gg++) if (n >= goff[gg+1]) g = gg+1;
    atomicAdd(&eacc[g], en);
    float nx=nodes[n*4+0], ny=nodes[n*4+1], nz=nodes[n*4+2];
    float sc0 = nx*scale_occ[0] + ny*scale_occ[2] + nz*scale_occ[4];
    float sc1 = nx*scale_occ[1] + ny*scale_occ[3] + nz*scale_occ[5];
    float sf0 = nx*shift_occ[0] + ny*shift_occ[2] + nz*shift_occ[4];
    float sf1 = nx*shift_occ[1] + ny*shift_occ[3] + nz*shift_occ[5];
    out[16 + n*2 + 0] = sc0*m0 + sf0;
    out[16 + n*2 + 1] = sc1*m1 + sf1;
  }
  __syncthreads();
  if (tid < NG) atomicAdd(&out[tid], eacc[tid]);
}

extern "C" void kernel_launch(void* const* d_in, const int* in_sizes, int n_in,
                              void* d_out, int out_size, void* d_ws, size_t ws_size,
                              hipStream_t stream){
  const float* nodes   = (const float*)d_in[0];
  const float* dR      = (const float*)d_in[1];
  const int*  senders  = (const int*)d_in[2];
  const int*  receivers= (const int*)d_in[3];
  const int*  n_node   = (const int*)d_in[4];
  const float* W_embed = (const float*)d_in[5];
  const float* W_sc_s  = (const float*)d_in[6];
  const float* W_sc_v  = (const float*)d_in[7];
  const float* W_l1_s  = (const float*)d_in[8];
  const float* W_l1_v  = (const float*)d_in[9];
  const float* Wr0     = (const float*)d_in[10];
  const float* Wr1     = (const float*)d_in[11];
  const float* Wr2     = (const float*)d_in[12];
  const float* W_l2_s  = (const float*)d_in[13];
  const float* W_l2_v  = (const float*)d_in[14];
  const float* W_en1   = (const float*)d_in[15];
  const float* W_en2   = (const float*)d_in[16];
  const float* W_mag1  = (const float*)d_in[17];
  const float* W_mag2  = (const float*)d_in[18];
  const float* scale_occ = (const float*)d_in[19];
  const float* shift_occ = (const float*)d_in[20];
  const float* escale  = (const float*)d_in[21];
  const float* eshift  = (const float*)d_in[22];
  float* out = (float*)d_out;
  float* ws  = (float*)d_ws;

  // ---- workspace map (float-index offsets) ----
  float*  sh1  = ws + 0;         // NE*3 f32 (PERMUTED order in fast path)
  float*  sA   = ws + 960000;    // NN*64 f32
  float*  vA   = ws + 2240000;   // NN*96 f32
  __half* s1h  = (__half*)(ws + 4160000);   // NN*64 halves = 640,000 f32
  __half* v1h  = (__half*)(ws + 4800000);   // NN*96 halves = 960,000 f32
  float*  dRp  = ws + 5760000;   // NE*3 f32 permuted dR = 960,000 f32
  int*    sendp= (int*)(ws + 6720000);      // NE ints = 320,000 -> ends 7,040,000
  float*  Wst  = ws + 7040000;   // 2*24576 = 49,152 transposed W_sc_s
  float*  Wvt  = ws + 7089152;   // 2*4096  =  8,192 transposed W_sc_v -> ends 7,097,344
  float*  scs  = ws + 7360000;   // 1,920,000 f32
  float*  scv  = ws + 9280000;   // 1,920,000 f32
  float*  a_s  = ws + 11200000;  // 1,920,000 f32
  float*  a_v  = ws + 13120000;  // 5,760,000 f32 -> ends 18,880,000
  int*    cnt  = (int*)(ws + 18880000);  // 20,000
  int*    row  = (int*)(ws + 18900000);  // 20,001
  int*    cur  = (int*)(ws + 18920004);  // 20,000
  int*    perm = (int*)(ws + 18940004);  // 320,000 -> ends 19,260,004
  __half* wbuf = (__half*)(ws + 19260008); // capacity-adaptive fp16, 16B-aligned

  size_t wsf = ws_size / 4;
  // fp16 wbuf: 192 halves = 384 B per edge
  size_t cap_edges = (wsf > 19260008) ? ((wsf - 19260008)*4) / 384 : 0;
  if (cap_edges > 128) cap_edges -= 64;   // slack for 64-edge tile granularity
  const bool fast = cap_edges >= 4096;
  int cap = (int)((cap_edges > (size_t)NE) ? (size_t)NE + 8192 : cap_edges);
  // single chunk when wbuf can hold ALL edges; else the statistical heuristic.
  int npc;
  if (cap_edges > (size_t)NE){
    npc = NN;
  } else {
    npc = (int)(cap / 20); if (npc < 1) npc = 1; if (npc > NN) npc = NN;
  }
  int nchunk = (NN + npc - 1) / npc;

  hipMemsetAsync(out, 0, 16*sizeof(float), stream);             // energy accumulators

  k_wt<<<225, 256, 0, stream>>>(W_sc_s, W_sc_v, Wst, Wvt);

  if (fast){
    hipMemsetAsync(cnt, 0, NN*sizeof(int), stream);
    k_hist<<<1250, 256, 0, stream>>>(receivers, cnt);
    k_scan<<<1, 1024, 0, stream>>>(cnt, row, cur);
    k_scatter<<<1250, 256, 0, stream>>>(receivers, cur, perm);
    k_prep<<<1250, 256, 0, stream>>>(dR, senders, perm, sh1, dRp, sendp);
  } else {
    // fallback needs materialized sA embed + zero vA (k_edge path reads them)
    hipMemsetAsync(vA, 0, (size_t)NN*96*sizeof(float), stream);
    k_embed<<<5000, 256, 0, stream>>>(nodes, W_embed, sA);
    k_geom<<<1250, 256, 0, stream>>>(dR, sh1);
  }

  for (int l=0; l<2; l++){
    // layer 0 (fast path): embed fused into k_node; v==0 path skipped exactly.
    const float* Wemb = (l==0 && fast) ? W_embed : nullptr;
    k_node<<<1250, 256, 0, stream>>>(sA, vA, nodes, Wemb,
                                     W_l1_s + l*4096, W_l1_v + l*1024,
                                     Wst + l*24576, Wvt + l*4096,
                                     s1h, v1h, scs, scv);
    if (fast){
      for (int ck=0; ck<nchunk; ck++){
        int n0 = ck*npc;
        int n1 = n0 + npc; if (n1 > NN) n1 = NN;
        int cover = (n1-n0)*17 + 4096; if (cover > cap) cover = cap;
        int ntile_ub = (cover+63)/64;
        int grid = ntile_ub < 1024 ? ntile_ub : 1024;   // 4 blocks/CU residency
        k_edgew<<<grid, 256, 0, stream>>>(dRp, row, n0, n1, cap,
                                       Wr0 + l*512, Wr1 + l*4096, Wr2 + l*12288, wbuf);
        k_gather<<<n1-n0, 128, 0, stream>>>(wbuf, row, sendp, sh1, s1h, v1h,
                                            n0, cap, a_s, a_v);
      }
    } else {
      hipMemsetAsync(a_s, 0, (size_t)NN*384*sizeof(float), stream);  // a_s+a_v contiguous
      k_edge<<<1250, 256, 0, stream>>>(dR, sh1, senders, receivers, s1h, v1h,
                                       Wr0 + l*512, Wr1 + l*4096, Wr2 + l*12288,
                                       a_s, a_v);
    }
    // writes back into sA/vA (safe: k_out reads only a_s/a_v/scs/scv)
    k_out<<<1250, 256, 0, stream>>>(a_s, a_v, scs, scv,
                                    W_l2_s + l*9216, W_l2_v + l*3072,
                                    sA, vA);
  }
  k_final<<<79, 256, 0, stream>>>(sA, nodes, n_node, W_en1, W_en2, W_mag1, W_mag2,
                                  scale_occ, shift_occ, escale, eshift, out);
}

// Round 16
// 553.406 us; speedup vs baseline: 1.7737x; 1.0019x over previous
//
#include <hip/hip_runtime.h>
#include <hip/hip_fp16.h>
#include <math.h>

#define NN 20000
#define NE 320000
#define NG 16
#define ECAP 48   // edges staged per batch in k_gather (deg ~16+-4, max ~40)

typedef _Float16 f16x2 __attribute__((ext_vector_type(2)));
typedef _Float16 f16x8 __attribute__((ext_vector_type(8)));
typedef float    f32x4 __attribute__((ext_vector_type(4)));

__device__ __forceinline__ float dot2f(f16x2 a, f16x2 b, float c){
#if defined(__has_builtin)
#if __has_builtin(__builtin_amdgcn_fdot2)
  return __builtin_amdgcn_fdot2(a, b, c, false);
#else
  return c + (float)a.x*(float)b.x + (float)a.y*(float)b.y;
#endif
#else
  return c + (float)a.x*(float)b.x + (float)a.y*(float)b.y;
#endif
}

__device__ __forceinline__ f16x2 pack2f(float a, float b){
  f16x2 r; r.x = (_Float16)a; r.y = (_Float16)b; return r;
}

__device__ __forceinline__ unsigned packu2f(float a, float b){
  union { f16x2 h; unsigned u; } X; X.h = pack2f(a, b); return X.u;
}

__device__ __forceinline__ float silu_f(float x){ return x / (1.0f + __expf(-x)); }

// recompute bessel basis from dR (identical math/constants throughout all rounds)
__device__ __forceinline__ void bessel8(const float* __restrict__ dR, int e, float* rb){
  float x = dR[3*e+0], y = dR[3*e+1], z = dR[3*e+2];
  float r = sqrtf(x*x + y*y + z*z);
  float rs = fmaxf(r, 1e-6f);
  float inv = 1.0f / rs;
  float env;
  if (r < 3.5f) env = 1.0f;
  else if (r > 4.0f) env = 0.0f;
  else {
    float t = (r - 3.5f) * 2.0f;
    env = 0.5f * (cosf(3.14159265358979323846f * t) + 1.0f);
  }
  float c = 0.7071067811865476f * inv * env;
  #pragma unroll
  for (int k=0;k<8;k++){
    float arg = (float)(k+1) * 0.7853981633974483f * rs;
    rb[k] = c * sinf(arg);
  }
}

// ---------------- geometry: spherical harmonics only (fallback path) ----------------
__global__ void k_geom(const float* __restrict__ dR, float* __restrict__ sh1){
  int e = blockIdx.x*256 + threadIdx.x;
  if (e >= NE) return;
  float x = dR[3*e+0], y = dR[3*e+1], z = dR[3*e+2];
  float r = sqrtf(x*x + y*y + z*z);
  float inv = 1.0f / fmaxf(r, 1e-6f);
  const float SQ3 = 1.7320508075688772f;
  sh1[3*e+0] = SQ3 * x * inv;
  sh1[3*e+1] = SQ3 * y * inv;
  sh1[3*e+2] = SQ3 * z * inv;
}

// ---------------- node embedding (fallback path only) ----------------
__global__ void k_embed(const float* __restrict__ nodes, const float* __restrict__ W,
                        float* __restrict__ s){
  int idx = blockIdx.x*256 + threadIdx.x;   // N*64 exact
  int n = idx>>6, o = idx&63;
  float a = nodes[n*4+0]*W[o] + nodes[n*4+1]*W[64+o]
          + nodes[n*4+2]*W[128+o] + nodes[n*4+3]*W[192+o];
  s[idx] = 0.5f*a;
}

// ---------------- edge pre-permute (fast path): kills dependent gather chains ----
__global__ void k_prep(const float* __restrict__ dR, const int* __restrict__ senders,
                       const int* __restrict__ perm,
                       float* __restrict__ sh1, float* __restrict__ dRp,
                       int* __restrict__ sendp){
  int p = blockIdx.x*256 + threadIdx.x;
  if (p >= NE) return;
  int e = perm[p];
  float x = dR[3*e+0], y = dR[3*e+1], z = dR[3*e+2];
  dRp[3*p+0] = x; dRp[3*p+1] = y; dRp[3*p+2] = z;
  float r = sqrtf(x*x + y*y + z*z);
  float inv = 1.0f / fmaxf(r, 1e-6f);
  const float SQ3 = 1.7320508075688772f;
  sh1[3*p+0] = SQ3 * x * inv;
  sh1[3*p+1] = SQ3 * y * inv;
  sh1[3*p+2] = SQ3 * z * inv;
  sendp[p] = senders[e];
}

// ---------------- one-time weight transpose: W[i][e][o] -> W[i][o][e] ------------
__global__ void k_wt(const float* __restrict__ Wscs, const float* __restrict__ Wscv,
                     float* __restrict__ Wst, float* __restrict__ Wvt){
  int idx = blockIdx.x*256 + threadIdx.x;
  if (idx < 49152){                       // 2 layers x 64 x 4 x 96
    int l = idx/24576, r = idx - l*24576;
    int i = r/384; int rem = r - i*384; int e = rem/96; int o = rem - e*96;
    Wst[l*24576 + i*384 + o*4 + e] = Wscs[idx];
  } else if (idx < 49152 + 8192){         // 2 layers x 32 x 4 x 32
    int k = idx - 49152;
    int l = k/4096, r = k - l*4096;
    int i = r/128; int rem = r - i*128; int e = rem/32; int op = rem - e*32;
    Wvt[l*4096 + i*128 + op*4 + e] = Wscv[idx];
  }
}

// ---------------- counting sort of edges by receiver ----------------
__global__ void k_hist(const int* __restrict__ receivers, int* __restrict__ cnt){
  int e = blockIdx.x*256 + threadIdx.x;
  if (e < NE) atomicAdd(&cnt[receivers[e]], 1);
}

__global__ void k_scan(const int* __restrict__ cnt, int* __restrict__ row, int* __restrict__ cur){
  __shared__ int lsum[1024];
  int t = threadIdx.x;
  int base = t*20;
  int local[20];
  int s = 0;
  #pragma unroll
  for (int i=0;i<20;i++){
    int idx = base+i;
    int v = (idx<NN) ? cnt[idx] : 0;
    local[i] = s; s += v;
  }
  lsum[t] = s; __syncthreads();
  for (int off=1; off<1024; off<<=1){
    int v = (t>=off) ? lsum[t-off] : 0;
    __syncthreads();
    lsum[t] += v;
    __syncthreads();
  }
  int pre = (t>0) ? lsum[t-1] : 0;
  #pragma unroll
  for (int i=0;i<20;i++){
    int idx = base+i;
    if (idx<NN){ int r = pre+local[i]; row[idx]=r; cur[idx]=r; }
  }
  if (t==1023) row[NN] = lsum[1023];
}

__global__ void k_scatter(const int* __restrict__ receivers, int* __restrict__ cur,
                          int* __restrict__ perm){
  int e = blockIdx.x*256 + threadIdx.x;
  if (e < NE){
    int d = receivers[e];
    int p = atomicAdd(&cur[d], 1);
    perm[p] = e;
  }
}

// ---------------- per-layer node linears: 16 nodes/block, 4 nodes/wave ----------
// Round-15/16: activation LDS reads vectorized to float4 broadcasts -- the scalar
// form issued ~1280 ds_read_b32/thread (the kernel's largest instruction
// population; all broadcast so conflict-free, but pure issue cost). ls rows are
// contiguous; lv is re-laid c-major ([j][c*32+op]) so v-reads are contiguous too.
// Global in/out formats unchanged.
__global__ void k_node(const float* __restrict__ s, const float* __restrict__ v,
                       const float* __restrict__ attrs, const float* __restrict__ W_embed,
                       const float* __restrict__ W1s, const float* __restrict__ W1v,
                       const float* __restrict__ Wscst, const float* __restrict__ Wscvt,
                       __half* __restrict__ s1, __half* __restrict__ v1,
                       float* __restrict__ scs, float* __restrict__ scv){
  __shared__ float ls[16][64];
  __shared__ float lv[16][96];   // c-major: [j][c*32+op]
  __shared__ float la[16][4];
  int tid = threadIdx.x;
  int nb = blockIdx.x*16;   // 1250*16 = 20000 exact
  if (W_embed){
    // layer 0: ls = embed(nodes) = (nodes @ W_embed)/2 ; v == 0 -> skip lv
    for (int i=tid;i<1024;i+=256){
      int j=i>>6, o=i&63;
      int n = nb + j;
      float a = attrs[n*4+0]*W_embed[o] + attrs[n*4+1]*W_embed[64+o]
              + attrs[n*4+2]*W_embed[128+o] + attrs[n*4+3]*W_embed[192+o];
      ls[j][o] = 0.5f*a;
    }
  } else {
    for (int i=tid;i<1024;i+=256) ls[i>>6][i&63] = s[(size_t)(nb+(i>>6))*64 + (i&63)];
    for (int i=tid;i<1536;i+=256){
      int j=i/96, q=i-96*j;
      int op=q/3, c=q-3*op;
      lv[j][c*32+op] = v[(size_t)(nb+j)*96+q];
    }
  }
  if (tid<64) la[tid>>2][tid&3] = attrs[(nb+(tid>>2))*4 + (tid&3)];
  __syncthreads();
  int w = tid>>6, q = tid&63;
  int jb = w*4;                       // this wave's 4 nodes: nb+jb .. nb+jb+3
  float laj[4][4];
  #pragma unroll
  for (int j=0;j<4;j++)
    #pragma unroll
    for (int e=0;e<4;e++) laj[j][e] = la[jb+j][e];

  // s1 = s @ W1s / 8  (weight loads batched x4; activation reads float4 bcast)
  {
    float acc[4] = {0,0,0,0};
    for (int i=0;i<64;i+=4){
      float wv0 = W1s[(i+0)*64+q];
      float wv1 = W1s[(i+1)*64+q];
      float wv2 = W1s[(i+2)*64+q];
      float wv3 = W1s[(i+3)*64+q];
      #pragma unroll
      for (int j=0;j<4;j++){
        float4 sv4 = *(const float4*)&ls[jb+j][i];
        acc[j] = fmaf(sv4.x, wv0, acc[j]);
        acc[j] = fmaf(sv4.y, wv1, acc[j]);
        acc[j] = fmaf(sv4.z, wv2, acc[j]);
        acc[j] = fmaf(sv4.w, wv3, acc[j]);
      }
    }
    #pragma unroll
    for (int j=0;j<4;j++) s1[(size_t)(nb+jb+j)*64+q] = __float2half(acc[j]*0.125f);
  }
  // sc_s (two-stage, weight loads batched x4, activation float4 bcast)
  #pragma unroll 1
  for (int o=q;o<96;o+=64){
    float t0[4]={0,0,0,0}, t1[4]={0,0,0,0}, t2[4]={0,0,0,0}, t3[4]={0,0,0,0};
    for (int i=0;i<64;i+=4){
      float4 wa = *(const float4*)(Wscst + (i+0)*384 + o*4);
      float4 wb = *(const float4*)(Wscst + (i+1)*384 + o*4);
      float4 wc = *(const float4*)(Wscst + (i+2)*384 + o*4);
      float4 wd = *(const float4*)(Wscst + (i+3)*384 + o*4);
      #pragma unroll
      for (int j=0;j<4;j++){
        float4 sv4 = *(const float4*)&ls[jb+j][i];
        t0[j] = fmaf(sv4.x, wa.x, t0[j]); t1[j] = fmaf(sv4.x, wa.y, t1[j]);
        t2[j] = fmaf(sv4.x, wa.z, t2[j]); t3[j] = fmaf(sv4.x, wa.w, t3[j]);
        t0[j] = fmaf(sv4.y, wb.x, t0[j]); t1[j] = fmaf(sv4.y, wb.y, t1[j]);
        t2[j] = fmaf(sv4.y, wb.z, t2[j]); t3[j] = fmaf(sv4.y, wb.w, t3[j]);
        t0[j] = fmaf(sv4.z, wc.x, t0[j]); t1[j] = fmaf(sv4.z, wc.y, t1[j]);
        t2[j] = fmaf(sv4.z, wc.z, t2[j]); t3[j] = fmaf(sv4.z, wc.w, t3[j]);
        t0[j] = fmaf(sv4.w, wd.x, t0[j]); t1[j] = fmaf(sv4.w, wd.y, t1[j]);
        t2[j] = fmaf(sv4.w, wd.z, t2[j]); t3[j] = fmaf(sv4.w, wd.w, t3[j]);
      }
    }
    #pragma unroll
    for (int j=0;j<4;j++){
      float acc = t0[j]*laj[j][0] + t1[j]*laj[j][1]
                + t2[j]*laj[j][2] + t3[j]*laj[j][3];
      scs[(size_t)(nb+jb+j)*96+o] = acc*0.0625f;
    }
  }
  if (W_embed){
    // layer 0: v == 0 -> v1 = 0, sc_v = 0 (exact)
    #pragma unroll 1
    for (int f=q;f<96;f+=64){
      #pragma unroll
      for (int j=0;j<4;j++){
        v1[(size_t)(nb+jb+j)*96+f] = __float2half(0.0f);
        scv[(size_t)(nb+jb+j)*96+f] = 0.0f;
      }
    }
    return;
  }
  // v1 (weight loads batched x4; lv reads contiguous float4 via c-major layout)
  #pragma unroll 1
  for (int f=q;f<96;f+=64){
    int op=f/3, c=f-3*op;
    float acc[4] = {0,0,0,0};
    for (int i=0;i<32;i+=4){
      float wv0 = W1v[(i+0)*32+op];
      float wv1 = W1v[(i+1)*32+op];
      float wv2 = W1v[(i+2)*32+op];
      float wv3 = W1v[(i+3)*32+op];
      #pragma unroll
      for (int j=0;j<4;j++){
        float4 vv4 = *(const float4*)&lv[jb+j][c*32+i];
        acc[j] = fmaf(vv4.x, wv0, acc[j]);
        acc[j] = fmaf(vv4.y, wv1, acc[j]);
        acc[j] = fmaf(vv4.z, wv2, acc[j]);
        acc[j] = fmaf(vv4.w, wv3, acc[j]);
      }
    }
    #pragma unroll
    for (int j=0;j<4;j++) v1[(size_t)(nb+jb+j)*96+f] = __float2half(acc[j]*0.17677669529663687f);
  }
  // sc_v (two-stage, weight loads batched x4, lv float4)
  #pragma unroll 1
  for (int f=q;f<96;f+=64){
    int op=f/3, c=f-3*op;
    float t0[4]={0,0,0,0}, t1[4]={0,0,0,0}, t2[4]={0,0,0,0}, t3[4]={0,0,0,0};
    for (int i=0;i<32;i+=4){
      float4 wa = *(const float4*)(Wscvt + (i+0)*128 + op*4);
      float4 wb = *(const float4*)(Wscvt + (i+1)*128 + op*4);
      float4 wc = *(const float4*)(Wscvt + (i+2)*128 + op*4);
      float4 wd = *(const float4*)(Wscvt + (i+3)*128 + op*4);
      #pragma unroll
      for (int j=0;j<4;j++){
        float4 vv4 = *(const float4*)&lv[jb+j][c*32+i];
        t0[j] = fmaf(vv4.x, wa.x, t0[j]); t1[j] = fmaf(vv4.x, wa.y, t1[j]);
        t2[j] = fmaf(vv4.x, wa.z, t2[j]); t3[j] = fmaf(vv4.x, wa.w, t3[j]);
        t0[j] = fmaf(vv4.y, wb.x, t0[j]); t1[j] = fmaf(vv4.y, wb.y, t1[j]);
        t2[j] = fmaf(vv4.y, wb.z, t2[j]); t3[j] = fmaf(vv4.y, wb.w, t3[j]);
        t0[j] = fmaf(vv4.z, wc.x, t0[j]); t1[j] = fmaf(vv4.z, wc.y, t1[j]);
        t2[j] = fmaf(vv4.z, wc.z, t2[j]); t3[j] = fmaf(vv4.z, wc.w, t3[j]);
        t0[j] = fmaf(vv4.w, wd.x, t0[j]); t1[j] = fmaf(vv4.w, wd.y, t1[j]);
        t2[j] = fmaf(vv4.w, wd.z, t2[j]); t3[j] = fmaf(vv4.w, wd.w, t3[j]);
      }
    }
    #pragma unroll
    for (int j=0;j<4;j++){
      float acc = t0[j]*laj[j][0] + t1[j]*laj[j][1]
                + t2[j]*laj[j][2] + t3[j]*laj[j][3];
      scv[(size_t)(nb+jb+j)*96+f] = acc*0.08838834764831845f;
    }
  }
}

// ---------------- edge MLP: persistent-weight multi-tile version -----------------
// R2 stored o-major (round-13): phase-C B-frags are 2 contiguous ds_read_b128.
#define W2S 36
#define HT2S 68
__launch_bounds__(256, 4)
__global__ void k_edgew(const float* __restrict__ dRp,
                        const int* __restrict__ row, int n0, int n1, int cap,
                        const float* __restrict__ R0, const float* __restrict__ R1,
                        const float* __restrict__ R2,
                        __half* __restrict__ wbuf){
  __shared__ __align__(16) f16x2 hT2[32*HT2S];  // 8.7 KB: [kpair][e] stride 68; rb staging (fp32 view) / h1 / h2
  __shared__ __align__(16) float r0s[512];      // 2 KB: R0 fp32
  __shared__ __align__(16) f16x2 wgt2[192*W2S]; // 27 KB: R2 o-major [o][kp], persistent
  int tid = threadIdx.x;
  int p0 = row[n0], p1 = row[n1];
  int vmax = p1 - p0; if (vmax > cap) vmax = cap;
  int ntiles = (vmax + 63) >> 6;

  int eg = tid & 15, e0 = eg*4;
  int jg = tid >> 4, j0 = jg*4;
  int wv = tid >> 6;
  int ln = tid & 63;
  int col = ln & 15;
  int quad = ln >> 4;

  // ---- persistent staging (once per block) ----
  if (tid < 128) ((float4*)r0s)[tid] = ((const float4*)R0)[tid];
  for (int i=tid; i<6144; i+=256){
    int kp = i/192, o = i-192*kp;     // coalesced R2 reads; o-major LDS writes
    wgt2[o*W2S + kp] = pack2f(R2[(2*kp)*192 + o], R2[(2*kp+1)*192 + o]);
  }
  // R1 A-frags direct from global into registers
  union { uint4 u; f16x8 v; } rA0, rA1;
  {
    int jA = 16*wv + col;
    rA0.u.x = packu2f(R1[(8*quad+0)*64 + jA], R1[(8*quad+1)*64 + jA]);
    rA0.u.y = packu2f(R1[(8*quad+2)*64 + jA], R1[(8*quad+3)*64 + jA]);
    rA0.u.z = packu2f(R1[(8*quad+4)*64 + jA], R1[(8*quad+5)*64 + jA]);
    rA0.u.w = packu2f(R1[(8*quad+6)*64 + jA], R1[(8*quad+7)*64 + jA]);
    rA1.u.x = packu2f(R1[(32+8*quad+0)*64 + jA], R1[(32+8*quad+1)*64 + jA]);
    rA1.u.y = packu2f(R1[(32+8*quad+2)*64 + jA], R1[(32+8*quad+3)*64 + jA]);
    rA1.u.z = packu2f(R1[(32+8*quad+4)*64 + jA], R1[(32+8*quad+5)*64 + jA]);
    rA1.u.w = packu2f(R1[(32+8*quad+6)*64 + jA], R1[(32+8*quad+7)*64 + jA]);
  }
  // visibility of r0s/wgt2 covered by the loop-top barrier of the first tile

  for (int tile = blockIdx.x; tile < ntiles; tile += gridDim.x){
    int tbase = tile*64;
    int vcnt = vmax - tbase; if (vcnt > 64) vcnt = 64;

    __syncthreads();   // [A] staging visible / prev tile's phase-C hT2 reads done
    // stage rb for the 64 edges into hT2 region (fp32 view, rows k<8)
    float* hTf = (float*)hT2;
    if (tid < 64){
      float rbv[8];
      if (tid < vcnt){
        bessel8(dRp, p0 + tbase + tid, rbv);
      } else {
        #pragma unroll
        for (int k=0;k<8;k++) rbv[k]=0.0f;
      }
      #pragma unroll
      for (int k=0;k<8;k++) hTf[k*HT2S + tid] = rbv[k];
    }
    __syncthreads();   // [B]

    // read rb tile into regs (before overwriting hT2 with h1 pairs)
    float rb[8][4];
    {
      const float4* hTf4 = (const float4*)hTf;
      #pragma unroll
      for (int k=0;k<8;k++){
        float4 v = hTf4[k*17 + eg];
        rb[k][0]=v.x; rb[k][1]=v.y; rb[k][2]=v.z; rb[k][3]=v.w;
      }
    }
    // phase A: h1 tile (fp32 math, tiny K=8)
    float a[4][4];
    #pragma unroll
    for (int j=0;j<4;j++)
      #pragma unroll
      for (int e=0;e<4;e++) a[j][e]=0.0f;
    {
      const float4* r0s4 = (const float4*)r0s;
      #pragma unroll
      for (int k=0;k<8;k++){
        float4 w = r0s4[k*16 + jg];
        float wj[4] = {w.x,w.y,w.z,w.w};
        #pragma unroll
        for (int j=0;j<4;j++)
          #pragma unroll
          for (int e=0;e<4;e++) a[j][e] = fmaf(rb[k][e], wj[j], a[j][e]);
      }
    }
    #pragma unroll
    for (int j=0;j<4;j++)
      #pragma unroll
      for (int e=0;e<4;e++) a[j][e] = silu_f(a[j][e]*0.3535533905932738f);
    __syncthreads();   // [C] all rb reads complete
    // write h1 as k-pairs: rows j0/2, j0/2+1 of hT2
    #pragma unroll
    for (int jp=0;jp<2;jp++){
      union {uint4 u; f16x2 h[4];} U;
      #pragma unroll
      for (int e=0;e<4;e++) U.h[e] = pack2f(a[2*jp][e], a[2*jp+1][e]);
      *(uint4*)(hT2 + (j0/2 + jp)*HT2S + e0) = U.u;
    }
    __syncthreads();   // [D]

    // phase B via MFMA: wave wv owns j-tile [16*wv,16*wv+16), loops 4 e-tiles.
    {
      const unsigned int* hT2u = (const unsigned int*)hT2;
      f32x4 accB[4];
      #pragma unroll
      for (int nt=0; nt<4; nt++){
        union { uint4 u; f16x8 v; } B0, B1;
        int eB = 16*nt + col;
        B0.u.x = hT2u[(4*quad+0)*HT2S + eB];
        B0.u.y = hT2u[(4*quad+1)*HT2S + eB];
        B0.u.z = hT2u[(4*quad+2)*HT2S + eB];
        B0.u.w = hT2u[(4*quad+3)*HT2S + eB];
        B1.u.x = hT2u[(16+4*quad+0)*HT2S + eB];
        B1.u.y = hT2u[(16+4*quad+1)*HT2S + eB];
        B1.u.z = hT2u[(16+4*quad+2)*HT2S + eB];
        B1.u.w = hT2u[(16+4*quad+3)*HT2S + eB];
        f32x4 acc = {0.0f,0.0f,0.0f,0.0f};
        acc = __builtin_amdgcn_mfma_f32_16x16x32_f16(rA0.v, B0.v, acc, 0, 0, 0);
        acc = __builtin_amdgcn_mfma_f32_16x16x32_f16(rA1.v, B1.v, acc, 0, 0, 0);
        accB[nt] = acc;
      }
      __syncthreads();   // [E] all h1 (hT2) reads complete
      // silu + pack + write h2^T as k-pairs
      #pragma unroll
      for (int nt=0; nt<4; nt++){
        float h0 = silu_f(accB[nt][0]*0.125f);
        float h1v = silu_f(accB[nt][1]*0.125f);
        float h2v = silu_f(accB[nt][2]*0.125f);
        float h3v = silu_f(accB[nt][3]*0.125f);
        hT2[(8*wv + 2*quad + 0)*HT2S + 16*nt + col] = pack2f(h0, h1v);
        hT2[(8*wv + 2*quad + 1)*HT2S + 16*nt + col] = pack2f(h2v, h3v);
      }
    }
    __syncthreads();   // [F] h2 visible

    // phase C via MFMA: wave wv handles edges [16*wv, 16*wv+16)
    {
      const unsigned int* hT2u = (const unsigned int*)hT2;
      const unsigned int* wgt2u = (const unsigned int*)wgt2;
      int eA = 16*wv + col;     // A's m index
      union { uint4 u; f16x8 v; } A0, A1;
      A0.u.x = hT2u[(4*quad+0)*HT2S + eA];
      A0.u.y = hT2u[(4*quad+1)*HT2S + eA];
      A0.u.z = hT2u[(4*quad+2)*HT2S + eA];
      A0.u.w = hT2u[(4*quad+3)*HT2S + eA];
      A1.u.x = hT2u[(16+4*quad+0)*HT2S + eA];
      A1.u.y = hT2u[(16+4*quad+1)*HT2S + eA];
      A1.u.z = hT2u[(16+4*quad+2)*HT2S + eA];
      A1.u.w = hT2u[(16+4*quad+3)*HT2S + eA];
      int erow = 16*wv + 4*quad;           // D rows: erow+0..3
      #pragma unroll
      for (int ot=0; ot<12; ot++){
        int o = 16*ot + col;
        union { uint4 u; f16x8 v; } B0, B1;
        B0.u = *(const uint4*)(wgt2u + o*W2S + 4*quad);
        B1.u = *(const uint4*)(wgt2u + o*W2S + 16 + 4*quad);
        f32x4 acc = {0.0f,0.0f,0.0f,0.0f};
        acc = __builtin_amdgcn_mfma_f32_16x16x32_f16(A0.v, B0.v, acc, 0, 0, 0);
        acc = __builtin_amdgcn_mfma_f32_16x16x32_f16(A1.v, B1.v, acc, 0, 0, 0);
        // direct predicated stores (uniform-true branch for full tiles)
        #pragma unroll
        for (int r=0;r<4;r++){
          int eib = erow + r;
          if (eib < vcnt)
            wbuf[(size_t)(tbase+eib)*192 + o] = __float2half(acc[r]);
        }
      }
    }
  }
}

// ---------------- gather: role-split + 8-deep load batching, spill-free ---------
__launch_bounds__(128, 4)
__global__ void k_gather(const __half* __restrict__ wbuf,
                         const int* __restrict__ row, const int* __restrict__ sendp,
                         const float* __restrict__ sh1,
                         const __half* __restrict__ s1, const __half* __restrict__ v1,
                         int n0, int cap,
                         float* __restrict__ a_s, float* __restrict__ a_v){
  __shared__ int   srcs[ECAP];
  __shared__ float sh1r[ECAP*3];
  int n = n0 + blockIdx.x;
  int t = threadIdx.x;
  int pc0 = row[n0];
  int p0 = row[n], p1 = row[n+1];
  int pmax = pc0 + cap; if (p1 > pmax) p1 = pmax;

  int iv = (t - 64) >> 1;          // 0..31 for vrole
  bool even = ((t & 1) == 0);

  float acs = 0.0f, av0 = 0.0f, av1 = 0.0f, av2 = 0.0f;

  for (int base = p0; base < p1; base += ECAP){
    int bc = p1 - base; if (bc > ECAP) bc = ECAP;
    __syncthreads();   // protect LDS reuse across batches
    if (t < bc){
      srcs[t] = sendp[base + t];
      sh1r[3*t+0] = sh1[3*(base+t)+0];
      sh1r[3*t+1] = sh1[3*(base+t)+1];
      sh1r[3*t+2] = sh1[3*(base+t)+2];
    }
    __syncthreads();
    const __half* wb = wbuf + (size_t)(base - pc0)*192;
    if (t < 64){
      int o = t;
      int j = 0;
      for (; j + 8 <= bc; j += 8){
        float sv[8], w1[8], w2[8];
        #pragma unroll
        for (int u=0;u<8;u++){
          const __half* wr = wb + (j+u)*192;
          sv[u] = __half2float(s1[(size_t)srcs[j+u]*64 + o]);
          w1[u] = __half2float(wr[o]);
          w2[u] = __half2float(wr[64 + o]);
        }
        #pragma unroll
        for (int u=0;u<8;u++){
          acs = fmaf(w1[u], sv[u], acs);
          float uu = w2[u] * sv[u];
          av0 = fmaf(uu, sh1r[3*(j+u)+0], av0);
          av1 = fmaf(uu, sh1r[3*(j+u)+1], av1);
          av2 = fmaf(uu, sh1r[3*(j+u)+2], av2);
        }
      }
      for (; j < bc; ++j){
        const __half* wr = wb + j*192;
        float sv = __half2float(s1[(size_t)srcs[j]*64 + o]);
        float w1v = __half2float(wr[o]);
        float w2v = __half2float(wr[64 + o]);
        acs = fmaf(w1v, sv, acs);
        float uu = w2v * sv;
        av0 = fmaf(uu, sh1r[3*j+0], av0);
        av1 = fmaf(uu, sh1r[3*j+1], av1);
        av2 = fmaf(uu, sh1r[3*j+2], av2);
      }
    } else {
      int j = 0;
      for (; j + 8 <= bc; j += 8){
        float v0[8], vc1[8], vc2[8], w3[8], w4[8];
        #pragma unroll
        for (int u=0;u<8;u++){
          const __half* wr = wb + (j+u)*192;
          const __half* vr = v1 + (size_t)srcs[j+u]*96 + 3*iv;
          v0[u]  = __half2float(vr[0]);
          vc1[u] = __half2float(vr[1]);
          vc2[u] = __half2float(vr[2]);
          w3[u]  = __half2float(wr[128 + iv]);
          w4[u]  = __half2float(wr[160 + iv]);
        }
        #pragma unroll
        for (int u=0;u<8;u++){
          if (even){
            float dv = v0[u]*sh1r[3*(j+u)+0] + vc1[u]*sh1r[3*(j+u)+1] + vc2[u]*sh1r[3*(j+u)+2];
            acs = fmaf(w4[u], dv, acs);
            av0 = fmaf(w3[u], v0[u], av0);
          } else {
            av1 = fmaf(w3[u], vc1[u], av1);
            av2 = fmaf(w3[u], vc2[u], av2);
          }
        }
      }
      for (; j < bc; ++j){
        const __half* wr = wb + j*192;
        const __half* vr = v1 + (size_t)srcs[j]*96 + 3*iv;
        float v0 = __half2float(vr[0]);
        float vc1 = __half2float(vr[1]);
        float vc2 = __half2float(vr[2]);
        float w3 = __half2float(wr[128 + iv]);
        if (even){
          float w4 = __half2float(wr[160 + iv]);
          float dv = v0*sh1r[3*j+0] + vc1*sh1r[3*j+1] + vc2*sh1r[3*j+2];
          acs = fmaf(w4, dv, acs);
          av0 = fmaf(w3, v0, av0);
        } else {
          av1 = fmaf(w3, vc1, av1);
          av2 = fmaf(w3, vc2, av2);
        }
      }
    }
  }

  if (t < 64){
    a_s[(size_t)n*96 + t] = 0.03125f*acs;              // (1/8)*(1/sqrt(16))
    a_v[(size_t)n*288 + 3*t + 0] = 0.03125f*av0;
    a_v[(size_t)n*288 + 3*t + 1] = 0.03125f*av1;
    a_v[(size_t)n*288 + 3*t + 2] = 0.03125f*av2;
  } else if (even){
    a_s[(size_t)n*96 + 64 + iv] = 0.018042195912175807f*acs;   // 0.03125/sqrt(3)
    a_v[(size_t)n*288 + 192 + 3*iv + 0] = 0.03125f*av0;
  } else {
    a_v[(size_t)n*288 + 192 + 3*iv + 1] = 0.03125f*av1;
    a_v[(size_t)n*288 + 192 + 3*iv + 2] = 0.03125f*av2;
  }
}

// ---------------- fallback: atomic edge kernel (only if ws too small) ----------------
__device__ __forceinline__ void mlp_h2(const float* __restrict__ R0,
                                       const float* lR1, const float rb[8],
                                       float h2[64]){
  float h1[64];
  #pragma unroll
  for (int j=0;j<64;j+=4){
    float a0=0,a1=0,a2=0,a3=0;
    #pragma unroll
    for (int k=0;k<8;k++){
      float r = rb[k];
      const float* wp = R0 + k*64 + j;
      a0 = fmaf(r, wp[0], a0); a1 = fmaf(r, wp[1], a1);
      a2 = fmaf(r, wp[2], a2); a3 = fmaf(r, wp[3], a3);
    }
    h1[j+0]=silu_f(a0*0.3535533905932738f);
    h1[j+1]=silu_f(a1*0.3535533905932738f);
    h1[j+2]=silu_f(a2*0.3535533905932738f);
    h1[j+3]=silu_f(a3*0.3535533905932738f);
  }
  #pragma unroll
  for (int j=0;j<64;j+=4){
    float a0=0,a1=0,a2=0,a3=0;
    #pragma unroll
    for (int k=0;k<64;k++){
      float h = h1[k];
      float4 w4 = *(const float4*)(lR1 + k*64 + j);
      a0 = fmaf(h,w4.x,a0); a1 = fmaf(h,w4.y,a1);
      a2 = fmaf(h,w4.z,a2); a3 = fmaf(h,w4.w,a3);
    }
    h2[j+0]=silu_f(a0*0.125f);
    h2[j+1]=silu_f(a1*0.125f);
    h2[j+2]=silu_f(a2*0.125f);
    h2[j+3]=silu_f(a3*0.125f);
  }
}

__launch_bounds__(256, 2)
__global__ void k_edge(const float* __restrict__ dR, const float* __restrict__ sh1,
                       const int* __restrict__ senders, const int* __restrict__ receivers,
                       const __half* __restrict__ s1, const __half* __restrict__ v1,
                       const float* __restrict__ R0, const float* __restrict__ R1,
                       const float* __restrict__ R2,
                       float* __restrict__ a_s, float* __restrict__ a_v){
  __shared__ __align__(16) float lR1[64*64];
  __shared__ __align__(16) float lR2[64*192];
  int tid = threadIdx.x;
  for (int i=tid;i<4096;i+=256)  lR1[i]=R1[i];
  for (int i=tid;i<12288;i+=256) lR2[i]=R2[i];
  __syncthreads();
  int e = blockIdx.x*256 + tid;
  float rb[8];
  bessel8(dR, e, rb);
  float h2[64];
  mlp_h2(R0, lR1, rb, h2);
  int src = senders[e], dst = receivers[e];
  float sx=sh1[3*e+0], sy=sh1[3*e+1], sz=sh1[3*e+2];
  const __half* srow = s1 + (size_t)src*64;
  const __half* vrow = v1 + (size_t)src*96;
  float* asr = a_s + (size_t)dst*96;
  float* avr = a_v + (size_t)dst*288;
  #pragma unroll 1
  for (int o=0;o<64;o+=4){
    float w10=0,w11=0,w12=0,w13=0, w20=0,w21=0,w22=0,w23=0;
    #pragma unroll
    for (int k=0;k<64;k++){
      float h = h2[k];
      float4 wa = *(const float4*)(lR2 + k*192 + o);
      float4 wb = *(const float4*)(lR2 + k*192 + 64 + o);
      w10=fmaf(h,wa.x,w10); w11=fmaf(h,wa.y,w11); w12=fmaf(h,wa.z,w12); w13=fmaf(h,wa.w,w13);
      w20=fmaf(h,wb.x,w20); w21=fmaf(h,wb.y,w21); w22=fmaf(h,wb.z,w22); w23=fmaf(h,wb.w,w23);
    }
    float sev[4] = {__half2float(srow[o+0]), __half2float(srow[o+1]),
                    __half2float(srow[o+2]), __half2float(srow[o+3])};
    float w1a[4] = {w10,w11,w12,w13};
    float w2a[4] = {w20,w21,w22,w23};
    #pragma unroll
    for (int u=0;u<4;u++){
      atomicAdd(asr+o+u, 0.03125f*w1a[u]*sev[u]);
      float m = 0.03125f*w2a[u]*sev[u];
      atomicAdd(avr+(o+u)*3+0, m*sx);
      atomicAdd(avr+(o+u)*3+1, m*sy);
      atomicAdd(avr+(o+u)*3+2, m*sz);
    }
  }
  #pragma unroll 1
  for (int i0=0;i0<32;i0+=4){
    float w30=0,w31=0,w32=0,w33=0, w40=0,w41=0,w42=0,w43=0;
    #pragma unroll
    for (int k=0;k<64;k++){
      float h = h2[k];
      float4 wa = *(const float4*)(lR2 + k*192 + 128 + i0);
      float4 wb = *(const float4*)(lR2 + k*192 + 160 + i0);
      w30=fmaf(h,wa.x,w30); w31=fmaf(h,wa.y,w31); w32=fmaf(h,wa.z,w32); w33=fmaf(h,wa.w,w33);
      w40=fmaf(h,wb.x,w40); w41=fmaf(h,wb.y,w41); w42=fmaf(h,wb.z,w42); w43=fmaf(h,wb.w,w43);
    }
    float w3a[4] = {w30,w31,w32,w33};
    float w4a[4] = {w40,w41,w42,w43};
    #pragma unroll
    for (int u=0;u<4;u++){
      int i = i0+u;
      float vx=__half2float(vrow[3*i+0]), vy=__half2float(vrow[3*i+1]), vz=__half2float(vrow[3*i+2]);
      float dv = vx*sx + vy*sy + vz*sz;
      atomicAdd(asr+64+i, 0.018042195912175807f*w4a[u]*dv);
      float m3 = 0.03125f*w3a[u];
      atomicAdd(avr+(64+i)*3+0, m3*vx);
      atomicAdd(avr+(64+i)*3+1, m3*vy);
      atomicAdd(avr+(64+i)*3+2, m3*vz);
    }
  }
}

// ---------------- per-layer output transform: o_s, o_v, gating ----------------
__launch_bounds__(256, 4)
__global__ void k_out(const float* __restrict__ a_s, const float* __restrict__ a_v,
                      const float* __restrict__ scs, const float* __restrict__ scv,
                      const float* __restrict__ W2s, const float* __restrict__ W2v,
                      float* __restrict__ s_out, float* __restrict__ v_out){
  __shared__ float las[16][96];
  __shared__ float lav[16][288];
  __shared__ float los[16][96];
  int tid = threadIdx.x;
  int nb = blockIdx.x*16;   // 1250*16 = 20000 exact
  for (int i=tid;i<1536;i+=256){ int j=i/96,  q=i-96*j;  las[j][q] = a_s[(size_t)(nb+j)*96 +q]; }
  for (int i=tid;i<4608;i+=256){ int j=i/288, q=i-288*j; lav[j][q] = a_v[(size_t)(nb+j)*288+q]; }
  __syncthreads();
  int w = tid>>6, q = tid&63;
  int jb = w*4;                       // this wave's 4 nodes: nb+jb .. nb+jb+3

  // o_s = a_s @ W2s * scale + scs   (outputs o = q and q+64, wave-private los)
  #pragma unroll 1
  for (int o=q; o<96; o+=64){
    float acc[4] = {0,0,0,0};
    for (int i=0;i<96;i++){
      float wv = W2s[i*96+o];
      #pragma unroll
      for (int j=0;j<4;j++) acc[j] = fmaf(las[jb+j][i], wv, acc[j]);
    }
    #pragma unroll
    for (int j=0;j<4;j++)
      los[jb+j][o] = acc[j]*0.10206207261596575f + scs[(size_t)(nb+jb+j)*96+o];
  }
  __syncthreads();   // (wave-private in fact; barrier keeps LDS ordering simple)

  // s_out = silu(o_s[:64])
  #pragma unroll
  for (int j=0;j<4;j++) s_out[(size_t)(nb+jb+j)*64+q] = silu_f(los[jb+j][q]);

  // o_v = a_v @ W2v * scale + scv, gated by silu(o_s[64+op])
  #pragma unroll 1
  for (int f=q; f<96; f+=64){
    int op=f/3, c=f-3*op;
    float acc[4] = {0,0,0,0};
    for (int i=0;i<96;i++){
      float wv = W2v[i*32+op];
      #pragma unroll
      for (int j=0;j<4;j++) acc[j] = fmaf(lav[jb+j][i*3+c], wv, acc[j]);
    }
    #pragma unroll
    for (int j=0;j<4;j++){
      float ov = acc[j]*0.10206207261596575f + scv[(size_t)(nb+jb+j)*96+f];
      float g = silu_f(los[jb+j][64+op]);
      v_out[(size_t)(nb+jb+j)*96+f] = ov*g;
    }
  }
}

// ---------------- final heads: energy + mags ----------------
__global__ void k_final(const float* __restrict__ s, const float* __restrict__ nodes,
                        const int* __restrict__ n_node,
                        const float* __restrict__ Wen1, const float* __restrict__ Wen2,
                        const float* __restrict__ Wm1, const float* __restrict__ Wm2,
                        const float* __restrict__ scale_occ, const float* __restrict__ shift_occ,
                        const float* __restrict__ escale, const float* __restrict__ eshift,
                        float* __restrict__ out){
  __shared__ float eacc[NG];
  __shared__ int goff[NG+1];
  int tid = threadIdx.x;
  if (tid < NG) eacc[tid] = 0.0f;
  if (tid == 0){
    int c = 0; goff[0] = 0;
    for (int g=0; g<NG; g++){ c += n_node[g]; goff[g+1] = c; }
  }
  __syncthreads();
  int n = blockIdx.x*256 + tid;
  if (n < NN){
    float sv[64];
    #pragma unroll
    for (int i=0;i<64;i++) sv[i]=s[(size_t)n*64+i];
    float en=0.0f, m0=0.0f, m1=0.0f;
    #pragma unroll 1
    for (int jj=0;jj<32;jj++){
      float he=0.0f, hm=0.0f;
      #pragma unroll
      for (int i=0;i<64;i++){
        he = fmaf(sv[i], Wen1[i*32+jj], he);
        hm = fmaf(sv[i], Wm1[i*32+jj], hm);
      }
      he *= 0.125f; hm *= 0.125f;
      en = fmaf(he, Wen2[jj], en);
      m0 = fmaf(hm, Wm2[jj*2+0], m0);
      m1 = fmaf(hm, Wm2[jj*2+1], m1);
    }
    const float INVS32 = 0.17677669529663687f;
    en *= INVS32; m0 *= INVS32; m1 *= INVS32;
    en = escale[0]*en + eshift[0];
    int g = 0;
    for (int gg=0; gg<NG; gg++) if (n >= goff[gg+1]) g = gg+1;
    atomicAdd(&eacc[g], en);
    float nx=nodes[n*4+0], ny=nodes[n*4+1], nz=nodes[n*4+2];
    float sc0 = nx*scale_occ[0] + ny*scale_occ[2] + nz*scale_occ[4];
    float sc1 = nx*scale_occ[1] + ny*scale_occ[3] + nz*scale_occ[5];
    float sf0 = nx*shift_occ[0] + ny*shift_occ[2] + nz*shift_occ[4];
    float sf1 = nx*shift_occ[1] + ny*shift_occ[3] + nz*shift_occ[5];
    out[16 + n*2 + 0] = sc0*m0 + sf0;
    out[16 + n*2 + 1] = sc1*m1 + sf1;
  }
  __syncthreads();
  if (tid < NG) atomicAdd(&out[tid], eacc[tid]);
}

extern "C" void kernel_launch(void* const* d_in, const int* in_sizes, int n_in,
                              void* d_out, int out_size, void* d_ws, size_t ws_size,
                              hipStream_t stream){
  const float* nodes   = (const float*)d_in[0];
  const float* dR      = (const float*)d_in[1];
  const int*  senders  = (const int*)d_in[2];
  const int*  receivers= (const int*)d_in[3];
  const int*  n_node   = (const int*)d_in[4];
  const float* W_embed = (const float*)d_in[5];
  const float* W_sc_s  = (const float*)d_in[6];
  const float* W_sc_v  = (const float*)d_in[7];
  const float* W_l1_s  = (const float*)d_in[8];
  const float* W_l1_v  = (const float*)d_in[9];
  const float* Wr0     = (const float*)d_in[10];
  const float* Wr1     = (const float*)d_in[11];
  const float* Wr2     = (const float*)d_in[12];
  const float* W_l2_s  = (const float*)d_in[13];
  const float* W_l2_v  = (const float*)d_in[14];
  const float* W_en1   = (const float*)d_in[15];
  const float* W_en2   = (const float*)d_in[16];
  const float* W_mag1  = (const float*)d_in[17];
  const float* W_mag2  = (const float*)d_in[18];
  const float* scale_occ = (const float*)d_in[19];
  const float* shift_occ = (const float*)d_in[20];
  const float* escale  = (const float*)d_in[21];
  const float* eshift  = (const float*)d_in[22];
  float* out = (float*)d_out;
  float* ws  = (float*)d_ws;

  // ---- workspace map (float-index offsets) ----
  float*  sh1  = ws + 0;         // NE*3 f32 (PERMUTED order in fast path)
  float*  sA   = ws + 960000;    // NN*64 f32
  float*  vA   = ws + 2240000;   // NN*96 f32
  __half* s1h  = (__half*)(ws + 4160000);   // NN*64 halves = 640,000 f32
  __half* v1h  = (__half*)(ws + 4800000);   // NN*96 halves = 960,000 f32
  float*  dRp  = ws + 5760000;   // NE*3 f32 permuted dR = 960,000 f32
  int*    sendp= (int*)(ws + 6720000);      // NE ints = 320,000 -> ends 7,040,000
  float*  Wst  = ws + 7040000;   // 2*24576 = 49,152 transposed W_sc_s
  float*  Wvt  = ws + 7089152;   // 2*4096  =  8,192 transposed W_sc_v -> ends 7,097,344
  float*  scs  = ws + 7360000;   // 1,920,000 f32
  float*  scv  = ws + 9280000;   // 1,920,000 f32
  float*  a_s  = ws + 11200000;  // 1,920,000 f32
  float*  a_v  = ws + 13120000;  // 5,760,000 f32 -> ends 18,880,000
  int*    cnt  = (int*)(ws + 18880000);  // 20,000
  int*    row  = (int*)(ws + 18900000);  // 20,001
  int*    cur  = (int*)(ws + 18920004);  // 20,000
  int*    perm = (int*)(ws + 18940004);  // 320,000 -> ends 19,260,004
  __half* wbuf = (__half*)(ws + 19260008); // capacity-adaptive fp16, 16B-aligned

  size_t wsf = ws_size / 4;
  // fp16 wbuf: 192 halves = 384 B per edge
  size_t cap_edges = (wsf > 19260008) ? ((wsf - 19260008)*4) / 384 : 0;
  if (cap_edges > 128) cap_edges -= 64;   // slack for 64-edge tile granularity
  const bool fast = cap_edges >= 4096;
  int cap = (int)((cap_edges > (size_t)NE) ? (size_t)NE + 8192 : cap_edges);
  // single chunk when wbuf can hold ALL edges; else the statistical heuristic.
  int npc;
  if (cap_edges > (size_t)NE){
    npc = NN;
  } else {
    npc = (int)(cap / 20); if (npc < 1) npc = 1; if (npc > NN) npc = NN;
  }
  int nchunk = (NN + npc - 1) / npc;

  hipMemsetAsync(out, 0, 16*sizeof(float), stream);             // energy accumulators

  k_wt<<<225, 256, 0, stream>>>(W_sc_s, W_sc_v, Wst, Wvt);

  if (fast){
    hipMemsetAsync(cnt, 0, NN*sizeof(int), stream);
    k_hist<<<1250, 256, 0, stream>>>(receivers, cnt);
    k_scan<<<1, 1024, 0, stream>>>(cnt, row, cur);
    k_scatter<<<1250, 256, 0, stream>>>(receivers, cur, perm);
    k_prep<<<1250, 256, 0, stream>>>(dR, senders, perm, sh1, dRp, sendp);
  } else {
    // fallback needs materialized sA embed + zero vA (k_edge path reads them)
    hipMemsetAsync(vA, 0, (size_t)NN*96*sizeof(float), stream);
    k_embed<<<5000, 256, 0, stream>>>(nodes, W_embed, sA);
    k_geom<<<1250, 256, 0, stream>>>(dR, sh1);
  }

  for (int l=0; l<2; l++){
    // layer 0 (fast path): embed fused into k_node; v==0 path skipped exactly.
    const float* Wemb = (l==0 && fast) ? W_embed : nullptr;
    k_node<<<1250, 256, 0, stream>>>(sA, vA, nodes, Wemb,
                                     W_l1_s + l*4096, W_l1_v + l*1024,
                                     Wst + l*24576, Wvt + l*4096,
                                     s1h, v1h, scs, scv);
    if (fast){
      for (int ck=0; ck<nchunk; ck++){
        int n0 = ck*npc;
        int n1 = n0 + npc; if (n1 > NN) n1 = NN;
        int cover = (n1-n0)*17 + 4096; if (cover > cap) cover = cap;
        int ntile_ub = (cover+63)/64;
        int grid = ntile_ub < 1024 ? ntile_ub : 1024;   // 4 blocks/CU residency
        k_edgew<<<grid, 256, 0, stream>>>(dRp, row, n0, n1, cap,
                                       Wr0 + l*512, Wr1 + l*4096, Wr2 + l*12288, wbuf);
        k_gather<<<n1-n0, 128, 0, stream>>>(wbuf, row, sendp, sh1, s1h, v1h,
                                            n0, cap, a_s, a_v);
      }
    } else {
      hipMemsetAsync(a_s, 0, (size_t)NN*384*sizeof(float), stream);  // a_s+a_v contiguous
      k_edge<<<1250, 256, 0, stream>>>(dR, sh1, senders, receivers, s1h, v1h,
                                       Wr0 + l*512, Wr1 + l*4096, Wr2 + l*12288,
                                       a_s, a_v);
    }
    // writes back into sA/vA (safe: k_out reads only a_s/a_v/scs/scv)
    k_out<<<1250, 256, 0, stream>>>(a_s, a_v, scs, scv,
                                    W_l2_s + l*9216, W_l2_v + l*3072,
                                    sA, vA);
  }
  k_final<<<79, 256, 0, stream>>>(sA, nodes, n_node, W_en1, W_en2, W_mag1, W_mag2,
                                  scale_occ, shift_occ, escale, eshift, out);
}